// Round 4
// baseline (503.660 us; speedup 1.0000x reference)
//
#include <hip/hip_runtime.h>

// Shapes: B=16, S=1024, E=64, H=8, d=8, INPUT_DIM=310
// local mask: |i-j|<=5 (11 keys); sparse mask: j%3==0 or i==j (342 keys + diag)

#define INV_SQRT8 0.3535533905932738f

__device__ __forceinline__ float4 ld4(const float* p) { return *(const float4*)p; }

__device__ __forceinline__ float4 f4fma(float s, float4 w, float4 a) {
  a.x = fmaf(s, w.x, a.x); a.y = fmaf(s, w.y, a.y);
  a.z = fmaf(s, w.z, a.z); a.w = fmaf(s, w.w, a.w);
  return a;
}

// ---------------- Scalar-W GEMM: C[r, coff+n] = A[r,:K].W[n,:K] + bias[n]
// lane = row (A row chunk in VGPRs), W rows read via WAVE-UNIFORM addresses ->
// compiler emits s_load (scalar pipe + K$). No LDS, no barriers, ~80 VGPR.
// Block 256 = 4 waves; wave w covers cols c0 = blockIdx.y*32 + w*8 .. +8.
// K handled in chunks of 64; remainder must be 54 (proj K=310) or 0.
__global__ __launch_bounds__(256) void gemm_sw(
    const float* __restrict__ A0, const float* __restrict__ A1,
    const float* __restrict__ W0, const float* __restrict__ W1,
    const float* __restrict__ b0, const float* __restrict__ b1,
    float* __restrict__ C0, float* __restrict__ C1,
    int lda, int K, int ldc, int coff0, int coff1)
{
  const int z = blockIdx.z;
  const float* A = z ? A1 : A0;
  const float* W = z ? W1 : W0;
  const float* bias = z ? b1 : b0;
  float* C = z ? C1 : C0;
  const int coff = z ? coff1 : coff0;

  const int lane = threadIdx.x & 63;
  const int wv   = threadIdx.x >> 6;
  const int row  = blockIdx.x * 64 + lane;
  const int c0   = blockIdx.y * 32 + wv * 8;

  const float* arow = A + (size_t)row * lda;
  float acc[8];
  #pragma unroll
  for (int j = 0; j < 8; j++) acc[j] = bias[c0 + j];   // uniform s_load

  float a[64];
  const bool vec4 = ((lda & 3) == 0);
  for (int kc = 0; kc + 64 <= K; kc += 64) {
    if (vec4) {
      #pragma unroll
      for (int t = 0; t < 16; t++) {
        float4 v = ld4(arow + kc + t * 4);
        a[t*4+0] = v.x; a[t*4+1] = v.y; a[t*4+2] = v.z; a[t*4+3] = v.w;
      }
    } else {
      #pragma unroll
      for (int t = 0; t < 32; t++) {
        float2 v = *(const float2*)(arow + kc + t * 2);
        a[t*2+0] = v.x; a[t*2+1] = v.y;
      }
    }
    #pragma unroll
    for (int j = 0; j < 8; j++) {
      const float* wrow = W + (size_t)(c0 + j) * K + kc;  // wave-uniform
      float s0 = 0.f, s1 = 0.f;
      #pragma unroll
      for (int k = 0; k < 64; k += 2) {
        s0 = fmaf(a[k],     wrow[k],     s0);
        s1 = fmaf(a[k + 1], wrow[k + 1], s1);
      }
      acc[j] += s0 + s1;
    }
  }
  if (K & 63) {   // remainder: only proj uses this, 310 = 4*64 + 54
    const int kc = K & ~63;
    #pragma unroll
    for (int t = 0; t < 27; t++) {
      float2 v = *(const float2*)(arow + kc + t * 2);
      a[t*2+0] = v.x; a[t*2+1] = v.y;
    }
    #pragma unroll
    for (int j = 0; j < 8; j++) {
      const float* wrow = W + (size_t)(c0 + j) * K + kc;
      float s0 = 0.f, s1 = 0.f;
      #pragma unroll
      for (int k = 0; k < 54; k += 2) {
        s0 = fmaf(a[k],     wrow[k],     s0);
        s1 = fmaf(a[k + 1], wrow[k + 1], s1);
      }
      acc[j] += s0 + s1;
    }
  }
  float* cp = C + (size_t)row * ldc + coff + c0;
  *(float4*)cp       = make_float4(acc[0], acc[1], acc[2], acc[3]);
  *(float4*)(cp + 4) = make_float4(acc[4], acc[5], acc[6], acc[7]);
}

// ---------------- Local attention: thread per (b,i,h), 11-key window.
// qkv layout [B*S][192]: q=0..63, k=64..127, v=128..191; head h -> dims h*8..h*8+7
__global__ __launch_bounds__(256) void local_attn(
    const float* __restrict__ qkv, float* __restrict__ o)
{
  int t = blockIdx.x * 256 + threadIdx.x;   // B*S*H = 131072
  int h = t & 7;
  int i = (t >> 3) & 1023;
  int b = t >> 13;
  const float* base = qkv + (size_t)b * 1024 * 192;
  const float* qp = base + (size_t)i * 192 + h * 8;
  float4 q0 = ld4(qp), q1 = ld4(qp + 4);
  float l = 0.f;
  float4 o0 = make_float4(0.f, 0.f, 0.f, 0.f);
  float4 o1 = make_float4(0.f, 0.f, 0.f, 0.f);
  int jlo = i - 5; if (jlo < 0) jlo = 0;
  int jhi = i + 5; if (jhi > 1023) jhi = 1023;
  for (int j = jlo; j <= jhi; j++) {
    const float* kp = base + (size_t)j * 192 + 64 + h * 8;
    float4 k0 = ld4(kp), k1 = ld4(kp + 4);
    float s = q0.x * k0.x + q0.y * k0.y + q0.z * k0.z + q0.w * k0.w
            + q1.x * k1.x + q1.y * k1.y + q1.z * k1.z + q1.w * k1.w;
    float p = __expf(s * INV_SQRT8);
    l += p;
    float4 v0 = ld4(kp + 64), v1 = ld4(kp + 68);
    o0 = f4fma(p, v0, o0);
    o1 = f4fma(p, v1, o1);
  }
  float inv = 1.f / l;
  float* op = o + (size_t)(b * 1024 + i) * 64 + h * 8;
  float4 r0, r1;
  r0.x = o0.x * inv; r0.y = o0.y * inv; r0.z = o0.z * inv; r0.w = o0.w * inv;
  r1.x = o1.x * inv; r1.y = o1.y * inv; r1.z = o1.z * inv; r1.w = o1.w * inv;
  *(float4*)op = r0;
  *(float4*)(op + 4) = r1;
}

// ---------------- Global (sparse) attention, key-split x3 for occupancy.
// Split sp handles keys kk = sp*114 .. +113 (j = 3*kk); sp 0 also adds the
// diagonal when i%3!=0. Partials (o[8], l) per (t=query-head, sp) to ws.
// Grid (16, 8, 12): z = qq*3... encoded z = qq*3 + sp? Use z: qq = z>>2? No:
// z in [0,12): qq = z & 3, sp = z >> 2. 1536 blocks -> ~6 blocks/CU.
#define NKEY 342
#define KSPL 114
__global__ __launch_bounds__(256) void global_attn_part(
    const float* __restrict__ qkv, float* __restrict__ po, float* __restrict__ pl)
{
  int b = blockIdx.x, h = blockIdx.y;
  int qq = blockIdx.z & 3, sp = blockIdx.z >> 2;
  const float* base = qkv + (size_t)b * 1024 * 192;
  int i = qq * 256 + threadIdx.x;
  const float* qp = base + (size_t)i * 192 + h * 8;
  float4 q0 = ld4(qp), q1 = ld4(qp + 4);
  float l = 0.f;
  float4 o0 = make_float4(0.f, 0.f, 0.f, 0.f);
  float4 o1 = make_float4(0.f, 0.f, 0.f, 0.f);
  const float* kvb = base + 64 + h * 8;
  int kk0 = sp * KSPL;
  #pragma unroll 2
  for (int u = 0; u < KSPL; u++) {
    const float* kp = kvb + (size_t)((kk0 + u) * 3) * 192;   // wave-uniform
    float k0 = kp[0], k1 = kp[1], k2 = kp[2], k3 = kp[3];
    float k4 = kp[4], k5 = kp[5], k6 = kp[6], k7 = kp[7];
    float v0 = kp[64], v1 = kp[65], v2 = kp[66], v3 = kp[67];
    float v4 = kp[68], v5 = kp[69], v6 = kp[70], v7 = kp[71];
    float s = q0.x*k0 + q0.y*k1 + q0.z*k2 + q0.w*k3
            + q1.x*k4 + q1.y*k5 + q1.z*k6 + q1.w*k7;
    float p = __expf(s * INV_SQRT8);
    l += p;
    o0.x = fmaf(p, v0, o0.x); o0.y = fmaf(p, v1, o0.y);
    o0.z = fmaf(p, v2, o0.z); o0.w = fmaf(p, v3, o0.w);
    o1.x = fmaf(p, v4, o1.x); o1.y = fmaf(p, v5, o1.y);
    o1.z = fmaf(p, v6, o1.z); o1.w = fmaf(p, v7, o1.w);
  }
  if (sp == 0 && (i % 3) != 0) {   // diagonal key (per-lane address)
    const float* kp = base + (size_t)i * 192 + 64 + h * 8;
    float4 k0 = ld4(kp), k1 = ld4(kp + 4);
    float s = q0.x*k0.x + q0.y*k0.y + q0.z*k0.z + q0.w*k0.w
            + q1.x*k1.x + q1.y*k1.y + q1.z*k1.z + q1.w*k1.w;
    float p = __expf(s * INV_SQRT8);
    l += p;
    float4 v0 = ld4(kp + 64), v1 = ld4(kp + 68);
    o0 = f4fma(p, v0, o0);
    o1 = f4fma(p, v1, o1);
  }
  int t = ((b << 10) + i) * 8 + h;           // 0..131071
  float* pp = po + ((size_t)sp * 131072 + t) * 8;
  *(float4*)pp       = o0;
  *(float4*)(pp + 4) = o1;
  pl[sp * 131072 + t] = l;
}

__global__ __launch_bounds__(256) void global_attn_combine(
    const float* __restrict__ po, const float* __restrict__ pl,
    float* __restrict__ o)
{
  int t = blockIdx.x * 256 + threadIdx.x;    // 131072
  float l = pl[t] + pl[131072 + t] + pl[262144 + t];
  const float* p0 = po + (size_t)t * 8;
  const float* p1 = po + (size_t)(131072 + t) * 8;
  const float* p2 = po + (size_t)(262144 + t) * 8;
  float4 a0 = ld4(p0), a1 = ld4(p0 + 4);
  float4 b0 = ld4(p1), b1 = ld4(p1 + 4);
  float4 c0 = ld4(p2), c1 = ld4(p2 + 4);
  float inv = 1.f / l;
  float4 r0, r1;
  r0.x = (a0.x + b0.x + c0.x) * inv; r0.y = (a0.y + b0.y + c0.y) * inv;
  r0.z = (a0.z + b0.z + c0.z) * inv; r0.w = (a0.w + b0.w + c0.w) * inv;
  r1.x = (a1.x + b1.x + c1.x) * inv; r1.y = (a1.y + b1.y + c1.y) * inv;
  r1.z = (a1.z + b1.z + c1.z) * inv; r1.w = (a1.w + b1.w + c1.w) * inv;
  float* op = o + (size_t)(t >> 3) * 64 + (t & 7) * 8;
  *(float4*)op       = r0;
  *(float4*)(op + 4) = r1;
}

// ---------------- Pool scores: thread per row (64-thr blocks, grid 256)
__global__ __launch_bounds__(64) void score_kernel(
    const float* __restrict__ fused,
    const float* __restrict__ pw1, const float* __restrict__ pb1,
    const float* __restrict__ pw2, const float* __restrict__ pb2,
    float* __restrict__ scores)
{
  int r = blockIdx.x * 64 + threadIdx.x;   // 16384 rows
  const float* f = fused + (size_t)r * 64;
  float4 fr[16];
  #pragma unroll
  for (int e = 0; e < 16; e++) fr[e] = ld4(f + e * 4);
  float sc = pb2[0];
  #pragma unroll 4
  for (int j = 0; j < 32; j++) {
    const float* wr = pw1 + j * 64;   // wave-uniform -> scalar loads
    float hj = pb1[j];
    #pragma unroll
    for (int e = 0; e < 16; e++) {
      float4 w = ld4(wr + e * 4);
      hj += fr[e].x * w.x + fr[e].y * w.y + fr[e].z * w.z + fr[e].w * w.w;
    }
    sc += tanhf(hj) * pw2[j];
  }
  scores[r] = sc;
}

// ---------------- Softmax over S (per b) + weighted sum -> out[b][64]
__global__ __launch_bounds__(1024) void pool_kernel(
    const float* __restrict__ fused, const float* __restrict__ scores,
    float* __restrict__ out)
{
  __shared__ float pbuf[1024];
  __shared__ float part[1024];
  __shared__ float red[20];
  int b = blockIdx.x, t = threadIdx.x;
  float sc = scores[b * 1024 + t];
  float m = sc;
  #pragma unroll
  for (int off = 32; off > 0; off >>= 1)
    m = fmaxf(m, __shfl_xor(m, off, 64));
  int wid = t >> 6, lane = t & 63;
  if (lane == 0) red[wid] = m;
  __syncthreads();
  if (t == 0) {
    float mm = red[0];
    for (int g = 1; g < 16; g++) mm = fmaxf(mm, red[g]);
    red[16] = mm;
  }
  __syncthreads();
  m = red[16];
  float p = __expf(sc - m);
  pbuf[t] = p;
  float ss = p;
  #pragma unroll
  for (int off = 32; off > 0; off >>= 1)
    ss += __shfl_xor(ss, off, 64);
  if (lane == 0) red[wid] = ss;
  __syncthreads();
  if (t == 0) {
    float s2 = 0.f;
    for (int g = 0; g < 16; g++) s2 += red[g];
    red[17] = 1.f / s2;
  }
  __syncthreads();
  float inv = red[17];
  int e = t & 63, g = t >> 6;
  float acc = 0.f;
  for (int s = g; s < 1024; s += 16)
    acc = fmaf(pbuf[s], fused[((size_t)b * 1024 + s) * 64 + e], acc);
  part[t] = acc;
  __syncthreads();
  if (t < 64) {
    float tot = 0.f;
    for (int g2 = 0; g2 < 16; g2++) tot += part[g2 * 64 + t];
    out[b * 64 + t] = tot * inv;
  }
}

extern "C" void kernel_launch(void* const* d_in, const int* in_sizes, int n_in,
                              void* d_out, int out_size, void* d_ws, size_t ws_size,
                              hipStream_t stream)
{
  const float* x          = (const float*)d_in[0];
  const float* proj_w     = (const float*)d_in[1];
  const float* proj_b     = (const float*)d_in[2];
  const float* loc_in_w   = (const float*)d_in[3];
  const float* loc_in_b   = (const float*)d_in[4];
  const float* loc_out_w  = (const float*)d_in[5];
  const float* loc_out_b  = (const float*)d_in[6];
  const float* glob_in_w  = (const float*)d_in[7];
  const float* glob_in_b  = (const float*)d_in[8];
  const float* glob_out_w = (const float*)d_in[9];
  const float* glob_out_b = (const float*)d_in[10];
  const float* fusion_w   = (const float*)d_in[11];
  const float* fusion_b   = (const float*)d_in[12];
  const float* pw1        = (const float*)d_in[13];
  const float* pb1        = (const float*)d_in[14];
  const float* pw2        = (const float*)d_in[15];
  const float* pb2        = (const float*)d_in[16];

  float* ws     = (float*)d_ws;
  float* xp     = ws;                 // [16384,64]  (reused as FUSED later)
  float* qkv_l  = ws + 1048576;       // [16384,192] (reused as po partials)
  float* qkv_g  = ws + 4194304;       // [16384,192]
  float* o_l    = ws + 7340032;       // [16384,64]
  float* o_g    = ws + 8388608;       // [16384,64]
  float* cat    = ws + 9437184;       // [16384,128]
  float* scores = ws + 11534336;      // [16384]
  float* pl     = ws + 11550720;      // [3*131072]
  float* po     = qkv_l;              // 3*131072*8 floats == qkv_l size; safe:
                                      // written after local_attn consumed qkv_l
  float* fused  = xp;
  float* out    = (float*)d_out;

  dim3 blk(256);
  // xp = x @ proj_w^T + proj_b      (M=16384,K=310,N=64)
  gemm_sw<<<dim3(256, 2, 1), blk, 0, stream>>>(
      x, x, proj_w, proj_w, proj_b, proj_b, xp, xp, 310, 310, 64, 0, 0);
  // qkv (both branches): N=192, z=2 -> grid (256,6,2)
  gemm_sw<<<dim3(256, 6, 2), blk, 0, stream>>>(
      xp, xp, loc_in_w, glob_in_w, loc_in_b, glob_in_b, qkv_l, qkv_g,
      64, 64, 192, 0, 0);
  // attention branches
  local_attn<<<512, blk, 0, stream>>>(qkv_l, o_l);
  global_attn_part<<<dim3(16, 8, 12), blk, 0, stream>>>(qkv_g, po, pl);
  global_attn_combine<<<512, blk, 0, stream>>>(po, pl, o_g);
  // out-projections into concat buffer: N=64, z=2 -> (256,2,2)
  gemm_sw<<<dim3(256, 2, 2), blk, 0, stream>>>(
      o_l, o_g, loc_out_w, glob_out_w, loc_out_b, glob_out_b, cat, cat,
      64, 64, 128, 0, 64);
  // fused = cat @ fusion_w^T + fusion_b   (K=128,N=64)
  gemm_sw<<<dim3(256, 2, 1), blk, 0, stream>>>(
      cat, cat, fusion_w, fusion_w, fusion_b, fusion_b, fused, fused,
      128, 128, 64, 0, 0);
  // pooling
  score_kernel<<<256, dim3(64), 0, stream>>>(fused, pw1, pb1, pw2, pb2, scores);
  pool_kernel<<<16, dim3(1024), 0, stream>>>(fused, scores, out);
}

// Round 5
// 342.906 us; speedup vs baseline: 1.4688x; 1.4688x over previous
//
#include <hip/hip_runtime.h>

// Shapes: B=16, S=1024, E=64, H=8, d=8, INPUT_DIM=310
// local mask: |i-j|<=5 (11 keys); sparse mask: j%3==0 or i==j (342 keys + diag)

#define INV_SQRT8 0.3535533905932738f

__device__ __forceinline__ float4 ld4(const float* p) { return *(const float4*)p; }

__device__ __forceinline__ float4 f4fma(float s, float4 w, float4 a) {
  a.x = fmaf(s, w.x, a.x); a.y = fmaf(s, w.y, a.y);
  a.z = fmaf(s, w.z, a.z); a.w = fmaf(s, w.w, a.w);
  return a;
}

// ---------------- Scalar-W GEMM, workgroup-uniform W addressing.
// RULE (learned R3/R4): only blockIdx-derived addresses scalarize to s_load.
// Block = 256 threads = 256 rows (lane=row); cols c0 = blockIdx.y*NCOL (+j,
// j unrolled) -> W reads are s_load (scalar pipe + K$), inner loop is pure
// v_fmac_f32(v,s,v). No LDS, no barriers. A rows per-lane from L2/L3.
// K in chunks of 64; KREM (template) handles proj's 310 = 4*64 + 54.
template<int NCOL, int KREM>
__global__ __launch_bounds__(256) void gemm_su(
    const float* __restrict__ A0, const float* __restrict__ A1,
    const float* __restrict__ W0, const float* __restrict__ W1,
    const float* __restrict__ b0, const float* __restrict__ b1,
    float* __restrict__ C0, float* __restrict__ C1,
    int lda, int K, int ldc, int coff0, int coff1)
{
  const int z = blockIdx.z;
  const float* A = z ? A1 : A0;
  const float* W = z ? W1 : W0;
  const float* bias = z ? b1 : b0;
  float* C = z ? C1 : C0;
  const int coff = z ? coff1 : coff0;

  const int row = blockIdx.x * 256 + threadIdx.x;
  const int c0  = blockIdx.y * NCOL;          // workgroup-uniform!

  const float* arow = A + (size_t)row * lda;
  float acc[NCOL];
  #pragma unroll
  for (int j = 0; j < NCOL; j++) acc[j] = bias[c0 + j];

  float a[64];
  const bool vec4 = ((lda & 3) == 0);
  for (int kc = 0; kc + 64 <= K; kc += 64) {
    if (vec4) {
      #pragma unroll
      for (int t = 0; t < 16; t++) {
        float4 v = ld4(arow + kc + t * 4);
        a[t*4+0] = v.x; a[t*4+1] = v.y; a[t*4+2] = v.z; a[t*4+3] = v.w;
      }
    } else {
      #pragma unroll
      for (int t = 0; t < 32; t++) {
        float2 v = *(const float2*)(arow + kc + t * 2);
        a[t*2+0] = v.x; a[t*2+1] = v.y;
      }
    }
    #pragma unroll
    for (int j = 0; j < NCOL; j++) {
      const float* wrow = W + (size_t)(c0 + j) * K + kc;  // uniform -> s_load
      float s0 = 0.f, s1 = 0.f;
      #pragma unroll
      for (int k = 0; k < 64; k += 2) {
        s0 = fmaf(a[k],     wrow[k],     s0);
        s1 = fmaf(a[k + 1], wrow[k + 1], s1);
      }
      acc[j] += s0 + s1;
    }
  }
  if (KREM > 0) {
    const int kc = K & ~63;
    #pragma unroll
    for (int t = 0; t < KREM / 2; t++) {
      float2 v = *(const float2*)(arow + kc + t * 2);
      a[t*2+0] = v.x; a[t*2+1] = v.y;
    }
    #pragma unroll
    for (int j = 0; j < NCOL; j++) {
      const float* wrow = W + (size_t)(c0 + j) * K + kc;
      float s0 = 0.f, s1 = 0.f;
      #pragma unroll
      for (int k = 0; k < KREM; k += 2) {
        s0 = fmaf(a[k],     wrow[k],     s0);
        s1 = fmaf(a[k + 1], wrow[k + 1], s1);
      }
      acc[j] += s0 + s1;
    }
  }
  float* cp = C + (size_t)row * ldc + coff + c0;
  #pragma unroll
  for (int j = 0; j < NCOL; j += 4)
    *(float4*)(cp + j) = make_float4(acc[j], acc[j+1], acc[j+2], acc[j+3]);
}

// ---------------- Local attention: thread per (b,i,h), 11-key window.
// qkv layout [B*S][192]: q=0..63, k=64..127, v=128..191; head h -> dims h*8..h*8+7
__global__ __launch_bounds__(256) void local_attn(
    const float* __restrict__ qkv, float* __restrict__ o)
{
  int t = blockIdx.x * 256 + threadIdx.x;   // B*S*H = 131072
  int h = t & 7;
  int i = (t >> 3) & 1023;
  int b = t >> 13;
  const float* base = qkv + (size_t)b * 1024 * 192;
  const float* qp = base + (size_t)i * 192 + h * 8;
  float4 q0 = ld4(qp), q1 = ld4(qp + 4);
  float l = 0.f;
  float4 o0 = make_float4(0.f, 0.f, 0.f, 0.f);
  float4 o1 = make_float4(0.f, 0.f, 0.f, 0.f);
  int jlo = i - 5; if (jlo < 0) jlo = 0;
  int jhi = i + 5; if (jhi > 1023) jhi = 1023;
  for (int j = jlo; j <= jhi; j++) {
    const float* kp = base + (size_t)j * 192 + 64 + h * 8;
    float4 k0 = ld4(kp), k1 = ld4(kp + 4);
    float s = q0.x * k0.x + q0.y * k0.y + q0.z * k0.z + q0.w * k0.w
            + q1.x * k1.x + q1.y * k1.y + q1.z * k1.z + q1.w * k1.w;
    float p = __expf(s * INV_SQRT8);
    l += p;
    float4 v0 = ld4(kp + 64), v1 = ld4(kp + 68);
    o0 = f4fma(p, v0, o0);
    o1 = f4fma(p, v1, o1);
  }
  float inv = 1.f / l;
  float* op = o + (size_t)(b * 1024 + i) * 64 + h * 8;
  float4 r0, r1;
  r0.x = o0.x * inv; r0.y = o0.y * inv; r0.z = o0.z * inv; r0.w = o0.w * inv;
  r1.x = o1.x * inv; r1.y = o1.y * inv; r1.z = o1.z * inv; r1.w = o1.w * inv;
  *(float4*)op = r0;
  *(float4*)(op + 4) = r1;
}

// ---------------- Global (sparse) attention, key-split x3 for occupancy.
// K/V addresses blockIdx+loop-derived -> s_load. Grid (16,8,12), 1536 blocks.
#define NKEY 342
#define KSPL 114
__global__ __launch_bounds__(256) void global_attn_part(
    const float* __restrict__ qkv, float* __restrict__ po, float* __restrict__ pl)
{
  int b = blockIdx.x, h = blockIdx.y;
  int qq = blockIdx.z & 3, sp = blockIdx.z >> 2;
  const float* base = qkv + (size_t)b * 1024 * 192;
  int i = qq * 256 + threadIdx.x;
  const float* qp = base + (size_t)i * 192 + h * 8;
  float4 q0 = ld4(qp), q1 = ld4(qp + 4);
  float l = 0.f;
  float4 o0 = make_float4(0.f, 0.f, 0.f, 0.f);
  float4 o1 = make_float4(0.f, 0.f, 0.f, 0.f);
  const float* kvb = base + 64 + h * 8;
  int kk0 = sp * KSPL;
  #pragma unroll 2
  for (int u = 0; u < KSPL; u++) {
    const float* kp = kvb + (size_t)((kk0 + u) * 3) * 192;   // uniform
    float k0 = kp[0], k1 = kp[1], k2 = kp[2], k3 = kp[3];
    float k4 = kp[4], k5 = kp[5], k6 = kp[6], k7 = kp[7];
    float v0 = kp[64], v1 = kp[65], v2 = kp[66], v3 = kp[67];
    float v4 = kp[68], v5 = kp[69], v6 = kp[70], v7 = kp[71];
    float s = q0.x*k0 + q0.y*k1 + q0.z*k2 + q0.w*k3
            + q1.x*k4 + q1.y*k5 + q1.z*k6 + q1.w*k7;
    float p = __expf(s * INV_SQRT8);
    l += p;
    o0.x = fmaf(p, v0, o0.x); o0.y = fmaf(p, v1, o0.y);
    o0.z = fmaf(p, v2, o0.z); o0.w = fmaf(p, v3, o0.w);
    o1.x = fmaf(p, v4, o1.x); o1.y = fmaf(p, v5, o1.y);
    o1.z = fmaf(p, v6, o1.z); o1.w = fmaf(p, v7, o1.w);
  }
  if (sp == 0 && (i % 3) != 0) {   // diagonal key (per-lane address)
    const float* kp = base + (size_t)i * 192 + 64 + h * 8;
    float4 k0 = ld4(kp), k1 = ld4(kp + 4);
    float s = q0.x*k0.x + q0.y*k0.y + q0.z*k0.z + q0.w*k0.w
            + q1.x*k1.x + q1.y*k1.y + q1.z*k1.z + q1.w*k1.w;
    float p = __expf(s * INV_SQRT8);
    l += p;
    float4 v0 = ld4(kp + 64), v1 = ld4(kp + 68);
    o0 = f4fma(p, v0, o0);
    o1 = f4fma(p, v1, o1);
  }
  int t = ((b << 10) + i) * 8 + h;           // 0..131071
  float* pp = po + ((size_t)sp * 131072 + t) * 8;
  *(float4*)pp       = o0;
  *(float4*)(pp + 4) = o1;
  pl[sp * 131072 + t] = l;
}

__global__ __launch_bounds__(256) void global_attn_combine(
    const float* __restrict__ po, const float* __restrict__ pl,
    float* __restrict__ o)
{
  int t = blockIdx.x * 256 + threadIdx.x;    // 131072
  float l = pl[t] + pl[131072 + t] + pl[262144 + t];
  const float* p0 = po + (size_t)t * 8;
  const float* p1 = po + (size_t)(131072 + t) * 8;
  const float* p2 = po + (size_t)(262144 + t) * 8;
  float4 a0 = ld4(p0), a1 = ld4(p0 + 4);
  float4 b0 = ld4(p1), b1 = ld4(p1 + 4);
  float4 c0 = ld4(p2), c1 = ld4(p2 + 4);
  float inv = 1.f / l;
  float4 r0, r1;
  r0.x = (a0.x + b0.x + c0.x) * inv; r0.y = (a0.y + b0.y + c0.y) * inv;
  r0.z = (a0.z + b0.z + c0.z) * inv; r0.w = (a0.w + b0.w + c0.w) * inv;
  r1.x = (a1.x + b1.x + c1.x) * inv; r1.y = (a1.y + b1.y + c1.y) * inv;
  r1.z = (a1.z + b1.z + c1.z) * inv; r1.w = (a1.w + b1.w + c1.w) * inv;
  float* op = o + (size_t)(t >> 3) * 64 + (t & 7) * 8;
  *(float4*)op       = r0;
  *(float4*)(op + 4) = r1;
}

// ---------------- Pool scores: thread per row (64-thr blocks, grid 256)
__global__ __launch_bounds__(64) void score_kernel(
    const float* __restrict__ fused,
    const float* __restrict__ pw1, const float* __restrict__ pb1,
    const float* __restrict__ pw2, const float* __restrict__ pb2,
    float* __restrict__ scores)
{
  int r = blockIdx.x * 64 + threadIdx.x;   // 16384 rows
  const float* f = fused + (size_t)r * 64;
  float4 fr[16];
  #pragma unroll
  for (int e = 0; e < 16; e++) fr[e] = ld4(f + e * 4);
  float sc = pb2[0];
  #pragma unroll 4
  for (int j = 0; j < 32; j++) {
    const float* wr = pw1 + j * 64;   // loop-uniform -> scalar loads
    float hj = pb1[j];
    #pragma unroll
    for (int e = 0; e < 16; e++) {
      float4 w = ld4(wr + e * 4);
      hj += fr[e].x * w.x + fr[e].y * w.y + fr[e].z * w.z + fr[e].w * w.w;
    }
    sc += tanhf(hj) * pw2[j];
  }
  scores[r] = sc;
}

// ---------------- Softmax over S (per b) + weighted sum -> out[b][64]
__global__ __launch_bounds__(1024) void pool_kernel(
    const float* __restrict__ fused, const float* __restrict__ scores,
    float* __restrict__ out)
{
  __shared__ float pbuf[1024];
  __shared__ float part[1024];
  __shared__ float red[20];
  int b = blockIdx.x, t = threadIdx.x;
  float sc = scores[b * 1024 + t];
  float m = sc;
  #pragma unroll
  for (int off = 32; off > 0; off >>= 1)
    m = fmaxf(m, __shfl_xor(m, off, 64));
  int wid = t >> 6, lane = t & 63;
  if (lane == 0) red[wid] = m;
  __syncthreads();
  if (t == 0) {
    float mm = red[0];
    for (int g = 1; g < 16; g++) mm = fmaxf(mm, red[g]);
    red[16] = mm;
  }
  __syncthreads();
  m = red[16];
  float p = __expf(sc - m);
  pbuf[t] = p;
  float ss = p;
  #pragma unroll
  for (int off = 32; off > 0; off >>= 1)
    ss += __shfl_xor(ss, off, 64);
  if (lane == 0) red[wid] = ss;
  __syncthreads();
  if (t == 0) {
    float s2 = 0.f;
    for (int g = 0; g < 16; g++) s2 += red[g];
    red[17] = 1.f / s2;
  }
  __syncthreads();
  float inv = red[17];
  int e = t & 63, g = t >> 6;
  float acc = 0.f;
  for (int s = g; s < 1024; s += 16)
    acc = fmaf(pbuf[s], fused[((size_t)b * 1024 + s) * 64 + e], acc);
  part[t] = acc;
  __syncthreads();
  if (t < 64) {
    float tot = 0.f;
    for (int g2 = 0; g2 < 16; g2++) tot += part[g2 * 64 + t];
    out[b * 64 + t] = tot * inv;
  }
}

extern "C" void kernel_launch(void* const* d_in, const int* in_sizes, int n_in,
                              void* d_out, int out_size, void* d_ws, size_t ws_size,
                              hipStream_t stream)
{
  const float* x          = (const float*)d_in[0];
  const float* proj_w     = (const float*)d_in[1];
  const float* proj_b     = (const float*)d_in[2];
  const float* loc_in_w   = (const float*)d_in[3];
  const float* loc_in_b   = (const float*)d_in[4];
  const float* loc_out_w  = (const float*)d_in[5];
  const float* loc_out_b  = (const float*)d_in[6];
  const float* glob_in_w  = (const float*)d_in[7];
  const float* glob_in_b  = (const float*)d_in[8];
  const float* glob_out_w = (const float*)d_in[9];
  const float* glob_out_b = (const float*)d_in[10];
  const float* fusion_w   = (const float*)d_in[11];
  const float* fusion_b   = (const float*)d_in[12];
  const float* pw1        = (const float*)d_in[13];
  const float* pb1        = (const float*)d_in[14];
  const float* pw2        = (const float*)d_in[15];
  const float* pb2        = (const float*)d_in[16];

  float* ws     = (float*)d_ws;
  float* xp     = ws;                 // [16384,64]  (reused as FUSED later)
  float* qkv_l  = ws + 1048576;       // [16384,192] (reused as po partials)
  float* qkv_g  = ws + 4194304;       // [16384,192]
  float* o_l    = ws + 7340032;       // [16384,64]
  float* o_g    = ws + 8388608;       // [16384,64]
  float* cat    = ws + 9437184;       // [16384,128]
  float* scores = ws + 11534336;      // [16384]
  float* pl     = ws + 11550720;      // [3*131072]
  float* po     = qkv_l;              // safe: written after local_attn read qkv_l
  float* fused  = xp;
  float* out    = (float*)d_out;

  dim3 blk(256);
  // xp = x @ proj_w^T + proj_b   (M=16384, K=310, N=64): NCOL=8, KREM=54
  gemm_su<8, 54><<<dim3(64, 8, 1), blk, 0, stream>>>(
      x, x, proj_w, proj_w, proj_b, proj_b, xp, xp, 310, 310, 64, 0, 0);
  // qkv both branches: K=64, N=192: NCOL=16 -> grid (64,12,2)
  gemm_su<16, 0><<<dim3(64, 12, 2), blk, 0, stream>>>(
      xp, xp, loc_in_w, glob_in_w, loc_in_b, glob_in_b, qkv_l, qkv_g,
      64, 64, 192, 0, 0);
  // attention branches
  local_attn<<<512, blk, 0, stream>>>(qkv_l, o_l);
  global_attn_part<<<dim3(16, 8, 12), blk, 0, stream>>>(qkv_g, po, pl);
  global_attn_combine<<<512, blk, 0, stream>>>(po, pl, o_g);
  // out-projections into concat buffer: K=64, N=64 each: NCOL=16 -> (64,4,2)
  gemm_su<16, 0><<<dim3(64, 4, 2), blk, 0, stream>>>(
      o_l, o_g, loc_out_w, glob_out_w, loc_out_b, glob_out_b, cat, cat,
      64, 64, 128, 0, 64);
  // fused = cat @ fusion_w^T + fusion_b  (K=128, N=64): NCOL=8 -> (64,8)
  gemm_su<8, 0><<<dim3(64, 8, 1), blk, 0, stream>>>(
      cat, cat, fusion_w, fusion_w, fusion_b, fusion_b, fused, fused,
      128, 128, 64, 0, 0);
  // pooling
  score_kernel<<<256, dim3(64), 0, stream>>>(fused, pw1, pb1, pw2, pb2, scores);
  pool_kernel<<<16, dim3(1024), 0, stream>>>(fused, scores, out);
}

// Round 6
// 265.165 us; speedup vs baseline: 1.8994x; 1.2932x over previous
//
#include <hip/hip_runtime.h>

// Shapes: B=16, S=1024, E=64, H=8, d=8, INPUT_DIM=310
// local mask: |i-j|<=5 (11 keys); sparse mask: j%3==0 or i==j (342 keys + diag)
//
// GEMMs via mfma_f32_16x16x32_bf16 with fp32 = bf16hi + bf16lo split (3 MFMA).
// Verified layouts (guide §3): A-frag A[m=lane&15][k=quad*8+j]; B-frag
// B[n=lane&15][k=quad*8+j] (W is [N][K] row-major = B-frag-ready);
// C/D: col=lane&15, row=quad*4+reg.

typedef __attribute__((ext_vector_type(8))) short short8;
typedef __attribute__((ext_vector_type(4))) float float4v;

#define INV_SQRT8 0.3535533905932738f

__device__ __forceinline__ float4 ld4(const float* p) { return *(const float4*)p; }

__device__ __forceinline__ float4 f4fma(float s, float4 w, float4 a) {
  a.x = fmaf(s, w.x, a.x); a.y = fmaf(s, w.y, a.y);
  a.z = fmaf(s, w.z, a.z); a.w = fmaf(s, w.w, a.w);
  return a;
}

// RNE fp32 -> (bf16 hi, bf16 lo); x == hi + lo to ~2^-16 relative.
__device__ __forceinline__ void bsplit(float x, short& h, short& l) {
  unsigned xb = __float_as_uint(x);
  unsigned hb = (xb + 0x7fffu + ((xb >> 16) & 1u)) & 0xffff0000u;
  h = (short)(hb >> 16);
  float lf = x - __uint_as_float(hb);
  unsigned lb = __float_as_uint(lf);
  l = (short)((lb + 0x7fffu + ((lb >> 16) & 1u)) >> 16);
}

// ---------------- prep_x: x[16384][310] fp32 -> Xh/Xl[16384][320] bf16 (zero pad)
__global__ __launch_bounds__(256) void prep_x(
    const float* __restrict__ x, short* __restrict__ Xh, short* __restrict__ Xl)
{
  unsigned idx = blockIdx.x * 256 + threadIdx.x;   // 16384*320 = 5242880
  unsigned row = idx / 320u, k = idx - row * 320u;
  float v = (k < 310u) ? x[row * 310u + k] : 0.f;
  short h, l; bsplit(v, h, l);
  Xh[idx] = h; Xl[idx] = l;
}

// ---------------- prep_w: split all weight matrices into wbuf segments.
// Segment offsets (shorts): projh 0, projl 20480 (64x320 padded from 64x310),
// linh 40960, linl 53248 (192x64), ginh 65536, ginl 77824,
// louth 90112, loutl 94208 (64x64), gouth 98304, goutl 102400,
// fush 106496, fusl 114688 (64x128). Total 122880 shorts.
__global__ __launch_bounds__(256) void prep_w(
    const float* __restrict__ pw, const float* __restrict__ liw,
    const float* __restrict__ giw, const float* __restrict__ low,
    const float* __restrict__ gow, const float* __restrict__ fw,
    short* __restrict__ wb)
{
  unsigned idx = blockIdx.x * 256 + threadIdx.x;   // 61440
  float v; unsigned ho, lo_;
  if (idx < 20480u) {           // proj, padded
    unsigned r = idx / 320u, k = idx - r * 320u;
    v = (k < 310u) ? pw[r * 310u + k] : 0.f;
    ho = 0u + idx; lo_ = 20480u + idx;
  } else if (idx < 32768u) {    // loc_in
    unsigned i = idx - 20480u; v = liw[i]; ho = 40960u + i; lo_ = 53248u + i;
  } else if (idx < 45056u) {    // glob_in
    unsigned i = idx - 32768u; v = giw[i]; ho = 65536u + i; lo_ = 77824u + i;
  } else if (idx < 49152u) {    // loc_out
    unsigned i = idx - 45056u; v = low[i]; ho = 90112u + i; lo_ = 94208u + i;
  } else if (idx < 53248u) {    // glob_out
    unsigned i = idx - 49152u; v = gow[i]; ho = 98304u + i; lo_ = 102400u + i;
  } else {                      // fusion
    unsigned i = idx - 53248u; v = fw[i]; ho = 106496u + i; lo_ = 114688u + i;
  }
  short h, l; bsplit(v, h, l);
  wb[ho] = h; wb[lo_] = l;
}

// ---------------- MFMA GEMM: C[m, coff+n] = A[m,:KP].W[n,:KP] + bias[n]
// Block 256 = 4 waves; wave w: rows m0=bx*64+w*16, cols n0=by*32 (2 n-frags).
// blockIdx.z picks between two (A,W,bias,C,coff) sets.
template<int KP, bool ABF16, bool WF32, bool WBF16>
__global__ __launch_bounds__(256) void gemm_mfma(
    const void* A0a, const void* A0b, const void* A1a, const void* A1b,
    const short* __restrict__ Wh0, const short* __restrict__ Wl0,
    const short* __restrict__ Wh1, const short* __restrict__ Wl1,
    const float* __restrict__ bias0, const float* __restrict__ bias1,
    float* __restrict__ C0, float* __restrict__ C1,
    short* __restrict__ Ch, short* __restrict__ Cl,
    int ldc, int coff0, int coff1)
{
  const int z = blockIdx.z;
  const short* Wh = z ? Wh1 : Wh0;
  const short* Wl = z ? Wl1 : Wl0;
  const float* bias = z ? bias1 : bias0;
  float* C = z ? C1 : C0;
  const int coff = z ? coff1 : coff0;

  const int lane = threadIdx.x & 63;
  const int w = threadIdx.x >> 6;
  const int q = lane >> 4, r = lane & 15;
  const int m0 = blockIdx.x * 64 + w * 16;
  const int n0 = blockIdx.y * 32;

  const short* Ah = nullptr; const short* Al = nullptr; const float* Af = nullptr;
  if (ABF16) {
    Ah = (const short*)(z ? A1a : A0a);
    Al = (const short*)(z ? A1b : A0b);
  } else {
    Af = (const float*)(z ? A1a : A0a);
  }

  float bv0 = bias[n0 + r], bv1 = bias[n0 + 16 + r];
  float4v acc0 = {bv0, bv0, bv0, bv0};
  float4v acc1 = {bv1, bv1, bv1, bv1};

  #pragma unroll
  for (int ks = 0; ks < KP / 32; ks++) {
    const int k0 = ks * 32 + q * 8;
    short8 ah, al;
    if (ABF16) {
      ah = *(const short8*)(Ah + (size_t)(m0 + r) * KP + k0);
      al = *(const short8*)(Al + (size_t)(m0 + r) * KP + k0);
    } else {
      const float* ap = Af + (size_t)(m0 + r) * KP + k0;
      float4 f0 = ld4(ap), f1 = ld4(ap + 4);
      short h, l;
      bsplit(f0.x, h, l); ah[0] = h; al[0] = l;
      bsplit(f0.y, h, l); ah[1] = h; al[1] = l;
      bsplit(f0.z, h, l); ah[2] = h; al[2] = l;
      bsplit(f0.w, h, l); ah[3] = h; al[3] = l;
      bsplit(f1.x, h, l); ah[4] = h; al[4] = l;
      bsplit(f1.y, h, l); ah[5] = h; al[5] = l;
      bsplit(f1.z, h, l); ah[6] = h; al[6] = l;
      bsplit(f1.w, h, l); ah[7] = h; al[7] = l;
    }
    short8 bh0 = *(const short8*)(Wh + (size_t)(n0 + r) * KP + k0);
    short8 bl0 = *(const short8*)(Wl + (size_t)(n0 + r) * KP + k0);
    short8 bh1 = *(const short8*)(Wh + (size_t)(n0 + 16 + r) * KP + k0);
    short8 bl1 = *(const short8*)(Wl + (size_t)(n0 + 16 + r) * KP + k0);
    acc0 = __builtin_amdgcn_mfma_f32_16x16x32_bf16(al, bh0, acc0, 0, 0, 0);
    acc0 = __builtin_amdgcn_mfma_f32_16x16x32_bf16(ah, bl0, acc0, 0, 0, 0);
    acc0 = __builtin_amdgcn_mfma_f32_16x16x32_bf16(ah, bh0, acc0, 0, 0, 0);
    acc1 = __builtin_amdgcn_mfma_f32_16x16x32_bf16(al, bh1, acc1, 0, 0, 0);
    acc1 = __builtin_amdgcn_mfma_f32_16x16x32_bf16(ah, bl1, acc1, 0, 0, 0);
    acc1 = __builtin_amdgcn_mfma_f32_16x16x32_bf16(ah, bh1, acc1, 0, 0, 0);
  }

  #pragma unroll
  for (int e = 0; e < 4; e++) {
    const int row = m0 + q * 4 + e;
    const int col0c = n0 + r, col1c = n0 + 16 + r;
    float v0 = acc0[e], v1 = acc1[e];
    if (WF32) {
      C[(size_t)row * ldc + coff + col0c] = v0;
      C[(size_t)row * ldc + coff + col1c] = v1;
    }
    if (WBF16) {
      short h, l;
      bsplit(v0, h, l);
      Ch[(size_t)row * 64 + col0c] = h; Cl[(size_t)row * 64 + col0c] = l;
      bsplit(v1, h, l);
      Ch[(size_t)row * 64 + col1c] = h; Cl[(size_t)row * 64 + col1c] = l;
    }
  }
}

// ---------------- Local attention: thread per (b,i,h), 11-key window.
// qkv layout [B*S][192]: q=0..63, k=64..127, v=128..191; head h -> dims h*8..h*8+7
__global__ __launch_bounds__(256) void local_attn(
    const float* __restrict__ qkv, float* __restrict__ o)
{
  int t = blockIdx.x * 256 + threadIdx.x;   // B*S*H = 131072
  int h = t & 7;
  int i = (t >> 3) & 1023;
  int b = t >> 13;
  const float* base = qkv + (size_t)b * 1024 * 192;
  const float* qp = base + (size_t)i * 192 + h * 8;
  float4 q0 = ld4(qp), q1 = ld4(qp + 4);
  float l = 0.f;
  float4 o0 = make_float4(0.f, 0.f, 0.f, 0.f);
  float4 o1 = make_float4(0.f, 0.f, 0.f, 0.f);
  int jlo = i - 5; if (jlo < 0) jlo = 0;
  int jhi = i + 5; if (jhi > 1023) jhi = 1023;
  for (int j = jlo; j <= jhi; j++) {
    const float* kp = base + (size_t)j * 192 + 64 + h * 8;
    float4 k0 = ld4(kp), k1 = ld4(kp + 4);
    float s = q0.x * k0.x + q0.y * k0.y + q0.z * k0.z + q0.w * k0.w
            + q1.x * k1.x + q1.y * k1.y + q1.z * k1.z + q1.w * k1.w;
    float p = __expf(s * INV_SQRT8);
    l += p;
    float4 v0 = ld4(kp + 64), v1 = ld4(kp + 68);
    o0 = f4fma(p, v0, o0);
    o1 = f4fma(p, v1, o1);
  }
  float inv = 1.f / l;
  float* op = o + (size_t)(b * 1024 + i) * 64 + h * 8;
  float4 r0, r1;
  r0.x = o0.x * inv; r0.y = o0.y * inv; r0.z = o0.z * inv; r0.w = o0.w * inv;
  r1.x = o1.x * inv; r1.y = o1.y * inv; r1.z = o1.z * inv; r1.w = o1.w * inv;
  *(float4*)op = r0;
  *(float4*)(op + 4) = r1;
}

// ---------------- Global (sparse) attention, key-split x3.
#define NKEY 342
#define KSPL 114
__global__ __launch_bounds__(256) void global_attn_part(
    const float* __restrict__ qkv, float* __restrict__ po, float* __restrict__ pl)
{
  int b = blockIdx.x, h = blockIdx.y;
  int qq = blockIdx.z & 3, sp = blockIdx.z >> 2;
  const float* base = qkv + (size_t)b * 1024 * 192;
  int i = qq * 256 + threadIdx.x;
  const float* qp = base + (size_t)i * 192 + h * 8;
  float4 q0 = ld4(qp), q1 = ld4(qp + 4);
  float l = 0.f;
  float4 o0 = make_float4(0.f, 0.f, 0.f, 0.f);
  float4 o1 = make_float4(0.f, 0.f, 0.f, 0.f);
  const float* kvb = base + 64 + h * 8;
  int kk0 = sp * KSPL;
  #pragma unroll 2
  for (int u = 0; u < KSPL; u++) {
    const float* kp = kvb + (size_t)((kk0 + u) * 3) * 192;   // uniform -> s_load
    float k0 = kp[0], k1 = kp[1], k2 = kp[2], k3 = kp[3];
    float k4 = kp[4], k5 = kp[5], k6 = kp[6], k7 = kp[7];
    float v0 = kp[64], v1 = kp[65], v2 = kp[66], v3 = kp[67];
    float v4 = kp[68], v5 = kp[69], v6 = kp[70], v7 = kp[71];
    float s = q0.x*k0 + q0.y*k1 + q0.z*k2 + q0.w*k3
            + q1.x*k4 + q1.y*k5 + q1.z*k6 + q1.w*k7;
    float p = __expf(s * INV_SQRT8);
    l += p;
    o0.x = fmaf(p, v0, o0.x); o0.y = fmaf(p, v1, o0.y);
    o0.z = fmaf(p, v2, o0.z); o0.w = fmaf(p, v3, o0.w);
    o1.x = fmaf(p, v4, o1.x); o1.y = fmaf(p, v5, o1.y);
    o1.z = fmaf(p, v6, o1.z); o1.w = fmaf(p, v7, o1.w);
  }
  if (sp == 0 && (i % 3) != 0) {   // diagonal key (per-lane address)
    const float* kp = base + (size_t)i * 192 + 64 + h * 8;
    float4 k0 = ld4(kp), k1 = ld4(kp + 4);
    float s = q0.x*k0.x + q0.y*k0.y + q0.z*k0.z + q0.w*k0.w
            + q1.x*k1.x + q1.y*k1.y + q1.z*k1.z + q1.w*k1.w;
    float p = __expf(s * INV_SQRT8);
    l += p;
    float4 v0 = ld4(kp + 64), v1 = ld4(kp + 68);
    o0 = f4fma(p, v0, o0);
    o1 = f4fma(p, v1, o1);
  }
  int t = ((b << 10) + i) * 8 + h;           // 0..131071
  float* pp = po + ((size_t)sp * 131072 + t) * 8;
  *(float4*)pp       = o0;
  *(float4*)(pp + 4) = o1;
  pl[sp * 131072 + t] = l;
}

__global__ __launch_bounds__(256) void global_attn_combine(
    const float* __restrict__ po, const float* __restrict__ pl,
    float* __restrict__ o)
{
  int t = blockIdx.x * 256 + threadIdx.x;    // 131072
  float l = pl[t] + pl[131072 + t] + pl[262144 + t];
  const float* p0 = po + (size_t)t * 8;
  const float* p1 = po + (size_t)(131072 + t) * 8;
  const float* p2 = po + (size_t)(262144 + t) * 8;
  float4 a0 = ld4(p0), a1 = ld4(p0 + 4);
  float4 b0 = ld4(p1), b1 = ld4(p1 + 4);
  float4 c0 = ld4(p2), c1 = ld4(p2 + 4);
  float inv = 1.f / l;
  float4 r0, r1;
  r0.x = (a0.x + b0.x + c0.x) * inv; r0.y = (a0.y + b0.y + c0.y) * inv;
  r0.z = (a0.z + b0.z + c0.z) * inv; r0.w = (a0.w + b0.w + c0.w) * inv;
  r1.x = (a1.x + b1.x + c1.x) * inv; r1.y = (a1.y + b1.y + c1.y) * inv;
  r1.z = (a1.z + b1.z + c1.z) * inv; r1.w = (a1.w + b1.w + c1.w) * inv;
  float* op = o + (size_t)(t >> 3) * 64 + (t & 7) * 8;
  *(float4*)op       = r0;
  *(float4*)(op + 4) = r1;
}

// ---------------- Pool scores: thread per row (64-thr blocks, grid 256)
__global__ __launch_bounds__(64) void score_kernel(
    const float* __restrict__ fused,
    const float* __restrict__ pw1, const float* __restrict__ pb1,
    const float* __restrict__ pw2, const float* __restrict__ pb2,
    float* __restrict__ scores)
{
  int r = blockIdx.x * 64 + threadIdx.x;   // 16384 rows
  const float* f = fused + (size_t)r * 64;
  float4 fr[16];
  #pragma unroll
  for (int e = 0; e < 16; e++) fr[e] = ld4(f + e * 4);
  float sc = pb2[0];
  #pragma unroll 4
  for (int j = 0; j < 32; j++) {
    const float* wr = pw1 + j * 64;   // loop-uniform -> scalar loads
    float hj = pb1[j];
    #pragma unroll
    for (int e = 0; e < 16; e++) {
      float4 w = ld4(wr + e * 4);
      hj += fr[e].x * w.x + fr[e].y * w.y + fr[e].z * w.z + fr[e].w * w.w;
    }
    sc += tanhf(hj) * pw2[j];
  }
  scores[r] = sc;
}

// ---------------- Softmax over S (per b) + weighted sum -> out[b][64]
__global__ __launch_bounds__(1024) void pool_kernel(
    const float* __restrict__ fused, const float* __restrict__ scores,
    float* __restrict__ out)
{
  __shared__ float pbuf[1024];
  __shared__ float part[1024];
  __shared__ float red[20];
  int b = blockIdx.x, t = threadIdx.x;
  float sc = scores[b * 1024 + t];
  float m = sc;
  #pragma unroll
  for (int off = 32; off > 0; off >>= 1)
    m = fmaxf(m, __shfl_xor(m, off, 64));
  int wid = t >> 6, lane = t & 63;
  if (lane == 0) red[wid] = m;
  __syncthreads();
  if (t == 0) {
    float mm = red[0];
    for (int g = 1; g < 16; g++) mm = fmaxf(mm, red[g]);
    red[16] = mm;
  }
  __syncthreads();
  m = red[16];
  float p = __expf(sc - m);
  pbuf[t] = p;
  float ss = p;
  #pragma unroll
  for (int off = 32; off > 0; off >>= 1)
    ss += __shfl_xor(ss, off, 64);
  if (lane == 0) red[wid] = ss;
  __syncthreads();
  if (t == 0) {
    float s2 = 0.f;
    for (int g = 0; g < 16; g++) s2 += red[g];
    red[17] = 1.f / s2;
  }
  __syncthreads();
  float inv = red[17];
  int e = t & 63, g = t >> 6;
  float acc = 0.f;
  for (int s = g; s < 1024; s += 16)
    acc = fmaf(pbuf[s], fused[((size_t)b * 1024 + s) * 64 + e], acc);
  part[t] = acc;
  __syncthreads();
  if (t < 64) {
    float tot = 0.f;
    for (int g2 = 0; g2 < 16; g2++) tot += part[g2 * 64 + t];
    out[b * 64 + t] = tot * inv;
  }
}

extern "C" void kernel_launch(void* const* d_in, const int* in_sizes, int n_in,
                              void* d_out, int out_size, void* d_ws, size_t ws_size,
                              hipStream_t stream)
{
  const float* x          = (const float*)d_in[0];
  const float* proj_w     = (const float*)d_in[1];
  const float* proj_b     = (const float*)d_in[2];
  const float* loc_in_w   = (const float*)d_in[3];
  const float* loc_in_b   = (const float*)d_in[4];
  const float* loc_out_w  = (const float*)d_in[5];
  const float* loc_out_b  = (const float*)d_in[6];
  const float* glob_in_w  = (const float*)d_in[7];
  const float* glob_in_b  = (const float*)d_in[8];
  const float* glob_out_w = (const float*)d_in[9];
  const float* glob_out_b = (const float*)d_in[10];
  const float* fusion_w   = (const float*)d_in[11];
  const float* fusion_b   = (const float*)d_in[12];
  const float* pw1        = (const float*)d_in[13];
  const float* pb1        = (const float*)d_in[14];
  const float* pw2        = (const float*)d_in[15];
  const float* pb2        = (const float*)d_in[16];

  float* ws = (float*)d_ws;
  // Lifetime-packed layout (float offsets), peak 10,547,200 floats = 42.2 MB:
  //  X hi/lo  [0, 5242880)      (launch 2 -> 3)
  //  qkv_g    [0, 3145728)      (4 -> 6, over dead X)
  //  fused    [0, 1048576)      (9 -> 11, over dead qkv_g)
  //  o_g      [1048576, 2097152)   (7 -> 8)
  //  scores   [2097152, 2113536)   (10 -> 11)
  //  cat      [2113536, 4210688)   (8 -> 9)
  //  pl       [3145728, 3538944)   (6 -> 7; dead before cat written? no -
  //                                 cat written launch 8 AFTER gcomb(7) ✓)
  //  xp hi/lo [5242880, 6291456)   (3 -> 4)
  //  qkv_l    [6291456, 9437184)   (4 -> 5)
  //  po       [6291456, 9437184)   (6 -> 7, over dead qkv_l)
  //  o_l      [9437184, 10485760)  (5 -> 8)
  //  wbuf     [10485760, 10547200) (1 -> 9)
  short* Xh    = (short*)ws;                    // 5242880 shorts
  short* Xl    = (short*)ws + 5242880;
  float* qkv_g = ws;
  float* fused = ws;
  float* o_g   = ws + 1048576;
  float* scores= ws + 2097152;
  float* cat   = ws + 2113536;
  float* pl    = ws + 3145728;
  short* xph   = (short*)(ws + 5242880);
  short* xpl   = (short*)(ws + 5767168);
  float* qkv_l = ws + 6291456;
  float* po    = ws + 6291456;
  float* o_l   = ws + 9437184;
  short* wb    = (short*)(ws + 10485760);
  short* projh = wb;           short* projl = wb + 20480;
  short* linh  = wb + 40960;   short* linl  = wb + 53248;
  short* ginh  = wb + 65536;   short* ginl  = wb + 77824;
  short* louth = wb + 90112;   short* loutl = wb + 94208;
  short* gouth = wb + 98304;   short* goutl = wb + 102400;
  short* fush  = wb + 106496;  short* fusl  = wb + 114688;
  float* out   = (float*)d_out;

  dim3 blk(256);
  // 1: weight split
  prep_w<<<240, blk, 0, stream>>>(proj_w, loc_in_w, glob_in_w, loc_out_w,
                                  glob_out_w, fusion_w, wb);
  // 2: x split + pad to K=320
  prep_x<<<20480, blk, 0, stream>>>(x, Xh, Xl);
  // 3: proj -> xp (bf16 hi/lo only)   M=16384 K=320 N=64
  gemm_mfma<320, true, false, true><<<dim3(256, 2, 1), blk, 0, stream>>>(
      Xh, Xl, Xh, Xl, projh, projl, projh, projl, proj_b, proj_b,
      nullptr, nullptr, xph, xpl, 64, 0, 0);
  // 4: qkv both branches  K=64 N=192
  gemm_mfma<64, true, true, false><<<dim3(256, 6, 2), blk, 0, stream>>>(
      xph, xpl, xph, xpl, linh, linl, ginh, ginl, loc_in_b, glob_in_b,
      qkv_l, qkv_g, nullptr, nullptr, 192, 0, 0);
  // 5: local attention
  local_attn<<<512, blk, 0, stream>>>(qkv_l, o_l);
  // 6,7: global attention (key-split + combine)
  global_attn_part<<<dim3(16, 8, 12), blk, 0, stream>>>(qkv_g, po, pl);
  global_attn_combine<<<512, blk, 0, stream>>>(po, pl, o_g);
  // 8: out-projections (fp32 A, converted in-register)  K=64 N=64 x2 -> cat
  gemm_mfma<64, false, true, false><<<dim3(256, 2, 2), blk, 0, stream>>>(
      o_l, nullptr, o_g, nullptr, louth, loutl, gouth, goutl,
      loc_out_b, glob_out_b, cat, cat, nullptr, nullptr, 128, 0, 64);
  // 9: fusion  K=128 N=64
  gemm_mfma<128, false, true, false><<<dim3(256, 2, 1), blk, 0, stream>>>(
      cat, nullptr, cat, nullptr, fush, fusl, fush, fusl, fusion_b, fusion_b,
      fused, fused, nullptr, nullptr, 64, 0, 0);
  // 10, 11: pooling
  score_kernel<<<256, dim3(64), 0, stream>>>(fused, pw1, pb1, pw2, pb2, scores);
  pool_kernel<<<16, dim3(1024), 0, stream>>>(fused, scores, out);
}

// Round 7
// 249.657 us; speedup vs baseline: 2.0174x; 1.0621x over previous
//
#include <hip/hip_runtime.h>

// Shapes: B=16, S=1024, E=64, H=8, d=8, INPUT_DIM=310
// local mask: |i-j|<=5 (11 keys); sparse mask: j%3==0 or i==j (342 keys + diag)
//
// GEMMs via mfma_f32_16x16x32_bf16 with fp32 = bf16hi + bf16lo split (3 MFMA).
// A-frag A[m=lane&15][k=quad*8+j]; B-frag B[n=lane&15][k=quad*8+j];
// C/D: col=lane&15, row=quad*4+reg.
//
// Algebraic fusion: fused = o_l @ W1^T + o_g @ W2^T + bc with
// W1 = F[:, :64]@loc_out_w, W2 = F[:, 64:]@glob_out_w,
// bc = F[:, :64]@lob + F[:, 64:]@gob + fb  -> out-projections eliminated.

typedef __attribute__((ext_vector_type(8))) short short8;
typedef __attribute__((ext_vector_type(4))) float float4v;

#define INV_SQRT8 0.3535533905932738f

__device__ __forceinline__ float4 ld4(const float* p) { return *(const float4*)p; }

__device__ __forceinline__ float4 f4fma(float s, float4 w, float4 a) {
  a.x = fmaf(s, w.x, a.x); a.y = fmaf(s, w.y, a.y);
  a.z = fmaf(s, w.z, a.z); a.w = fmaf(s, w.w, a.w);
  return a;
}

// RNE fp32 -> (bf16 hi, bf16 lo); x == hi + lo to ~2^-16 relative.
__device__ __forceinline__ void bsplit(float x, short& h, short& l) {
  unsigned xb = __float_as_uint(x);
  unsigned hb = (xb + 0x7fffu + ((xb >> 16) & 1u)) & 0xffff0000u;
  h = (short)(hb >> 16);
  float lf = x - __uint_as_float(hb);
  unsigned lb = __float_as_uint(lf);
  l = (short)((lb + 0x7fffu + ((lb >> 16) & 1u)) >> 16);
}

// ---------------- prep_small: W12[n][k] (k<64: F1@low, k>=64: F2@gow), bc[n]
__global__ __launch_bounds__(256) void prep_small(
    const float* __restrict__ fw, const float* __restrict__ low,
    const float* __restrict__ gow, const float* __restrict__ lob,
    const float* __restrict__ gob, const float* __restrict__ fb,
    float* __restrict__ w12, float* __restrict__ bc)
{
  int idx = blockIdx.x * 256 + threadIdx.x;   // 8192
  int n = idx >> 7, k = idx & 127;
  float s = 0.f;
  if (k < 64) {
    for (int e = 0; e < 64; e++) s += fw[n * 128 + e] * low[e * 64 + k];
  } else {
    for (int e = 0; e < 64; e++) s += fw[n * 128 + 64 + e] * gow[e * 64 + (k - 64)];
  }
  w12[idx] = s;
  if (idx < 64) {
    float b = fb[idx];
    for (int e = 0; e < 64; e++)
      b += lob[e] * fw[idx * 128 + e] + gob[e] * fw[idx * 128 + 64 + e];
    bc[idx] = b;
  }
}

// ---------------- prep_w: split weights into wb segments (shorts):
// projh 0 / projl 20480  (64x320, zero-padded from 64x310)
// linh 40960 / linl 53248 (192x64)
// ginh 65536 / ginl 77824 (192x64)
// wfh 90112 / wfl 98304   (64x128, from w12 fp32)
__global__ __launch_bounds__(256) void prep_w(
    const float* __restrict__ pw, const float* __restrict__ liw,
    const float* __restrict__ giw, const float* __restrict__ w12,
    short* __restrict__ wb)
{
  unsigned idx = blockIdx.x * 256 + threadIdx.x;   // 53248
  if (idx >= 53248u) return;
  float v; unsigned ho, lo_;
  if (idx < 20480u) {           // proj, padded
    unsigned r = idx / 320u, k = idx - r * 320u;
    v = (k < 310u) ? pw[r * 310u + k] : 0.f;
    ho = 0u + idx; lo_ = 20480u + idx;
  } else if (idx < 32768u) {    // loc_in
    unsigned i = idx - 20480u; v = liw[i]; ho = 40960u + i; lo_ = 53248u + i;
  } else if (idx < 45056u) {    // glob_in
    unsigned i = idx - 32768u; v = giw[i]; ho = 65536u + i; lo_ = 77824u + i;
  } else {                      // fused weight W12
    unsigned i = idx - 45056u; v = w12[i]; ho = 90112u + i; lo_ = 98304u + i;
  }
  short h, l; bsplit(v, h, l);
  wb[ho] = h; wb[lo_] = l;
}

// ---------------- prep_x: x[16384][310] fp32 -> Xh/Xl[16384][320] bf16 (pad 0)
__global__ __launch_bounds__(256) void prep_x(
    const float* __restrict__ x, short* __restrict__ Xh, short* __restrict__ Xl)
{
  unsigned idx = blockIdx.x * 256 + threadIdx.x;   // 5242880
  unsigned row = idx / 320u, k = idx - row * 320u;
  float v = (k < 310u) ? x[row * 310u + k] : 0.f;
  short h, l; bsplit(v, h, l);
  Xh[idx] = h; Xl[idx] = l;
}

// ---------------- MFMA GEMM (bf16 A): C = A.W^T + bias
template<int KP, bool WF32, bool WBF16>
__global__ __launch_bounds__(256) void gemm_mfma(
    const short* __restrict__ Ah, const short* __restrict__ Al,
    const short* __restrict__ Wh0, const short* __restrict__ Wl0,
    const short* __restrict__ Wh1, const short* __restrict__ Wl1,
    const float* __restrict__ bias0, const float* __restrict__ bias1,
    float* __restrict__ C0, float* __restrict__ C1,
    short* __restrict__ Ch, short* __restrict__ Cl, int ldc)
{
  const int z = blockIdx.z;
  const short* Wh = z ? Wh1 : Wh0;
  const short* Wl = z ? Wl1 : Wl0;
  const float* bias = z ? bias1 : bias0;
  float* C = z ? C1 : C0;

  const int lane = threadIdx.x & 63;
  const int w = threadIdx.x >> 6;
  const int q = lane >> 4, r = lane & 15;
  const int m0 = blockIdx.x * 64 + w * 16;
  const int n0 = blockIdx.y * 32;

  float bv0 = bias[n0 + r], bv1 = bias[n0 + 16 + r];
  float4v acc0 = {bv0, bv0, bv0, bv0};
  float4v acc1 = {bv1, bv1, bv1, bv1};

  #pragma unroll
  for (int ks = 0; ks < KP / 32; ks++) {
    const int k0 = ks * 32 + q * 8;
    short8 ah = *(const short8*)(Ah + (size_t)(m0 + r) * KP + k0);
    short8 al = *(const short8*)(Al + (size_t)(m0 + r) * KP + k0);
    short8 bh0 = *(const short8*)(Wh + (size_t)(n0 + r) * KP + k0);
    short8 bl0 = *(const short8*)(Wl + (size_t)(n0 + r) * KP + k0);
    short8 bh1 = *(const short8*)(Wh + (size_t)(n0 + 16 + r) * KP + k0);
    short8 bl1 = *(const short8*)(Wl + (size_t)(n0 + 16 + r) * KP + k0);
    acc0 = __builtin_amdgcn_mfma_f32_16x16x32_bf16(al, bh0, acc0, 0, 0, 0);
    acc0 = __builtin_amdgcn_mfma_f32_16x16x32_bf16(ah, bl0, acc0, 0, 0, 0);
    acc0 = __builtin_amdgcn_mfma_f32_16x16x32_bf16(ah, bh0, acc0, 0, 0, 0);
    acc1 = __builtin_amdgcn_mfma_f32_16x16x32_bf16(al, bh1, acc1, 0, 0, 0);
    acc1 = __builtin_amdgcn_mfma_f32_16x16x32_bf16(ah, bl1, acc1, 0, 0, 0);
    acc1 = __builtin_amdgcn_mfma_f32_16x16x32_bf16(ah, bh1, acc1, 0, 0, 0);
  }

  #pragma unroll
  for (int e = 0; e < 4; e++) {
    const int row = m0 + q * 4 + e;
    const int col0c = n0 + r, col1c = n0 + 16 + r;
    float v0 = acc0[e], v1 = acc1[e];
    if (WF32) {
      C[(size_t)row * ldc + col0c] = v0;
      C[(size_t)row * ldc + col1c] = v1;
    }
    if (WBF16) {
      short h, l;
      bsplit(v0, h, l);
      Ch[(size_t)row * 64 + col0c] = h; Cl[(size_t)row * 64 + col0c] = l;
      bsplit(v1, h, l);
      Ch[(size_t)row * 64 + col1c] = h; Cl[(size_t)row * 64 + col1c] = l;
    }
  }
}

// ---------------- Fusion GEMM: fused = [o_l | combine(po,pl)] @ Wf^T + bc
// A cols 0..63 from o_l fp32; cols 64..127 combined from po/pl in-register.
__global__ __launch_bounds__(256) void gemm_fuse(
    const float* __restrict__ o_l, const float* __restrict__ po,
    const float* __restrict__ pl,
    const short* __restrict__ Wh, const short* __restrict__ Wl,
    const float* __restrict__ bc, float* __restrict__ C)
{
  const int lane = threadIdx.x & 63;
  const int w = threadIdx.x >> 6;
  const int q = lane >> 4, r = lane & 15;
  const int m0 = blockIdx.x * 64 + w * 16;
  const int n0 = blockIdx.y * 32;

  float bv0 = bc[n0 + r], bv1 = bc[n0 + 16 + r];
  float4v acc0 = {bv0, bv0, bv0, bv0};
  float4v acc1 = {bv1, bv1, bv1, bv1};

  #pragma unroll
  for (int ks = 0; ks < 4; ks++) {
    const int k0 = ks * 32 + q * 8;
    const int row = m0 + r;
    float av[8];
    if (ks < 2) {   // k0 in [0,64): o_l
      const float* ap = o_l + (size_t)row * 64 + k0;
      float4 f0 = ld4(ap), f1 = ld4(ap + 4);
      av[0]=f0.x; av[1]=f0.y; av[2]=f0.z; av[3]=f0.w;
      av[4]=f1.x; av[5]=f1.y; av[6]=f1.z; av[7]=f1.w;
    } else {        // k0 in [64,128): combine global-attn partials, head h
      const int h = (k0 - 64) >> 3;
      const size_t t = (size_t)row * 8 + h;
      const float* p0 = po + t * 8;
      const float* p1 = po + (131072 + t) * 8;
      const float* p2 = po + (262144 + t) * 8;
      float4 a0 = ld4(p0), a1 = ld4(p0 + 4);
      float4 b0 = ld4(p1), b1 = ld4(p1 + 4);
      float4 c0 = ld4(p2), c1 = ld4(p2 + 4);
      float inv = 1.f / (pl[t] + pl[131072 + t] + pl[262144 + t]);
      av[0]=(a0.x+b0.x+c0.x)*inv; av[1]=(a0.y+b0.y+c0.y)*inv;
      av[2]=(a0.z+b0.z+c0.z)*inv; av[3]=(a0.w+b0.w+c0.w)*inv;
      av[4]=(a1.x+b1.x+c1.x)*inv; av[5]=(a1.y+b1.y+c1.y)*inv;
      av[6]=(a1.z+b1.z+c1.z)*inv; av[7]=(a1.w+b1.w+c1.w)*inv;
    }
    short8 ah, al;
    #pragma unroll
    for (int i = 0; i < 8; i++) { short h, l; bsplit(av[i], h, l); ah[i]=h; al[i]=l; }
    short8 bh0 = *(const short8*)(Wh + (size_t)(n0 + r) * 128 + k0);
    short8 bl0 = *(const short8*)(Wl + (size_t)(n0 + r) * 128 + k0);
    short8 bh1 = *(const short8*)(Wh + (size_t)(n0 + 16 + r) * 128 + k0);
    short8 bl1 = *(const short8*)(Wl + (size_t)(n0 + 16 + r) * 128 + k0);
    acc0 = __builtin_amdgcn_mfma_f32_16x16x32_bf16(al, bh0, acc0, 0, 0, 0);
    acc0 = __builtin_amdgcn_mfma_f32_16x16x32_bf16(ah, bl0, acc0, 0, 0, 0);
    acc0 = __builtin_amdgcn_mfma_f32_16x16x32_bf16(ah, bh0, acc0, 0, 0, 0);
    acc1 = __builtin_amdgcn_mfma_f32_16x16x32_bf16(al, bh1, acc1, 0, 0, 0);
    acc1 = __builtin_amdgcn_mfma_f32_16x16x32_bf16(ah, bl1, acc1, 0, 0, 0);
    acc1 = __builtin_amdgcn_mfma_f32_16x16x32_bf16(ah, bh1, acc1, 0, 0, 0);
  }

  #pragma unroll
  for (int e = 0; e < 4; e++) {
    const int row = m0 + q * 4 + e;
    C[(size_t)row * 64 + n0 + r] = acc0[e];
    C[(size_t)row * 64 + n0 + 16 + r] = acc1[e];
  }
}

// ---------------- Local attention: thread per (b,i,h), 11-key window.
__global__ __launch_bounds__(256) void local_attn(
    const float* __restrict__ qkv, float* __restrict__ o)
{
  int t = blockIdx.x * 256 + threadIdx.x;   // 131072
  int h = t & 7;
  int i = (t >> 3) & 1023;
  int b = t >> 13;
  const float* base = qkv + (size_t)b * 1024 * 192;
  const float* qp = base + (size_t)i * 192 + h * 8;
  float4 q0 = ld4(qp), q1 = ld4(qp + 4);
  float l = 0.f;
  float4 o0 = make_float4(0.f, 0.f, 0.f, 0.f);
  float4 o1 = make_float4(0.f, 0.f, 0.f, 0.f);
  int jlo = i - 5; if (jlo < 0) jlo = 0;
  int jhi = i + 5; if (jhi > 1023) jhi = 1023;
  for (int j = jlo; j <= jhi; j++) {
    const float* kp = base + (size_t)j * 192 + 64 + h * 8;
    float4 k0 = ld4(kp), k1 = ld4(kp + 4);
    float s = q0.x * k0.x + q0.y * k0.y + q0.z * k0.z + q0.w * k0.w
            + q1.x * k1.x + q1.y * k1.y + q1.z * k1.z + q1.w * k1.w;
    float p = __expf(s * INV_SQRT8);
    l += p;
    float4 v0 = ld4(kp + 64), v1 = ld4(kp + 68);
    o0 = f4fma(p, v0, o0);
    o1 = f4fma(p, v1, o1);
  }
  float inv = 1.f / l;
  float* op = o + (size_t)(b * 1024 + i) * 64 + h * 8;
  float4 r0, r1;
  r0.x = o0.x * inv; r0.y = o0.y * inv; r0.z = o0.z * inv; r0.w = o0.w * inv;
  r1.x = o1.x * inv; r1.y = o1.y * inv; r1.z = o1.z * inv; r1.w = o1.w * inv;
  *(float4*)op = r0;
  *(float4*)(op + 4) = r1;
}

// ---------------- Global (sparse) attention, key-split x3; s_load K/V.
#define NKEY 342
#define KSPL 114
__global__ __launch_bounds__(256) void global_attn_part(
    const float* __restrict__ qkv, float* __restrict__ po, float* __restrict__ pl)
{
  int b = blockIdx.x, h = blockIdx.y;
  int qq = blockIdx.z & 3, sp = blockIdx.z >> 2;
  const float* base = qkv + (size_t)b * 1024 * 192;
  int i = qq * 256 + threadIdx.x;
  const float* qp = base + (size_t)i * 192 + h * 8;
  float4 q0 = ld4(qp), q1 = ld4(qp + 4);
  float l = 0.f;
  float4 o0 = make_float4(0.f, 0.f, 0.f, 0.f);
  float4 o1 = make_float4(0.f, 0.f, 0.f, 0.f);
  const float* kvb = base + 64 + h * 8;
  int kk0 = sp * KSPL;
  #pragma unroll 2
  for (int u = 0; u < KSPL; u++) {
    const float* kp = kvb + (size_t)((kk0 + u) * 3) * 192;   // uniform -> s_load
    float k0 = kp[0], k1 = kp[1], k2 = kp[2], k3 = kp[3];
    float k4 = kp[4], k5 = kp[5], k6 = kp[6], k7 = kp[7];
    float v0 = kp[64], v1 = kp[65], v2 = kp[66], v3 = kp[67];
    float v4 = kp[68], v5 = kp[69], v6 = kp[70], v7 = kp[71];
    float s = q0.x*k0 + q0.y*k1 + q0.z*k2 + q0.w*k3
            + q1.x*k4 + q1.y*k5 + q1.z*k6 + q1.w*k7;
    float p = __expf(s * INV_SQRT8);
    l += p;
    o0.x = fmaf(p, v0, o0.x); o0.y = fmaf(p, v1, o0.y);
    o0.z = fmaf(p, v2, o0.z); o0.w = fmaf(p, v3, o0.w);
    o1.x = fmaf(p, v4, o1.x); o1.y = fmaf(p, v5, o1.y);
    o1.z = fmaf(p, v6, o1.z); o1.w = fmaf(p, v7, o1.w);
  }
  if (sp == 0 && (i % 3) != 0) {   // diagonal key (per-lane address)
    const float* kp = base + (size_t)i * 192 + 64 + h * 8;
    float4 k0 = ld4(kp), k1 = ld4(kp + 4);
    float s = q0.x*k0.x + q0.y*k0.y + q0.z*k0.z + q0.w*k0.w
            + q1.x*k1.x + q1.y*k1.y + q1.z*k1.z + q1.w*k1.w;
    float p = __expf(s * INV_SQRT8);
    l += p;
    float4 v0 = ld4(kp + 64), v1 = ld4(kp + 68);
    o0 = f4fma(p, v0, o0);
    o1 = f4fma(p, v1, o1);
  }
  int t = ((b << 10) + i) * 8 + h;           // = row*8 + h
  float* pp = po + ((size_t)sp * 131072 + t) * 8;
  *(float4*)pp       = o0;
  *(float4*)(pp + 4) = o1;
  pl[sp * 131072 + t] = l;
}

// ---------------- Pool scores: thread per row
__global__ __launch_bounds__(64) void score_kernel(
    const float* __restrict__ fused,
    const float* __restrict__ pw1, const float* __restrict__ pb1,
    const float* __restrict__ pw2, const float* __restrict__ pb2,
    float* __restrict__ scores)
{
  int r = blockIdx.x * 64 + threadIdx.x;   // 16384 rows
  const float* f = fused + (size_t)r * 64;
  float4 fr[16];
  #pragma unroll
  for (int e = 0; e < 16; e++) fr[e] = ld4(f + e * 4);
  float sc = pb2[0];
  #pragma unroll 4
  for (int j = 0; j < 32; j++) {
    const float* wr = pw1 + j * 64;   // loop-uniform -> s_load
    float hj = pb1[j];
    #pragma unroll
    for (int e = 0; e < 16; e++) {
      float4 w = ld4(wr + e * 4);
      hj += fr[e].x * w.x + fr[e].y * w.y + fr[e].z * w.z + fr[e].w * w.w;
    }
    sc += tanhf(hj) * pw2[j];
  }
  scores[r] = sc;
}

// ---------------- pool_a: per-batch max & 1/Z; zero d_out
__global__ __launch_bounds__(1024) void pool_a(
    const float* __restrict__ scores, float* __restrict__ msum,
    float* __restrict__ out)
{
  __shared__ float red[20];
  int b = blockIdx.x, t = threadIdx.x;
  float sc = scores[b * 1024 + t];
  float m = sc;
  #pragma unroll
  for (int off = 32; off > 0; off >>= 1)
    m = fmaxf(m, __shfl_xor(m, off, 64));
  int wid = t >> 6, lane = t & 63;
  if (lane == 0) red[wid] = m;
  __syncthreads();
  if (t == 0) {
    float mm = red[0];
    for (int g = 1; g < 16; g++) mm = fmaxf(mm, red[g]);
    red[16] = mm;
  }
  __syncthreads();
  m = red[16];
  float p = __expf(sc - m);
  float ss = p;
  #pragma unroll
  for (int off = 32; off > 0; off >>= 1)
    ss += __shfl_xor(ss, off, 64);
  if (lane == 0) red[wid] = ss;
  __syncthreads();
  if (t == 0) {
    float s2 = 0.f;
    for (int g = 0; g < 16; g++) s2 += red[g];
    msum[b] = m;
    msum[16 + b] = 1.f / s2;
  }
  if (t < 64) out[b * 64 + t] = 0.f;
}

// ---------------- pool_b: distributed weighted sum, atomicAdd into d_out
__global__ __launch_bounds__(256) void pool_b(
    const float* __restrict__ fused, const float* __restrict__ scores,
    const float* __restrict__ msum, float* __restrict__ out)
{
  __shared__ float pbuf[64];
  __shared__ float part[256];
  int b = blockIdx.x, c = blockIdx.y, t = threadIdx.x;
  float m = msum[b], invZ = msum[16 + b];
  if (t < 64) pbuf[t] = __expf(scores[b * 1024 + c * 64 + t] - m);
  __syncthreads();
  int e = t & 63, g = t >> 6;
  float acc = 0.f;
  for (int rr = g; rr < 64; rr += 4)
    acc = fmaf(pbuf[rr], fused[((size_t)(b * 1024 + c * 64 + rr)) * 64 + e], acc);
  part[t] = acc;
  __syncthreads();
  if (g == 0) {
    float tot = part[e] + part[64 + e] + part[128 + e] + part[192 + e];
    atomicAdd(&out[b * 64 + e], tot * invZ);
  }
}

extern "C" void kernel_launch(void* const* d_in, const int* in_sizes, int n_in,
                              void* d_out, int out_size, void* d_ws, size_t ws_size,
                              hipStream_t stream)
{
  const float* x          = (const float*)d_in[0];
  const float* proj_w     = (const float*)d_in[1];
  const float* proj_b     = (const float*)d_in[2];
  const float* loc_in_w   = (const float*)d_in[3];
  const float* loc_in_b   = (const float*)d_in[4];
  const float* loc_out_w  = (const float*)d_in[5];
  const float* loc_out_b  = (const float*)d_in[6];
  const float* glob_in_w  = (const float*)d_in[7];
  const float* glob_in_b  = (const float*)d_in[8];
  const float* glob_out_w = (const float*)d_in[9];
  const float* glob_out_b = (const float*)d_in[10];
  const float* fusion_w   = (const float*)d_in[11];
  const float* fusion_b   = (const float*)d_in[12];
  const float* pw1        = (const float*)d_in[13];
  const float* pb1        = (const float*)d_in[14];
  const float* pw2        = (const float*)d_in[15];
  const float* pb2        = (const float*)d_in[16];

  float* ws = (float*)d_ws;
  // Lifetime-packed (float offsets):
  //  Xh/Xl     [0, 5242880)        prep_x -> proj
  //  qkv_g     [0, 3145728)        qkv -> gpart      (over dead X)
  //  fused     [0, 1048576)        gemm_fuse -> score/pool (over dead qkv_g)
  //  scores    [2097152, 2113536)  score -> pool
  //  msum      [2113536, 2113568)  pool_a -> pool_b
  //  pl        [3145728, 3538944)  gpart -> gemm_fuse
  //  xph/xpl   [5242880, 6291456)  proj -> qkv
  //  qkv_l     [6291456, 9437184)  qkv -> local
  //  po        [6291456, 9437184)  gpart -> gemm_fuse (over dead qkv_l)
  //  o_l       [9437184, 10485760) local -> gemm_fuse
  //  w12       [10485760, 10493952), bc [10493952, 10494016)
  //  wb shorts [10494016, 10547264)
  short* Xh    = (short*)ws;
  short* Xl    = (short*)ws + 5242880;
  float* qkv_g = ws;
  float* fused = ws;
  float* scores= ws + 2097152;
  float* msum  = ws + 2113536;
  float* pl    = ws + 3145728;
  short* xph   = (short*)(ws + 5242880);
  short* xpl   = (short*)(ws + 5767168);
  float* qkv_l = ws + 6291456;
  float* po    = ws + 6291456;
  float* o_l   = ws + 9437184;
  float* w12   = ws + 10485760;
  float* bc    = ws + 10493952;
  short* wb    = (short*)(ws + 10494016);
  short* projh = wb;           short* projl = wb + 20480;
  short* linh  = wb + 40960;   short* linl  = wb + 53248;
  short* ginh  = wb + 65536;   short* ginl  = wb + 77824;
  short* wfh   = wb + 90112;   short* wfl   = wb + 98304;
  float* out   = (float*)d_out;

  dim3 blk(256);
  // 1: combined fusion weights (fp32)
  prep_small<<<32, blk, 0, stream>>>(fusion_w, loc_out_w, glob_out_w,
                                     loc_out_b, glob_out_b, fusion_b, w12, bc);
  // 2: weight bf16 split
  prep_w<<<208, blk, 0, stream>>>(proj_w, loc_in_w, glob_in_w, w12, wb);
  // 3: x split + pad to K=320
  prep_x<<<20480, blk, 0, stream>>>(x, Xh, Xl);
  // 4: proj -> xp (bf16 hi/lo)   M=16384 K=320 N=64
  gemm_mfma<320, false, true><<<dim3(256, 2, 1), blk, 0, stream>>>(
      Xh, Xl, projh, projl, projh, projl, proj_b, proj_b,
      nullptr, nullptr, xph, xpl, 64);
  // 5: qkv both branches  K=64 N=192
  gemm_mfma<64, true, false><<<dim3(256, 6, 2), blk, 0, stream>>>(
      xph, xpl, linh, linl, ginh, ginl, loc_in_b, glob_in_b,
      qkv_l, qkv_g, nullptr, nullptr, 192);
  // 6: local attention -> o_l
  local_attn<<<512, blk, 0, stream>>>(qkv_l, o_l);
  // 7: global attention partials (key-split x3)
  global_attn_part<<<dim3(16, 8, 12), blk, 0, stream>>>(qkv_g, po, pl);
  // 8: fusion GEMM (combine + outproj + fusion folded)  K=128 N=64
  gemm_fuse<<<dim3(256, 2, 1), blk, 0, stream>>>(o_l, po, pl, wfh, wfl, bc, fused);
  // 9,10,11: pooling
  score_kernel<<<256, dim3(64), 0, stream>>>(fused, pw1, pb1, pw2, pb2, scores);
  pool_a<<<16, dim3(1024), 0, stream>>>(scores, msum, out);
  pool_b<<<dim3(16, 16), blk, 0, stream>>>(fused, scores, msum, out);
}

// Round 8
// 238.891 us; speedup vs baseline: 2.1083x; 1.0451x over previous
//
#include <hip/hip_runtime.h>

// Shapes: B=16, S=1024, E=64, H=8, d=8, INPUT_DIM=310
// local mask: |i-j|<=5 (11 keys); sparse mask: j%3==0 or i==j (342 keys + diag)
//
// GEMMs via mfma_f32_16x16x32_bf16, fp32 = bf16hi + bf16lo split (3 MFMA).
// A-frag A[m=lane&15][k=quad*8+j]; B-frag B[n=lane&15][k=quad*8+j];
// C/D: col=lane&15, row=quad*4+reg.
// Algebraic fusion: fused = o_l@W1^T + o_g@W2^T + bc (out-projections folded).
// Global attention reads compressed K/V [b][h][342][8] via wave-uniform s_load
// (2 keys per 64B scalar-cache line).

typedef __attribute__((ext_vector_type(8))) short short8;
typedef __attribute__((ext_vector_type(4))) float float4v;

#define INV_SQRT8 0.3535533905932738f

__device__ __forceinline__ float4 ld4(const float* p) { return *(const float4*)p; }

__device__ __forceinline__ float4 f4fma(float s, float4 w, float4 a) {
  a.x = fmaf(s, w.x, a.x); a.y = fmaf(s, w.y, a.y);
  a.z = fmaf(s, w.z, a.z); a.w = fmaf(s, w.w, a.w);
  return a;
}

// RNE fp32 -> (bf16 hi, bf16 lo); x == hi + lo to ~2^-16 relative.
__device__ __forceinline__ void bsplit(float x, short& h, short& l) {
  unsigned xb = __float_as_uint(x);
  unsigned hb = (xb + 0x7fffu + ((xb >> 16) & 1u)) & 0xffff0000u;
  h = (short)(hb >> 16);
  float lf = x - __uint_as_float(hb);
  unsigned lb = __float_as_uint(lf);
  l = (short)((lb + 0x7fffu + ((lb >> 16) & 1u)) >> 16);
}

// ---------------- prep_w: split weights into wb segments (shorts) + fused
// fusion weights computed on the fly + combined bias bc.
// projh 0 / projl 20480 (64x320 zero-padded), linh 40960 / linl 53248,
// ginh 65536 / ginl 77824, wfh 90112 / wfl 98304 (64x128). 112640 shorts.
__global__ __launch_bounds__(256) void prep_w(
    const float* __restrict__ pw, const float* __restrict__ liw,
    const float* __restrict__ giw, const float* __restrict__ fw,
    const float* __restrict__ low, const float* __restrict__ gow,
    const float* __restrict__ lob, const float* __restrict__ gob,
    const float* __restrict__ fb,
    short* __restrict__ wb, float* __restrict__ bc)
{
  unsigned idx = blockIdx.x * 256 + threadIdx.x;   // 53248 total
  float v; unsigned ho, lo_;
  if (idx < 20480u) {           // proj, padded K 310->320
    unsigned r = idx / 320u, k = idx - r * 320u;
    v = (k < 310u) ? pw[r * 310u + k] : 0.f;
    ho = 0u + idx; lo_ = 20480u + idx;
  } else if (idx < 32768u) {    // loc_in
    unsigned i = idx - 20480u; v = liw[i]; ho = 40960u + i; lo_ = 53248u + i;
  } else if (idx < 45056u) {    // glob_in
    unsigned i = idx - 32768u; v = giw[i]; ho = 65536u + i; lo_ = 77824u + i;
  } else {                      // fused fusion weight W12[n][k]
    unsigned i = idx - 45056u;
    unsigned n = i >> 7, k = i & 127u;
    float s = 0.f;
    if (k < 64u) {
      for (int e = 0; e < 64; e++) s += fw[n * 128 + e] * low[e * 64 + k];
    } else {
      for (int e = 0; e < 64; e++) s += fw[n * 128 + 64 + e] * gow[e * 64 + (k - 64u)];
    }
    v = s; ho = 90112u + i; lo_ = 98304u + i;
  }
  short h, l; bsplit(v, h, l);
  wb[ho] = h; wb[lo_] = l;
  if (idx < 64u) {
    float b = fb[idx];
    for (int e = 0; e < 64; e++)
      b += lob[e] * fw[idx * 128 + e] + gob[e] * fw[idx * 128 + 64 + e];
    bc[idx] = b;
  }
}

// ---------------- proj GEMM: xp = x @ proj_w^T + proj_b, fp32 A converted
// in-register (prep_x fused away). K=310 (W padded to 320). Writes bf16 hi/lo.
__global__ __launch_bounds__(256) void gemm_proj(
    const float* __restrict__ X,
    const short* __restrict__ Wh, const short* __restrict__ Wl,
    const float* __restrict__ bias,
    short* __restrict__ Ch, short* __restrict__ Cl)
{
  const int lane = threadIdx.x & 63;
  const int w = threadIdx.x >> 6;
  const int q = lane >> 4, r = lane & 15;
  const int m0 = blockIdx.x * 64 + w * 16;
  const int n0 = blockIdx.y * 32;

  float bv0 = bias[n0 + r], bv1 = bias[n0 + 16 + r];
  float4v acc0 = {bv0, bv0, bv0, bv0};
  float4v acc1 = {bv1, bv1, bv1, bv1};

  const float* arow = X + (size_t)(m0 + r) * 310;

  #pragma unroll
  for (int ks = 0; ks < 10; ks++) {
    const int k0 = ks * 32 + q * 8;
    float av[8];
    if (ks < 9) {   // k0+7 <= 287+7 < 310, 8B-aligned (k0 even, 310 even)
      const float* ap = arow + k0;
      #pragma unroll
      for (int t = 0; t < 4; t++) {
        float2 f = *(const float2*)(ap + t * 2);
        av[t*2] = f.x; av[t*2+1] = f.y;
      }
    } else {        // tail: guard k>=310
      #pragma unroll
      for (int j = 0; j < 8; j++) {
        int kidx = k0 + j;
        av[j] = (kidx < 310) ? arow[kidx] : 0.f;
      }
    }
    short8 ah, al;
    #pragma unroll
    for (int i = 0; i < 8; i++) { short h, l; bsplit(av[i], h, l); ah[i]=h; al[i]=l; }
    short8 bh0 = *(const short8*)(Wh + (size_t)(n0 + r) * 320 + k0);
    short8 bl0 = *(const short8*)(Wl + (size_t)(n0 + r) * 320 + k0);
    short8 bh1 = *(const short8*)(Wh + (size_t)(n0 + 16 + r) * 320 + k0);
    short8 bl1 = *(const short8*)(Wl + (size_t)(n0 + 16 + r) * 320 + k0);
    acc0 = __builtin_amdgcn_mfma_f32_16x16x32_bf16(al, bh0, acc0, 0, 0, 0);
    acc0 = __builtin_amdgcn_mfma_f32_16x16x32_bf16(ah, bl0, acc0, 0, 0, 0);
    acc0 = __builtin_amdgcn_mfma_f32_16x16x32_bf16(ah, bh0, acc0, 0, 0, 0);
    acc1 = __builtin_amdgcn_mfma_f32_16x16x32_bf16(al, bh1, acc1, 0, 0, 0);
    acc1 = __builtin_amdgcn_mfma_f32_16x16x32_bf16(ah, bl1, acc1, 0, 0, 0);
    acc1 = __builtin_amdgcn_mfma_f32_16x16x32_bf16(ah, bh1, acc1, 0, 0, 0);
  }

  #pragma unroll
  for (int e = 0; e < 4; e++) {
    const int row = m0 + q * 4 + e;
    short h, l;
    bsplit(acc0[e], h, l);
    Ch[(size_t)row * 64 + n0 + r] = h; Cl[(size_t)row * 64 + n0 + r] = l;
    bsplit(acc1[e], h, l);
    Ch[(size_t)row * 64 + n0 + 16 + r] = h; Cl[(size_t)row * 64 + n0 + 16 + r] = l;
  }
}

// ---------------- MFMA GEMM (bf16 A): C = A.W^T + bias (fp32 C)
template<int KP>
__global__ __launch_bounds__(256) void gemm_mfma(
    const short* __restrict__ Ah, const short* __restrict__ Al,
    const short* __restrict__ Wh0, const short* __restrict__ Wl0,
    const short* __restrict__ Wh1, const short* __restrict__ Wl1,
    const float* __restrict__ bias0, const float* __restrict__ bias1,
    float* __restrict__ C0, float* __restrict__ C1, int ldc)
{
  const int z = blockIdx.z;
  const short* Wh = z ? Wh1 : Wh0;
  const short* Wl = z ? Wl1 : Wl0;
  const float* bias = z ? bias1 : bias0;
  float* C = z ? C1 : C0;

  const int lane = threadIdx.x & 63;
  const int w = threadIdx.x >> 6;
  const int q = lane >> 4, r = lane & 15;
  const int m0 = blockIdx.x * 64 + w * 16;
  const int n0 = blockIdx.y * 32;

  float bv0 = bias[n0 + r], bv1 = bias[n0 + 16 + r];
  float4v acc0 = {bv0, bv0, bv0, bv0};
  float4v acc1 = {bv1, bv1, bv1, bv1};

  #pragma unroll
  for (int ks = 0; ks < KP / 32; ks++) {
    const int k0 = ks * 32 + q * 8;
    short8 ah = *(const short8*)(Ah + (size_t)(m0 + r) * KP + k0);
    short8 al = *(const short8*)(Al + (size_t)(m0 + r) * KP + k0);
    short8 bh0 = *(const short8*)(Wh + (size_t)(n0 + r) * KP + k0);
    short8 bl0 = *(const short8*)(Wl + (size_t)(n0 + r) * KP + k0);
    short8 bh1 = *(const short8*)(Wh + (size_t)(n0 + 16 + r) * KP + k0);
    short8 bl1 = *(const short8*)(Wl + (size_t)(n0 + 16 + r) * KP + k0);
    acc0 = __builtin_amdgcn_mfma_f32_16x16x32_bf16(al, bh0, acc0, 0, 0, 0);
    acc0 = __builtin_amdgcn_mfma_f32_16x16x32_bf16(ah, bl0, acc0, 0, 0, 0);
    acc0 = __builtin_amdgcn_mfma_f32_16x16x32_bf16(ah, bh0, acc0, 0, 0, 0);
    acc1 = __builtin_amdgcn_mfma_f32_16x16x32_bf16(al, bh1, acc1, 0, 0, 0);
    acc1 = __builtin_amdgcn_mfma_f32_16x16x32_bf16(ah, bl1, acc1, 0, 0, 0);
    acc1 = __builtin_amdgcn_mfma_f32_16x16x32_bf16(ah, bh1, acc1, 0, 0, 0);
  }

  #pragma unroll
  for (int e = 0; e < 4; e++) {
    const int row = m0 + q * 4 + e;
    C[(size_t)row * ldc + n0 + r] = acc0[e];
    C[(size_t)row * ldc + n0 + 16 + r] = acc1[e];
  }
}

// ---------------- repack: compressed K/V for the sparse branch.
// Kc/Vc[b][h][kk][d], kk = 0..341 (j = 3*kk).
__global__ __launch_bounds__(256) void repack_kv(
    const float* __restrict__ qkv, float* __restrict__ Kc, float* __restrict__ Vc)
{
  unsigned idx = blockIdx.x * 256 + threadIdx.x;   // 16*342*128 = 700416
  if (idx >= 700416u) return;
  unsigned c = idx & 127u;
  unsigned bk = idx >> 7;          // b*342 + kk
  unsigned b = bk / 342u, kk = bk - b * 342u;
  float val = qkv[((size_t)(b * 1024 + kk * 3)) * 192 + 64 + c];
  unsigned h = (c & 63u) >> 3, d = c & 7u;
  unsigned o = ((b * 8 + h) * 342u + kk) * 8u + d;
  if (c < 64u) Kc[o] = val; else Vc[o] = val;
}

// ---------------- Local attention: thread per (b,i,h), 11-key window.
__global__ __launch_bounds__(256) void local_attn(
    const float* __restrict__ qkv, float* __restrict__ o)
{
  int t = blockIdx.x * 256 + threadIdx.x;   // 131072
  int h = t & 7;
  int i = (t >> 3) & 1023;
  int b = t >> 13;
  const float* base = qkv + (size_t)b * 1024 * 192;
  const float* qp = base + (size_t)i * 192 + h * 8;
  float4 q0 = ld4(qp), q1 = ld4(qp + 4);
  float l = 0.f;
  float4 o0 = make_float4(0.f, 0.f, 0.f, 0.f);
  float4 o1 = make_float4(0.f, 0.f, 0.f, 0.f);
  int jlo = i - 5; if (jlo < 0) jlo = 0;
  int jhi = i + 5; if (jhi > 1023) jhi = 1023;
  for (int j = jlo; j <= jhi; j++) {
    const float* kp = base + (size_t)j * 192 + 64 + h * 8;
    float4 k0 = ld4(kp), k1 = ld4(kp + 4);
    float s = q0.x * k0.x + q0.y * k0.y + q0.z * k0.z + q0.w * k0.w
            + q1.x * k1.x + q1.y * k1.y + q1.z * k1.z + q1.w * k1.w;
    float p = __expf(s * INV_SQRT8);
    l += p;
    float4 v0 = ld4(kp + 64), v1 = ld4(kp + 68);
    o0 = f4fma(p, v0, o0);
    o1 = f4fma(p, v1, o1);
  }
  float inv = 1.f / l;
  float* op = o + (size_t)(b * 1024 + i) * 64 + h * 8;
  float4 r0, r1;
  r0.x = o0.x * inv; r0.y = o0.y * inv; r0.z = o0.z * inv; r0.w = o0.w * inv;
  r1.x = o1.x * inv; r1.y = o1.y * inv; r1.z = o1.z * inv; r1.w = o1.w * inv;
  *(float4*)op = r0;
  *(float4*)(op + 4) = r1;
}

// ---------------- Global (sparse) attention: compressed K/V, 2 keys per
// 64B s_load line, key-split x3. Grid (16,8,12): qq=z&3, sp=z>>2.
#define KSPL 114
__global__ __launch_bounds__(256) void global_attn_part(
    const float* __restrict__ qkv, const float* __restrict__ Kc,
    const float* __restrict__ Vc,
    float* __restrict__ po, float* __restrict__ pl)
{
  int b = blockIdx.x, h = blockIdx.y;
  int qq = blockIdx.z & 3, sp = blockIdx.z >> 2;
  const float* base = qkv + (size_t)b * 1024 * 192;
  int i = qq * 256 + threadIdx.x;
  const float* qp = base + (size_t)i * 192 + h * 8;
  float4 q0 = ld4(qp), q1 = ld4(qp + 4);
  float l = 0.f;
  float4 o0 = make_float4(0.f, 0.f, 0.f, 0.f);
  float4 o1 = make_float4(0.f, 0.f, 0.f, 0.f);
  const size_t kvoff = ((size_t)(b * 8 + h) * 342 + sp * KSPL) * 8;
  const float* kbase = Kc + kvoff;
  const float* vbase = Vc + kvoff;
  for (int u = 0; u < KSPL / 2; u++) {
    const float* kp = kbase + u * 16;   // wave-uniform, 2 keys (64B)
    const float* vp = vbase + u * 16;
    float ka[16], va[16];
    #pragma unroll
    for (int d = 0; d < 16; d++) { ka[d] = kp[d]; va[d] = vp[d]; }
    float s0 = q0.x*ka[0] + q0.y*ka[1] + q0.z*ka[2] + q0.w*ka[3]
             + q1.x*ka[4] + q1.y*ka[5] + q1.z*ka[6] + q1.w*ka[7];
    float s1 = q0.x*ka[8] + q0.y*ka[9] + q0.z*ka[10] + q0.w*ka[11]
             + q1.x*ka[12] + q1.y*ka[13] + q1.z*ka[14] + q1.w*ka[15];
    float p0 = __expf(s0 * INV_SQRT8);
    float p1 = __expf(s1 * INV_SQRT8);
    l += p0 + p1;
    o0.x = fmaf(p0, va[0], fmaf(p1, va[8],  o0.x));
    o0.y = fmaf(p0, va[1], fmaf(p1, va[9],  o0.y));
    o0.z = fmaf(p0, va[2], fmaf(p1, va[10], o0.z));
    o0.w = fmaf(p0, va[3], fmaf(p1, va[11], o0.w));
    o1.x = fmaf(p0, va[4], fmaf(p1, va[12], o1.x));
    o1.y = fmaf(p0, va[5], fmaf(p1, va[13], o1.y));
    o1.z = fmaf(p0, va[6], fmaf(p1, va[14], o1.z));
    o1.w = fmaf(p0, va[7], fmaf(p1, va[15], o1.w));
  }
  if (sp == 0 && (i % 3) != 0) {   // diagonal key (per-lane address)
    const float* kp = base + (size_t)i * 192 + 64 + h * 8;
    float4 k0 = ld4(kp), k1 = ld4(kp + 4);
    float s = q0.x*k0.x + q0.y*k0.y + q0.z*k0.z + q0.w*k0.w
            + q1.x*k1.x + q1.y*k1.y + q1.z*k1.z + q1.w*k1.w;
    float p = __expf(s * INV_SQRT8);
    l += p;
    float4 v0 = ld4(kp + 64), v1 = ld4(kp + 68);
    o0 = f4fma(p, v0, o0);
    o1 = f4fma(p, v1, o1);
  }
  int t = ((b << 10) + i) * 8 + h;           // = row*8 + h
  float* pp = po + ((size_t)sp * 131072 + t) * 8;
  *(float4*)pp       = o0;
  *(float4*)(pp + 4) = o1;
  pl[sp * 131072 + t] = l;
}

// ---------------- Fusion GEMM: fused = [o_l | combine(po,pl)] @ Wf^T + bc
__global__ __launch_bounds__(256) void gemm_fuse(
    const float* __restrict__ o_l, const float* __restrict__ po,
    const float* __restrict__ pl,
    const short* __restrict__ Wh, const short* __restrict__ Wl,
    const float* __restrict__ bc, float* __restrict__ C)
{
  const int lane = threadIdx.x & 63;
  const int w = threadIdx.x >> 6;
  const int q = lane >> 4, r = lane & 15;
  const int m0 = blockIdx.x * 64 + w * 16;
  const int n0 = blockIdx.y * 32;

  float bv0 = bc[n0 + r], bv1 = bc[n0 + 16 + r];
  float4v acc0 = {bv0, bv0, bv0, bv0};
  float4v acc1 = {bv1, bv1, bv1, bv1};

  #pragma unroll
  for (int ks = 0; ks < 4; ks++) {
    const int k0 = ks * 32 + q * 8;
    const int row = m0 + r;
    float av[8];
    if (ks < 2) {   // k0 in [0,64): o_l
      const float* ap = o_l + (size_t)row * 64 + k0;
      float4 f0 = ld4(ap), f1 = ld4(ap + 4);
      av[0]=f0.x; av[1]=f0.y; av[2]=f0.z; av[3]=f0.w;
      av[4]=f1.x; av[5]=f1.y; av[6]=f1.z; av[7]=f1.w;
    } else {        // k0 in [64,128): combine global-attn partials, head h
      const int h = (k0 - 64) >> 3;
      const size_t t = (size_t)row * 8 + h;
      const float* p0 = po + t * 8;
      const float* p1 = po + (131072 + t) * 8;
      const float* p2 = po + (262144 + t) * 8;
      float4 a0 = ld4(p0), a1 = ld4(p0 + 4);
      float4 b0 = ld4(p1), b1 = ld4(p1 + 4);
      float4 c0 = ld4(p2), c1 = ld4(p2 + 4);
      float inv = 1.f / (pl[t] + pl[131072 + t] + pl[262144 + t]);
      av[0]=(a0.x+b0.x+c0.x)*inv; av[1]=(a0.y+b0.y+c0.y)*inv;
      av[2]=(a0.z+b0.z+c0.z)*inv; av[3]=(a0.w+b0.w+c0.w)*inv;
      av[4]=(a1.x+b1.x+c1.x)*inv; av[5]=(a1.y+b1.y+c1.y)*inv;
      av[6]=(a1.z+b1.z+c1.z)*inv; av[7]=(a1.w+b1.w+c1.w)*inv;
    }
    short8 ah, al;
    #pragma unroll
    for (int i = 0; i < 8; i++) { short h, l; bsplit(av[i], h, l); ah[i]=h; al[i]=l; }
    short8 bh0 = *(const short8*)(Wh + (size_t)(n0 + r) * 128 + k0);
    short8 bl0 = *(const short8*)(Wl + (size_t)(n0 + r) * 128 + k0);
    short8 bh1 = *(const short8*)(Wh + (size_t)(n0 + 16 + r) * 128 + k0);
    short8 bl1 = *(const short8*)(Wl + (size_t)(n0 + 16 + r) * 128 + k0);
    acc0 = __builtin_amdgcn_mfma_f32_16x16x32_bf16(al, bh0, acc0, 0, 0, 0);
    acc0 = __builtin_amdgcn_mfma_f32_16x16x32_bf16(ah, bl0, acc0, 0, 0, 0);
    acc0 = __builtin_amdgcn_mfma_f32_16x16x32_bf16(ah, bh0, acc0, 0, 0, 0);
    acc1 = __builtin_amdgcn_mfma_f32_16x16x32_bf16(al, bh1, acc1, 0, 0, 0);
    acc1 = __builtin_amdgcn_mfma_f32_16x16x32_bf16(ah, bl1, acc1, 0, 0, 0);
    acc1 = __builtin_amdgcn_mfma_f32_16x16x32_bf16(ah, bh1, acc1, 0, 0, 0);
  }

  #pragma unroll
  for (int e = 0; e < 4; e++) {
    const int row = m0 + q * 4 + e;
    C[(size_t)row * 64 + n0 + r] = acc0[e];
    C[(size_t)row * 64 + n0 + 16 + r] = acc1[e];
  }
}

// ---------------- Pool scores: thread per row
__global__ __launch_bounds__(64) void score_kernel(
    const float* __restrict__ fused,
    const float* __restrict__ pw1, const float* __restrict__ pb1,
    const float* __restrict__ pw2, const float* __restrict__ pb2,
    float* __restrict__ scores)
{
  int r = blockIdx.x * 64 + threadIdx.x;   // 16384 rows
  const float* f = fused + (size_t)r * 64;
  float4 fr[16];
  #pragma unroll
  for (int e = 0; e < 16; e++) fr[e] = ld4(f + e * 4);
  float sc = pb2[0];
  #pragma unroll 4
  for (int j = 0; j < 32; j++) {
    const float* wr = pw1 + j * 64;   // loop-uniform -> s_load
    float hj = pb1[j];
    #pragma unroll
    for (int e = 0; e < 16; e++) {
      float4 w = ld4(wr + e * 4);
      hj += fr[e].x * w.x + fr[e].y * w.y + fr[e].z * w.z + fr[e].w * w.w;
    }
    sc += tanhf(hj) * pw2[j];
  }
  scores[r] = sc;
}

// ---------------- pool_a: per-batch max & 1/Z; zero d_out
__global__ __launch_bounds__(1024) void pool_a(
    const float* __restrict__ scores, float* __restrict__ msum,
    float* __restrict__ out)
{
  __shared__ float red[20];
  int b = blockIdx.x, t = threadIdx.x;
  float sc = scores[b * 1024 + t];
  float m = sc;
  #pragma unroll
  for (int off = 32; off > 0; off >>= 1)
    m = fmaxf(m, __shfl_xor(m, off, 64));
  int wid = t >> 6, lane = t & 63;
  if (lane == 0) red[wid] = m;
  __syncthreads();
  if (t == 0) {
    float mm = red[0];
    for (int g = 1; g < 16; g++) mm = fmaxf(mm, red[g]);
    red[16] = mm;
  }
  __syncthreads();
  m = red[16];
  float p = __expf(sc - m);
  float ss = p;
  #pragma unroll
  for (int off = 32; off > 0; off >>= 1)
    ss += __shfl_xor(ss, off, 64);
  if (lane == 0) red[wid] = ss;
  __syncthreads();
  if (t == 0) {
    float s2 = 0.f;
    for (int g = 0; g < 16; g++) s2 += red[g];
    msum[b] = m;
    msum[16 + b] = 1.f / s2;
  }
  if (t < 64) out[b * 64 + t] = 0.f;
}

// ---------------- pool_b: distributed weighted sum, atomicAdd into d_out
__global__ __launch_bounds__(256) void pool_b(
    const float* __restrict__ fused, const float* __restrict__ scores,
    const float* __restrict__ msum, float* __restrict__ out)
{
  __shared__ float pbuf[64];
  __shared__ float part[256];
  int b = blockIdx.x, c = blockIdx.y, t = threadIdx.x;
  float m = msum[b], invZ = msum[16 + b];
  if (t < 64) pbuf[t] = __expf(scores[b * 1024 + c * 64 + t] - m);
  __syncthreads();
  int e = t & 63, g = t >> 6;
  float acc = 0.f;
  for (int rr = g; rr < 64; rr += 4)
    acc = fmaf(pbuf[rr], fused[((size_t)(b * 1024 + c * 64 + rr)) * 64 + e], acc);
  part[t] = acc;
  __syncthreads();
  if (g == 0) {
    float tot = part[e] + part[64 + e] + part[128 + e] + part[192 + e];
    atomicAdd(&out[b * 64 + e], tot * invZ);
  }
}

extern "C" void kernel_launch(void* const* d_in, const int* in_sizes, int n_in,
                              void* d_out, int out_size, void* d_ws, size_t ws_size,
                              hipStream_t stream)
{
  const float* x          = (const float*)d_in[0];
  const float* proj_w     = (const float*)d_in[1];
  const float* proj_b     = (const float*)d_in[2];
  const float* loc_in_w   = (const float*)d_in[3];
  const float* loc_in_b   = (const float*)d_in[4];
  const float* loc_out_w  = (const float*)d_in[5];
  const float* loc_out_b  = (const float*)d_in[6];
  const float* glob_in_w  = (const float*)d_in[7];
  const float* glob_in_b  = (const float*)d_in[8];
  const float* glob_out_w = (const float*)d_in[9];
  const float* glob_out_b = (const float*)d_in[10];
  const float* fusion_w   = (const float*)d_in[11];
  const float* fusion_b   = (const float*)d_in[12];
  const float* pw1        = (const float*)d_in[13];
  const float* pb1        = (const float*)d_in[14];
  const float* pw2        = (const float*)d_in[15];
  const float* pb2        = (const float*)d_in[16];

  float* ws = (float*)d_ws;
  // Layout (float offsets):
  //  qkv_g   [0, 3145728)          qkv -> repack/gpart
  //  fused   [0, 1048576)          gemm_fuse -> score/pool (over dead qkv_g)
  //  scores  [2097152, 2113536), msum [2113536, 2113568)
  //  pl      [3145728, 3538944)    gpart -> gemm_fuse
  //  xph/xpl [3538944, 4587520)    proj -> qkv (shorts)
  //  qkv_l   [4587520, 7733248)    qkv -> local_attn
  //  po      [4587520, 7733248)    gpart -> gemm_fuse (over dead qkv_l)
  //  o_l     [7733248, 8781824)    local_attn -> gemm_fuse
  //  Kc      [8781824, 9132032), Vc [9132032, 9482240)
  //  bc      [9482240, 9482304)
  //  wb      shorts at 9482304 (112640 shorts)
  float* qkv_g = ws;
  float* fused = ws;
  float* scores= ws + 2097152;
  float* msum  = ws + 2113536;
  float* pl    = ws + 3145728;
  short* xph   = (short*)(ws + 3538944);
  short* xpl   = (short*)(ws + 4063232);
  float* qkv_l = ws + 4587520;
  float* po    = ws + 4587520;
  float* o_l   = ws + 7733248;
  float* Kc    = ws + 8781824;
  float* Vc    = ws + 9132032;
  float* bc    = ws + 9482240;
  short* wb    = (short*)(ws + 9482304);
  short* projh = wb;           short* projl = wb + 20480;
  short* linh  = wb + 40960;   short* linl  = wb + 53248;
  short* ginh  = wb + 65536;   short* ginl  = wb + 77824;
  short* wfh   = wb + 90112;   short* wfl   = wb + 98304;
  float* out   = (float*)d_out;

  dim3 blk(256);
  // 1: weight split + fused fusion weights + combined bias
  prep_w<<<208, blk, 0, stream>>>(proj_w, loc_in_w, glob_in_w, fusion_w,
                                  loc_out_w, glob_out_w, loc_out_b, glob_out_b,
                                  fusion_b, wb, bc);
  // 2: proj (prep_x fused in)  M=16384 K=310 N=64 -> xp bf16 hi/lo
  gemm_proj<<<dim3(256, 2), blk, 0, stream>>>(x, projh, projl, proj_b, xph, xpl);
  // 3: qkv both branches  K=64 N=192
  gemm_mfma<64><<<dim3(256, 6, 2), blk, 0, stream>>>(
      xph, xpl, linh, linl, ginh, ginl, loc_in_b, glob_in_b,
      qkv_l, qkv_g, 192);
  // 4: compressed K/V for sparse branch
  repack_kv<<<2736, blk, 0, stream>>>(qkv_g, Kc, Vc);
  // 5: local attention -> o_l
  local_attn<<<512, blk, 0, stream>>>(qkv_l, o_l);
  // 6: global attention partials (key-split x3, compressed K/V)
  global_attn_part<<<dim3(16, 8, 12), blk, 0, stream>>>(qkv_g, Kc, Vc, po, pl);
  // 7: fusion GEMM (combine + outproj + fusion folded)  K=128 N=64
  gemm_fuse<<<dim3(256, 2, 1), blk, 0, stream>>>(o_l, po, pl, wfh, wfl, bc, fused);
  // 8,9,10: pooling
  score_kernel<<<256, dim3(64), 0, stream>>>(fused, pw1, pb1, pw2, pb2, scores);
  pool_a<<<16, dim3(1024), 0, stream>>>(scores, msum, out);
  pool_b<<<dim3(16, 16), blk, 0, stream>>>(fused, scores, msum, out);
}

// Round 9
// 228.808 us; speedup vs baseline: 2.2012x; 1.0441x over previous
//
#include <hip/hip_runtime.h>

// Shapes: B=16, S=1024, E=64, H=8, d=8, INPUT_DIM=310
// local mask: |i-j|<=5 (11 keys); sparse mask: j%3==0 or i==j (342 keys + diag)
//
// GEMMs + global attention via mfma_f32_16x16x32_bf16, fp32 = hi+lo bf16 split.
// A-frag A[m=lane&15][k=quad*8+j]; B-frag B[n=lane&15][k=quad*8+j];
// C/D: col=lane&15, row=quad*4+reg.  (verified by R6-R8 passing results)
// Global attn: S=Q.Kc^T (K=8 pad 32), exp in C-layout, same-wave LDS transpose
// to A-frag, O += P.Vaug with ones-column producing l. diag_fix normalizes.

typedef __attribute__((ext_vector_type(8))) short short8;
typedef __attribute__((ext_vector_type(4))) float float4v;

#define INV_SQRT8 0.3535533905932738f

__device__ __forceinline__ float4 ld4(const float* p) { return *(const float4*)p; }

__device__ __forceinline__ float4 f4fma(float s, float4 w, float4 a) {
  a.x = fmaf(s, w.x, a.x); a.y = fmaf(s, w.y, a.y);
  a.z = fmaf(s, w.z, a.z); a.w = fmaf(s, w.w, a.w);
  return a;
}

// RNE fp32 -> (bf16 hi, bf16 lo); x == hi + lo to ~2^-16 relative.
__device__ __forceinline__ void bsplit(float x, short& h, short& l) {
  unsigned xb = __float_as_uint(x);
  unsigned hb = (xb + 0x7fffu + ((xb >> 16) & 1u)) & 0xffff0000u;
  h = (short)(hb >> 16);
  float lf = x - __uint_as_float(hb);
  unsigned lb = __float_as_uint(lf);
  l = (short)((lb + 0x7fffu + ((lb >> 16) & 1u)) >> 16);
}

// ---------------- prep_w: split weights into wb segments (shorts) + fused
// fusion weights + combined bias bc. projh 0 / projl 20480 (64x320 padded),
// linh 40960 / linl 53248, ginh 65536 / ginl 77824, wfh 90112 / wfl 98304.
__global__ __launch_bounds__(256) void prep_w(
    const float* __restrict__ pw, const float* __restrict__ liw,
    const float* __restrict__ giw, const float* __restrict__ fw,
    const float* __restrict__ low, const float* __restrict__ gow,
    const float* __restrict__ lob, const float* __restrict__ gob,
    const float* __restrict__ fb,
    short* __restrict__ wb, float* __restrict__ bc)
{
  unsigned idx = blockIdx.x * 256 + threadIdx.x;   // 53248 total
  float v; unsigned ho, lo_;
  if (idx < 20480u) {           // proj, padded K 310->320
    unsigned r = idx / 320u, k = idx - r * 320u;
    v = (k < 310u) ? pw[r * 310u + k] : 0.f;
    ho = 0u + idx; lo_ = 20480u + idx;
  } else if (idx < 32768u) {    // loc_in
    unsigned i = idx - 20480u; v = liw[i]; ho = 40960u + i; lo_ = 53248u + i;
  } else if (idx < 45056u) {    // glob_in
    unsigned i = idx - 32768u; v = giw[i]; ho = 65536u + i; lo_ = 77824u + i;
  } else {                      // fused fusion weight W12[n][k]
    unsigned i = idx - 45056u;
    unsigned n = i >> 7, k = i & 127u;
    float s = 0.f;
    if (k < 64u) {
      for (int e = 0; e < 64; e++) s += fw[n * 128 + e] * low[e * 64 + k];
    } else {
      for (int e = 0; e < 64; e++) s += fw[n * 128 + 64 + e] * gow[e * 64 + (k - 64u)];
    }
    v = s; ho = 90112u + i; lo_ = 98304u + i;
  }
  short h, l; bsplit(v, h, l);
  wb[ho] = h; wb[lo_] = l;
  if (idx < 64u) {
    float b = fb[idx];
    for (int e = 0; e < 64; e++)
      b += lob[e] * fw[idx * 128 + e] + gob[e] * fw[idx * 128 + 64 + e];
    bc[idx] = b;
  }
}

// ---------------- proj GEMM: xp = x @ proj_w^T + proj_b, fp32 A converted
// in-register. K=310 (W padded to 320). Writes bf16 hi/lo.
__global__ __launch_bounds__(256) void gemm_proj(
    const float* __restrict__ X,
    const short* __restrict__ Wh, const short* __restrict__ Wl,
    const float* __restrict__ bias,
    short* __restrict__ Ch, short* __restrict__ Cl)
{
  const int lane = threadIdx.x & 63;
  const int w = threadIdx.x >> 6;
  const int q = lane >> 4, r = lane & 15;
  const int m0 = blockIdx.x * 64 + w * 16;
  const int n0 = blockIdx.y * 32;

  float bv0 = bias[n0 + r], bv1 = bias[n0 + 16 + r];
  float4v acc0 = {bv0, bv0, bv0, bv0};
  float4v acc1 = {bv1, bv1, bv1, bv1};

  const float* arow = X + (size_t)(m0 + r) * 310;

  #pragma unroll
  for (int ks = 0; ks < 10; ks++) {
    const int k0 = ks * 32 + q * 8;
    float av[8];
    if (ks < 9) {
      const float* ap = arow + k0;
      #pragma unroll
      for (int t = 0; t < 4; t++) {
        float2 f = *(const float2*)(ap + t * 2);
        av[t*2] = f.x; av[t*2+1] = f.y;
      }
    } else {
      #pragma unroll
      for (int j = 0; j < 8; j++) {
        int kidx = k0 + j;
        av[j] = (kidx < 310) ? arow[kidx] : 0.f;
      }
    }
    short8 ah, al;
    #pragma unroll
    for (int i = 0; i < 8; i++) { short h, l; bsplit(av[i], h, l); ah[i]=h; al[i]=l; }
    short8 bh0 = *(const short8*)(Wh + (size_t)(n0 + r) * 320 + k0);
    short8 bl0 = *(const short8*)(Wl + (size_t)(n0 + r) * 320 + k0);
    short8 bh1 = *(const short8*)(Wh + (size_t)(n0 + 16 + r) * 320 + k0);
    short8 bl1 = *(const short8*)(Wl + (size_t)(n0 + 16 + r) * 320 + k0);
    acc0 = __builtin_amdgcn_mfma_f32_16x16x32_bf16(al, bh0, acc0, 0, 0, 0);
    acc0 = __builtin_amdgcn_mfma_f32_16x16x32_bf16(ah, bl0, acc0, 0, 0, 0);
    acc0 = __builtin_amdgcn_mfma_f32_16x16x32_bf16(ah, bh0, acc0, 0, 0, 0);
    acc1 = __builtin_amdgcn_mfma_f32_16x16x32_bf16(al, bh1, acc1, 0, 0, 0);
    acc1 = __builtin_amdgcn_mfma_f32_16x16x32_bf16(ah, bl1, acc1, 0, 0, 0);
    acc1 = __builtin_amdgcn_mfma_f32_16x16x32_bf16(ah, bh1, acc1, 0, 0, 0);
  }

  #pragma unroll
  for (int e = 0; e < 4; e++) {
    const int row = m0 + q * 4 + e;
    short h, l;
    bsplit(acc0[e], h, l);
    Ch[(size_t)row * 64 + n0 + r] = h; Cl[(size_t)row * 64 + n0 + r] = l;
    bsplit(acc1[e], h, l);
    Ch[(size_t)row * 64 + n0 + 16 + r] = h; Cl[(size_t)row * 64 + n0 + 16 + r] = l;
  }
}

// ---------------- MFMA GEMM (bf16 A): C = A.W^T + bias (fp32 C)
template<int KP>
__global__ __launch_bounds__(256) void gemm_mfma(
    const short* __restrict__ Ah, const short* __restrict__ Al,
    const short* __restrict__ Wh0, const short* __restrict__ Wl0,
    const short* __restrict__ Wh1, const short* __restrict__ Wl1,
    const float* __restrict__ bias0, const float* __restrict__ bias1,
    float* __restrict__ C0, float* __restrict__ C1, int ldc)
{
  const int z = blockIdx.z;
  const short* Wh = z ? Wh1 : Wh0;
  const short* Wl = z ? Wl1 : Wl0;
  const float* bias = z ? bias1 : bias0;
  float* C = z ? C1 : C0;

  const int lane = threadIdx.x & 63;
  const int w = threadIdx.x >> 6;
  const int q = lane >> 4, r = lane & 15;
  const int m0 = blockIdx.x * 64 + w * 16;
  const int n0 = blockIdx.y * 32;

  float bv0 = bias[n0 + r], bv1 = bias[n0 + 16 + r];
  float4v acc0 = {bv0, bv0, bv0, bv0};
  float4v acc1 = {bv1, bv1, bv1, bv1};

  #pragma unroll
  for (int ks = 0; ks < KP / 32; ks++) {
    const int k0 = ks * 32 + q * 8;
    short8 ah = *(const short8*)(Ah + (size_t)(m0 + r) * KP + k0);
    short8 al = *(const short8*)(Al + (size_t)(m0 + r) * KP + k0);
    short8 bh0 = *(const short8*)(Wh + (size_t)(n0 + r) * KP + k0);
    short8 bl0 = *(const short8*)(Wl + (size_t)(n0 + r) * KP + k0);
    short8 bh1 = *(const short8*)(Wh + (size_t)(n0 + 16 + r) * KP + k0);
    short8 bl1 = *(const short8*)(Wl + (size_t)(n0 + 16 + r) * KP + k0);
    acc0 = __builtin_amdgcn_mfma_f32_16x16x32_bf16(al, bh0, acc0, 0, 0, 0);
    acc0 = __builtin_amdgcn_mfma_f32_16x16x32_bf16(ah, bl0, acc0, 0, 0, 0);
    acc0 = __builtin_amdgcn_mfma_f32_16x16x32_bf16(ah, bh0, acc0, 0, 0, 0);
    acc1 = __builtin_amdgcn_mfma_f32_16x16x32_bf16(al, bh1, acc1, 0, 0, 0);
    acc1 = __builtin_amdgcn_mfma_f32_16x16x32_bf16(ah, bl1, acc1, 0, 0, 0);
    acc1 = __builtin_amdgcn_mfma_f32_16x16x32_bf16(ah, bh1, acc1, 0, 0, 0);
  }

  #pragma unroll
  for (int e = 0; e < 4; e++) {
    const int row = m0 + q * 4 + e;
    C[(size_t)row * ldc + n0 + r] = acc0[e];
    C[(size_t)row * ldc + n0 + 16 + r] = acc1[e];
  }
}

// ---------------- prep_kv: KH/KL[bh][352][8] bf16 (keys j=3*kk, pad 0) and
// VTh/VTl[bh][16][352] bf16 (rows 0..7 = V dims, row 8 = ones, rest 0).
__global__ __launch_bounds__(256) void prep_kv(
    const float* __restrict__ qkv,
    short* __restrict__ KH, short* __restrict__ KL,
    short* __restrict__ VTh, short* __restrict__ VTl)
{
  unsigned idx = blockIdx.x * 256 + threadIdx.x;   // 360448 + 720896 = 1081344
  if (idx < 360448u) {
    unsigned bh = idx / 2816u;             // 352*8
    unsigned rem = idx - bh * 2816u;
    unsigned kk = rem >> 3, d = rem & 7u;
    float v = (kk < 342u)
      ? qkv[((size_t)((bh >> 3) * 1024 + kk * 3)) * 192 + 64 + (bh & 7u) * 8 + d]
      : 0.f;
    short h, l; bsplit(v, h, l);
    KH[idx] = h; KL[idx] = l;
  } else {
    unsigned j = idx - 360448u;
    unsigned bh = j / 5632u;               // 16*352
    unsigned rem = j - bh * 5632u;
    unsigned n = rem / 352u, kk = rem - n * 352u;
    float v;
    if (n < 8u) {
      v = (kk < 342u)
        ? qkv[((size_t)((bh >> 3) * 1024 + kk * 3)) * 192 + 128 + (bh & 7u) * 8 + n]
        : 0.f;
    } else {
      v = (n == 8u) ? 1.f : 0.f;
    }
    short h, l; bsplit(v, h, l);
    VTh[j] = h; VTl[j] = l;
  }
}

// ---------------- MFMA global attention: grid (b=16, h=8, qtile=16), 256 thr.
// Wave w handles 16 queries. Writes UNNORMALIZED O to o_g and l to pl.
__global__ __launch_bounds__(256) void mfma_gattn(
    const float* __restrict__ qkv,
    const short* __restrict__ KH, const short* __restrict__ KL,
    const short* __restrict__ VTh, const short* __restrict__ VTl,
    float* __restrict__ o_g, float* __restrict__ pl)
{
  __shared__ short Pbuf[4][2][2][16][32];   // wave, parity, hi/lo, q, k
  const int b = blockIdx.x, h = blockIdx.y, qt = blockIdx.z;
  const int w = threadIdx.x >> 6, lane = threadIdx.x & 63;
  const int quad = lane >> 4, r = lane & 15;
  const int bh = b * 8 + h;
  const int m0 = qt * 64 + w * 16;

  const short8 z8 = {0,0,0,0,0,0,0,0};
  short8 qh = z8, ql = z8;
  if (quad == 0) {
    const float* qp = qkv + (size_t)(b * 1024 + m0 + r) * 192 + h * 8;
    #pragma unroll
    for (int d = 0; d < 8; d++) { short hh, ll; bsplit(qp[d], hh, ll); qh[d]=hh; ql[d]=ll; }
  }
  const short* kbase  = KH + (size_t)bh * 2816;
  const short* klbase = KL + (size_t)bh * 2816;
  const short* vhbase = VTh + ((size_t)bh * 16 + r) * 352;
  const short* vlbase = VTl + ((size_t)bh * 16 + r) * 352;

  float4v oacc = {0.f, 0.f, 0.f, 0.f};

  for (int kc = 0; kc < 11; kc++) {
    short8 kh0 = z8, kl0 = z8, kh1 = z8, kl1 = z8;
    if (quad == 0) {
      kh0 = *(const short8*)(kbase  + (size_t)(kc * 32 + r) * 8);
      kl0 = *(const short8*)(klbase + (size_t)(kc * 32 + r) * 8);
      kh1 = *(const short8*)(kbase  + (size_t)(kc * 32 + 16 + r) * 8);
      kl1 = *(const short8*)(klbase + (size_t)(kc * 32 + 16 + r) * 8);
    }
    float4v s0 = {0.f,0.f,0.f,0.f}, s1 = {0.f,0.f,0.f,0.f};
    s0 = __builtin_amdgcn_mfma_f32_16x16x32_bf16(qh, kl0, s0, 0, 0, 0);
    s0 = __builtin_amdgcn_mfma_f32_16x16x32_bf16(ql, kh0, s0, 0, 0, 0);
    s0 = __builtin_amdgcn_mfma_f32_16x16x32_bf16(qh, kh0, s0, 0, 0, 0);
    s1 = __builtin_amdgcn_mfma_f32_16x16x32_bf16(qh, kl1, s1, 0, 0, 0);
    s1 = __builtin_amdgcn_mfma_f32_16x16x32_bf16(ql, kh1, s1, 0, 0, 0);
    s1 = __builtin_amdgcn_mfma_f32_16x16x32_bf16(qh, kh1, s1, 0, 0, 0);

    const int par = kc & 1;
    const int key0 = kc * 32 + r, key1 = key0 + 16;
    #pragma unroll
    for (int e = 0; e < 4; e++) {
      float p0 = (key0 < 342) ? __expf(s0[e] * INV_SQRT8) : 0.f;
      float p1 = (key1 < 342) ? __expf(s1[e] * INV_SQRT8) : 0.f;
      short h0, l0, h1, l1; bsplit(p0, h0, l0); bsplit(p1, h1, l1);
      const int qloc = quad * 4 + e;
      Pbuf[w][par][0][qloc][r]      = h0;
      Pbuf[w][par][0][qloc][16 + r] = h1;
      Pbuf[w][par][1][qloc][r]      = l0;
      Pbuf[w][par][1][qloc][16 + r] = l1;
    }
    // Same-wave LDS transpose read (DS ops in-order per wave; no barrier).
    short8 pA = *(const short8*)&Pbuf[w][par][0][r][quad * 8];
    short8 pB = *(const short8*)&Pbuf[w][par][1][r][quad * 8];
    short8 vh = *(const short8*)(vhbase + kc * 32 + quad * 8);
    short8 vl = *(const short8*)(vlbase + kc * 32 + quad * 8);
    oacc = __builtin_amdgcn_mfma_f32_16x16x32_bf16(pA, vl, oacc, 0, 0, 0);
    oacc = __builtin_amdgcn_mfma_f32_16x16x32_bf16(pB, vh, oacc, 0, 0, 0);
    oacc = __builtin_amdgcn_mfma_f32_16x16x32_bf16(pA, vh, oacc, 0, 0, 0);
  }

  #pragma unroll
  for (int e = 0; e < 4; e++) {
    const int orow = b * 1024 + m0 + quad * 4 + e;
    if (r < 8)       o_g[(size_t)orow * 64 + h * 8 + r] = oacc[e];
    else if (r == 8) pl[(size_t)orow * 8 + h] = oacc[e];
  }
}

// ---------------- diag_fix: add diagonal key (i%3!=0) and normalize o_g.
__global__ __launch_bounds__(256) void diag_fix(
    const float* __restrict__ qkv, float* __restrict__ o_g,
    const float* __restrict__ pl)
{
  int t = blockIdx.x * 256 + threadIdx.x;   // 131072
  int h = t & 7, row = t >> 3;
  int i = row & 1023;
  float l = pl[t];
  float* op = o_g + (size_t)row * 64 + h * 8;
  float4 O0 = ld4(op), O1 = ld4(op + 4);
  if (i % 3 != 0) {
    const float* base = qkv + (size_t)row * 192;
    const float* qp = base + h * 8;
    const float* kp = base + 64 + h * 8;
    const float* vp = base + 128 + h * 8;
    float4 q0 = ld4(qp), q1 = ld4(qp + 4);
    float4 k0 = ld4(kp), k1 = ld4(kp + 4);
    float s = q0.x*k0.x + q0.y*k0.y + q0.z*k0.z + q0.w*k0.w
            + q1.x*k1.x + q1.y*k1.y + q1.z*k1.z + q1.w*k1.w;
    float p = __expf(s * INV_SQRT8);
    float4 v0 = ld4(vp), v1 = ld4(vp + 4);
    O0 = f4fma(p, v0, O0); O1 = f4fma(p, v1, O1);
    l += p;
  }
  float inv = 1.f / l;
  float4 r0, r1;
  r0.x = O0.x*inv; r0.y = O0.y*inv; r0.z = O0.z*inv; r0.w = O0.w*inv;
  r1.x = O1.x*inv; r1.y = O1.y*inv; r1.z = O1.z*inv; r1.w = O1.w*inv;
  *(float4*)op = r0;
  *(float4*)(op + 4) = r1;
}

// ---------------- Local attention: thread per (b,i,h), 11-key window.
__global__ __launch_bounds__(256) void local_attn(
    const float* __restrict__ qkv, float* __restrict__ o)
{
  int t = blockIdx.x * 256 + threadIdx.x;   // 131072
  int h = t & 7;
  int i = (t >> 3) & 1023;
  int b = t >> 13;
  const float* base = qkv + (size_t)b * 1024 * 192;
  const float* qp = base + (size_t)i * 192 + h * 8;
  float4 q0 = ld4(qp), q1 = ld4(qp + 4);
  float l = 0.f;
  float4 o0 = make_float4(0.f, 0.f, 0.f, 0.f);
  float4 o1 = make_float4(0.f, 0.f, 0.f, 0.f);
  int jlo = i - 5; if (jlo < 0) jlo = 0;
  int jhi = i + 5; if (jhi > 1023) jhi = 1023;
  for (int j = jlo; j <= jhi; j++) {
    const float* kp = base + (size_t)j * 192 + 64 + h * 8;
    float4 k0 = ld4(kp), k1 = ld4(kp + 4);
    float s = q0.x * k0.x + q0.y * k0.y + q0.z * k0.z + q0.w * k0.w
            + q1.x * k1.x + q1.y * k1.y + q1.z * k1.z + q1.w * k1.w;
    float p = __expf(s * INV_SQRT8);
    l += p;
    float4 v0 = ld4(kp + 64), v1 = ld4(kp + 68);
    o0 = f4fma(p, v0, o0);
    o1 = f4fma(p, v1, o1);
  }
  float inv = 1.f / l;
  float* op = o + (size_t)(b * 1024 + i) * 64 + h * 8;
  float4 r0, r1;
  r0.x = o0.x * inv; r0.y = o0.y * inv; r0.z = o0.z * inv; r0.w = o0.w * inv;
  r1.x = o1.x * inv; r1.y = o1.y * inv; r1.z = o1.z * inv; r1.w = o1.w * inv;
  *(float4*)op = r0;
  *(float4*)(op + 4) = r1;
}

// ---------------- Fusion GEMM: fused = [o_l | o_g] @ Wf^T + bc
__global__ __launch_bounds__(256) void gemm_fuse(
    const float* __restrict__ o_l, const float* __restrict__ o_g,
    const short* __restrict__ Wh, const short* __restrict__ Wl,
    const float* __restrict__ bc, float* __restrict__ C)
{
  const int lane = threadIdx.x & 63;
  const int w = threadIdx.x >> 6;
  const int q = lane >> 4, r = lane & 15;
  const int m0 = blockIdx.x * 64 + w * 16;
  const int n0 = blockIdx.y * 32;

  float bv0 = bc[n0 + r], bv1 = bc[n0 + 16 + r];
  float4v acc0 = {bv0, bv0, bv0, bv0};
  float4v acc1 = {bv1, bv1, bv1, bv1};

  #pragma unroll
  for (int ks = 0; ks < 4; ks++) {
    const int k0 = ks * 32 + q * 8;
    const int row = m0 + r;
    const float* src = (ks < 2) ? o_l : o_g;
    const int off = (ks < 2) ? k0 : (k0 - 64);
    const float* ap = src + (size_t)row * 64 + off;
    float4 f0 = ld4(ap), f1 = ld4(ap + 4);
    float av[8] = {f0.x, f0.y, f0.z, f0.w, f1.x, f1.y, f1.z, f1.w};
    short8 ah, al;
    #pragma unroll
    for (int i = 0; i < 8; i++) { short h, l; bsplit(av[i], h, l); ah[i]=h; al[i]=l; }
    short8 bh0 = *(const short8*)(Wh + (size_t)(n0 + r) * 128 + k0);
    short8 bl0 = *(const short8*)(Wl + (size_t)(n0 + r) * 128 + k0);
    short8 bh1 = *(const short8*)(Wh + (size_t)(n0 + 16 + r) * 128 + k0);
    short8 bl1 = *(const short8*)(Wl + (size_t)(n0 + 16 + r) * 128 + k0);
    acc0 = __builtin_amdgcn_mfma_f32_16x16x32_bf16(al, bh0, acc0, 0, 0, 0);
    acc0 = __builtin_amdgcn_mfma_f32_16x16x32_bf16(ah, bl0, acc0, 0, 0, 0);
    acc0 = __builtin_amdgcn_mfma_f32_16x16x32_bf16(ah, bh0, acc0, 0, 0, 0);
    acc1 = __builtin_amdgcn_mfma_f32_16x16x32_bf16(al, bh1, acc1, 0, 0, 0);
    acc1 = __builtin_amdgcn_mfma_f32_16x16x32_bf16(ah, bl1, acc1, 0, 0, 0);
    acc1 = __builtin_amdgcn_mfma_f32_16x16x32_bf16(ah, bh1, acc1, 0, 0, 0);
  }

  #pragma unroll
  for (int e = 0; e < 4; e++) {
    const int row = m0 + q * 4 + e;
    C[(size_t)row * 64 + n0 + r] = acc0[e];
    C[(size_t)row * 64 + n0 + 16 + r] = acc1[e];
  }
}

// ---------------- Pool scores: thread per row
__global__ __launch_bounds__(64) void score_kernel(
    const float* __restrict__ fused,
    const float* __restrict__ pw1, const float* __restrict__ pb1,
    const float* __restrict__ pw2, const float* __restrict__ pb2,
    float* __restrict__ scores)
{
  int r = blockIdx.x * 64 + threadIdx.x;   // 16384 rows
  const float* f = fused + (size_t)r * 64;
  float4 fr[16];
  #pragma unroll
  for (int e = 0; e < 16; e++) fr[e] = ld4(f + e * 4);
  float sc = pb2[0];
  #pragma unroll 4
  for (int j = 0; j < 32; j++) {
    const float* wr = pw1 + j * 64;   // loop-uniform -> s_load
    float hj = pb1[j];
    #pragma unroll
    for (int e = 0; e < 16; e++) {
      float4 w = ld4(wr + e * 4);
      hj += fr[e].x * w.x + fr[e].y * w.y + fr[e].z * w.z + fr[e].w * w.w;
    }
    sc += tanhf(hj) * pw2[j];
  }
  scores[r] = sc;
}

// ---------------- pool_a: per-batch max & 1/Z; zero d_out
__global__ __launch_bounds__(1024) void pool_a(
    const float* __restrict__ scores, float* __restrict__ msum,
    float* __restrict__ out)
{
  __shared__ float red[20];
  int b = blockIdx.x, t = threadIdx.x;
  float sc = scores[b * 1024 + t];
  float m = sc;
  #pragma unroll
  for (int off = 32; off > 0; off >>= 1)
    m = fmaxf(m, __shfl_xor(m, off, 64));
  int wid = t >> 6, lane = t & 63;
  if (lane == 0) red[wid] = m;
  __syncthreads();
  if (t == 0) {
    float mm = red[0];
    for (int g = 1; g < 16; g++) mm = fmaxf(mm, red[g]);
    red[16] = mm;
  }
  __syncthreads();
  m = red[16];
  float p = __expf(sc - m);
  float ss = p;
  #pragma unroll
  for (int off = 32; off > 0; off >>= 1)
    ss += __shfl_xor(ss, off, 64);
  if (lane == 0) red[wid] = ss;
  __syncthreads();
  if (t == 0) {
    float s2 = 0.f;
    for (int g = 0; g < 16; g++) s2 += red[g];
    msum[b] = m;
    msum[16 + b] = 1.f / s2;
  }
  if (t < 64) out[b * 64 + t] = 0.f;
}

// ---------------- pool_b: distributed weighted sum, atomicAdd into d_out
__global__ __launch_bounds__(256) void pool_b(
    const float* __restrict__ fused, const float* __restrict__ scores,
    const float* __restrict__ msum, float* __restrict__ out)
{
  __shared__ float pbuf[64];
  __shared__ float part[256];
  int b = blockIdx.x, c = blockIdx.y, t = threadIdx.x;
  float m = msum[b], invZ = msum[16 + b];
  if (t < 64) pbuf[t] = __expf(scores[b * 1024 + c * 64 + t] - m);
  __syncthreads();
  int e = t & 63, g = t >> 6;
  float acc = 0.f;
  for (int rr = g; rr < 64; rr += 4)
    acc = fmaf(pbuf[rr], fused[((size_t)(b * 1024 + c * 64 + rr)) * 64 + e], acc);
  part[t] = acc;
  __syncthreads();
  if (g == 0) {
    float tot = part[e] + part[64 + e] + part[128 + e] + part[192 + e];
    atomicAdd(&out[b * 64 + e], tot * invZ);
  }
}

extern "C" void kernel_launch(void* const* d_in, const int* in_sizes, int n_in,
                              void* d_out, int out_size, void* d_ws, size_t ws_size,
                              hipStream_t stream)
{
  const float* x          = (const float*)d_in[0];
  const float* proj_w     = (const float*)d_in[1];
  const float* proj_b     = (const float*)d_in[2];
  const float* loc_in_w   = (const float*)d_in[3];
  const float* loc_in_b   = (const float*)d_in[4];
  const float* loc_out_w  = (const float*)d_in[5];
  const float* loc_out_b  = (const float*)d_in[6];
  const float* glob_in_w  = (const float*)d_in[7];
  const float* glob_in_b  = (const float*)d_in[8];
  const float* glob_out_w = (const float*)d_in[9];
  const float* glob_out_b = (const float*)d_in[10];
  const float* fusion_w   = (const float*)d_in[11];
  const float* fusion_b   = (const float*)d_in[12];
  const float* pw1        = (const float*)d_in[13];
  const float* pb1        = (const float*)d_in[14];
  const float* pw2        = (const float*)d_in[15];
  const float* pb2        = (const float*)d_in[16];

  float* ws = (float*)d_ws;
  // Layout (float offsets):
  //  qkv_g   [0, 3145728)          qkv -> prep_kv/mfma_gattn/diag_fix
  //  fused   [0, 1048576)          gemm_fuse -> score/pool (after qkv_g dead)
  //  scores  [2097152, 2113536), msum [2113536, 2113568)
  //  xph/xpl shorts at 3538944     proj -> qkv
  //  qkv_l   [4587520, 7733248)    qkv -> local_attn
  //  o_l     [7733248, 8781824)    local_attn -> gemm_fuse
  //  o_g     [8781824, 9830400)    mfma_gattn -> diag_fix -> gemm_fuse
  //  pl      [9830400, 9961472)    mfma_gattn -> diag_fix
  //  KH/KL   shorts at 9961472 / 10141696 (360448 each)
  //  VTh/VTl shorts at 10321920 / 10682368 (720896 each)
  //  bc      [11042816, 11042880)
  //  wb      shorts at 11042880 (112640)
  float* qkv_g = ws;
  float* fused = ws;
  float* scores= ws + 2097152;
  float* msum  = ws + 2113536;
  short* xph   = (short*)(ws + 3538944);
  short* xpl   = (short*)(ws + 4063232);
  float* qkv_l = ws + 4587520;
  float* o_l   = ws + 7733248;
  float* o_g   = ws + 8781824;
  float* pl    = ws + 9830400;
  short* KH    = (short*)(ws + 9961472);
  short* KL    = (short*)(ws + 10141696);
  short* VTh   = (short*)(ws + 10321920);
  short* VTl   = (short*)(ws + 10682368);
  float* bc    = ws + 11042816;
  short* wb    = (short*)(ws + 11042880);
  short* projh = wb;           short* projl = wb + 20480;
  short* linh  = wb + 40960;   short* linl  = wb + 53248;
  short* ginh  = wb + 65536;   short* ginl  = wb + 77824;
  short* wfh   = wb + 90112;   short* wfl   = wb + 98304;
  float* out   = (float*)d_out;

  dim3 blk(256);
  // 1: weight split + fused fusion weights + combined bias
  prep_w<<<208, blk, 0, stream>>>(proj_w, loc_in_w, glob_in_w, fusion_w,
                                  loc_out_w, glob_out_w, loc_out_b, glob_out_b,
                                  fusion_b, wb, bc);
  // 2: proj  M=16384 K=310 N=64 -> xp bf16 hi/lo
  gemm_proj<<<dim3(256, 2), blk, 0, stream>>>(x, projh, projl, proj_b, xph, xpl);
  // 3: qkv both branches  K=64 N=192
  gemm_mfma<64><<<dim3(256, 6, 2), blk, 0, stream>>>(
      xph, xpl, linh, linl, ginh, ginl, loc_in_b, glob_in_b,
      qkv_l, qkv_g, 192);
  // 4: K/V prep for MFMA global attention
  prep_kv<<<4224, blk, 0, stream>>>(qkv_g, KH, KL, VTh, VTl);
  // 5: local attention -> o_l
  local_attn<<<512, blk, 0, stream>>>(qkv_l, o_l);
  // 6: MFMA global attention -> unnormalized o_g + pl
  mfma_gattn<<<dim3(16, 8, 16), blk, 0, stream>>>(qkv_g, KH, KL, VTh, VTl, o_g, pl);
  // 7: diagonal fix + normalize
  diag_fix<<<512, blk, 0, stream>>>(qkv_g, o_g, pl);
  // 8: fusion GEMM  K=128 N=64
  gemm_fuse<<<dim3(256, 2, 1), blk, 0, stream>>>(o_l, o_g, wfh, wfl, bc, fused);
  // 9,10,11: pooling
  score_kernel<<<256, dim3(64), 0, stream>>>(fused, pw1, pb1, pw2, pb2, scores);
  pool_a<<<16, dim3(1024), 0, stream>>>(scores, msum, out);
  pool_b<<<dim3(16, 16), blk, 0, stream>>>(fused, scores, msum, out);
}

// Round 10
// 216.412 us; speedup vs baseline: 2.3273x; 1.0573x over previous
//
#include <hip/hip_runtime.h>

// Shapes: B=16, S=1024, E=64, H=8, d=8, INPUT_DIM=310
// local mask: |i-j|<=5 (11 keys); sparse mask: j%3==0 or i==j (342 keys + diag)
//
// GEMMs + global attention via mfma_f32_16x16x32_bf16, fp32 = hi+lo bf16 split.
// A-frag A[m=lane&15][k=quad*8+j]; B-frag B[n=lane&15][k=quad*8+j];
// C/D: col=lane&15, row=quad*4+reg.  (verified R6-R9 passing, absmax 4.9e-4)
// Global attn: S=Q.Kc^T (K=8 pad 32), exp in C-layout, same-wave LDS transpose
// to A-frag, O += P.Vaug with ones-column producing l. Diagonal key + 1/l
// normalization folded into gemm_fuse's A-fragment load.
// Pooling: max-free softmax (scores bounded by tanh), atomic num/den.

typedef __attribute__((ext_vector_type(8))) short short8;
typedef __attribute__((ext_vector_type(4))) float float4v;

#define INV_SQRT8 0.3535533905932738f

__device__ __forceinline__ float4 ld4(const float* p) { return *(const float4*)p; }

__device__ __forceinline__ float4 f4fma(float s, float4 w, float4 a) {
  a.x = fmaf(s, w.x, a.x); a.y = fmaf(s, w.y, a.y);
  a.z = fmaf(s, w.z, a.z); a.w = fmaf(s, w.w, a.w);
  return a;
}

// RNE fp32 -> (bf16 hi, bf16 lo); x == hi + lo to ~2^-16 relative.
__device__ __forceinline__ void bsplit(float x, short& h, short& l) {
  unsigned xb = __float_as_uint(x);
  unsigned hb = (xb + 0x7fffu + ((xb >> 16) & 1u)) & 0xffff0000u;
  h = (short)(hb >> 16);
  float lf = x - __uint_as_float(hb);
  unsigned lb = __float_as_uint(lf);
  l = (short)((lb + 0x7fffu + ((lb >> 16) & 1u)) >> 16);
}

// ---------------- prep_w: split weights into wb segments (shorts) + fused
// fusion weights + combined bias bc + zero the pooling accumulators.
// projh 0 / projl 20480 (64x320 padded), linh 40960 / linl 53248,
// ginh 65536 / ginl 77824, wfh 90112 / wfl 98304.
__global__ __launch_bounds__(256) void prep_w(
    const float* __restrict__ pw, const float* __restrict__ liw,
    const float* __restrict__ giw, const float* __restrict__ fw,
    const float* __restrict__ low, const float* __restrict__ gow,
    const float* __restrict__ lob, const float* __restrict__ gob,
    const float* __restrict__ fb,
    short* __restrict__ wb, float* __restrict__ bc, float* __restrict__ numden)
{
  unsigned idx = blockIdx.x * 256 + threadIdx.x;   // 53248 total
  float v; unsigned ho, lo_;
  if (idx < 20480u) {           // proj, padded K 310->320
    unsigned r = idx / 320u, k = idx - r * 320u;
    v = (k < 310u) ? pw[r * 310u + k] : 0.f;
    ho = 0u + idx; lo_ = 20480u + idx;
  } else if (idx < 32768u) {    // loc_in
    unsigned i = idx - 20480u; v = liw[i]; ho = 40960u + i; lo_ = 53248u + i;
  } else if (idx < 45056u) {    // glob_in
    unsigned i = idx - 32768u; v = giw[i]; ho = 65536u + i; lo_ = 77824u + i;
  } else {                      // fused fusion weight W12[n][k]
    unsigned i = idx - 45056u;
    unsigned n = i >> 7, k = i & 127u;
    float s = 0.f;
    if (k < 64u) {
      for (int e = 0; e < 64; e++) s += fw[n * 128 + e] * low[e * 64 + k];
    } else {
      for (int e = 0; e < 64; e++) s += fw[n * 128 + 64 + e] * gow[e * 64 + (k - 64u)];
    }
    v = s; ho = 90112u + i; lo_ = 98304u + i;
  }
  short h, l; bsplit(v, h, l);
  wb[ho] = h; wb[lo_] = l;
  if (idx < 64u) {
    float b = fb[idx];
    for (int e = 0; e < 64; e++)
      b += lob[e] * fw[idx * 128 + e] + gob[e] * fw[idx * 128 + 64 + e];
    bc[idx] = b;
  }
  if (idx < 1040u) numden[idx] = 0.f;   // num[1024] + den[16]
}

// ---------------- proj GEMM: xp = x @ proj_w^T + proj_b, fp32 A converted
// in-register. K=310 (W padded to 320). Writes bf16 hi/lo.
__global__ __launch_bounds__(256) void gemm_proj(
    const float* __restrict__ X,
    const short* __restrict__ Wh, const short* __restrict__ Wl,
    const float* __restrict__ bias,
    short* __restrict__ Ch, short* __restrict__ Cl)
{
  const int lane = threadIdx.x & 63;
  const int w = threadIdx.x >> 6;
  const int q = lane >> 4, r = lane & 15;
  const int m0 = blockIdx.x * 64 + w * 16;
  const int n0 = blockIdx.y * 32;

  float bv0 = bias[n0 + r], bv1 = bias[n0 + 16 + r];
  float4v acc0 = {bv0, bv0, bv0, bv0};
  float4v acc1 = {bv1, bv1, bv1, bv1};

  const float* arow = X + (size_t)(m0 + r) * 310;

  #pragma unroll
  for (int ks = 0; ks < 10; ks++) {
    const int k0 = ks * 32 + q * 8;
    float av[8];
    if (ks < 9) {
      const float* ap = arow + k0;
      #pragma unroll
      for (int t = 0; t < 4; t++) {
        float2 f = *(const float2*)(ap + t * 2);
        av[t*2] = f.x; av[t*2+1] = f.y;
      }
    } else {
      #pragma unroll
      for (int j = 0; j < 8; j++) {
        int kidx = k0 + j;
        av[j] = (kidx < 310) ? arow[kidx] : 0.f;
      }
    }
    short8 ah, al;
    #pragma unroll
    for (int i = 0; i < 8; i++) { short h, l; bsplit(av[i], h, l); ah[i]=h; al[i]=l; }
    short8 bh0 = *(const short8*)(Wh + (size_t)(n0 + r) * 320 + k0);
    short8 bl0 = *(const short8*)(Wl + (size_t)(n0 + r) * 320 + k0);
    short8 bh1 = *(const short8*)(Wh + (size_t)(n0 + 16 + r) * 320 + k0);
    short8 bl1 = *(const short8*)(Wl + (size_t)(n0 + 16 + r) * 320 + k0);
    acc0 = __builtin_amdgcn_mfma_f32_16x16x32_bf16(al, bh0, acc0, 0, 0, 0);
    acc0 = __builtin_amdgcn_mfma_f32_16x16x32_bf16(ah, bl0, acc0, 0, 0, 0);
    acc0 = __builtin_amdgcn_mfma_f32_16x16x32_bf16(ah, bh0, acc0, 0, 0, 0);
    acc1 = __builtin_amdgcn_mfma_f32_16x16x32_bf16(al, bh1, acc1, 0, 0, 0);
    acc1 = __builtin_amdgcn_mfma_f32_16x16x32_bf16(ah, bl1, acc1, 0, 0, 0);
    acc1 = __builtin_amdgcn_mfma_f32_16x16x32_bf16(ah, bh1, acc1, 0, 0, 0);
  }

  #pragma unroll
  for (int e = 0; e < 4; e++) {
    const int row = m0 + q * 4 + e;
    short h, l;
    bsplit(acc0[e], h, l);
    Ch[(size_t)row * 64 + n0 + r] = h; Cl[(size_t)row * 64 + n0 + r] = l;
    bsplit(acc1[e], h, l);
    Ch[(size_t)row * 64 + n0 + 16 + r] = h; Cl[(size_t)row * 64 + n0 + 16 + r] = l;
  }
}

// ---------------- MFMA GEMM (bf16 A): C = A.W^T + bias (fp32 C)
template<int KP>
__global__ __launch_bounds__(256) void gemm_mfma(
    const short* __restrict__ Ah, const short* __restrict__ Al,
    const short* __restrict__ Wh0, const short* __restrict__ Wl0,
    const short* __restrict__ Wh1, const short* __restrict__ Wl1,
    const float* __restrict__ bias0, const float* __restrict__ bias1,
    float* __restrict__ C0, float* __restrict__ C1, int ldc)
{
  const int z = blockIdx.z;
  const short* Wh = z ? Wh1 : Wh0;
  const short* Wl = z ? Wl1 : Wl0;
  const float* bias = z ? bias1 : bias0;
  float* C = z ? C1 : C0;

  const int lane = threadIdx.x & 63;
  const int w = threadIdx.x >> 6;
  const int q = lane >> 4, r = lane & 15;
  const int m0 = blockIdx.x * 64 + w * 16;
  const int n0 = blockIdx.y * 32;

  float bv0 = bias[n0 + r], bv1 = bias[n0 + 16 + r];
  float4v acc0 = {bv0, bv0, bv0, bv0};
  float4v acc1 = {bv1, bv1, bv1, bv1};

  #pragma unroll
  for (int ks = 0; ks < KP / 32; ks++) {
    const int k0 = ks * 32 + q * 8;
    short8 ah = *(const short8*)(Ah + (size_t)(m0 + r) * KP + k0);
    short8 al = *(const short8*)(Al + (size_t)(m0 + r) * KP + k0);
    short8 bh0 = *(const short8*)(Wh + (size_t)(n0 + r) * KP + k0);
    short8 bl0 = *(const short8*)(Wl + (size_t)(n0 + r) * KP + k0);
    short8 bh1 = *(const short8*)(Wh + (size_t)(n0 + 16 + r) * KP + k0);
    short8 bl1 = *(const short8*)(Wl + (size_t)(n0 + 16 + r) * KP + k0);
    acc0 = __builtin_amdgcn_mfma_f32_16x16x32_bf16(al, bh0, acc0, 0, 0, 0);
    acc0 = __builtin_amdgcn_mfma_f32_16x16x32_bf16(ah, bl0, acc0, 0, 0, 0);
    acc0 = __builtin_amdgcn_mfma_f32_16x16x32_bf16(ah, bh0, acc0, 0, 0, 0);
    acc1 = __builtin_amdgcn_mfma_f32_16x16x32_bf16(al, bh1, acc1, 0, 0, 0);
    acc1 = __builtin_amdgcn_mfma_f32_16x16x32_bf16(ah, bl1, acc1, 0, 0, 0);
    acc1 = __builtin_amdgcn_mfma_f32_16x16x32_bf16(ah, bh1, acc1, 0, 0, 0);
  }

  #pragma unroll
  for (int e = 0; e < 4; e++) {
    const int row = m0 + q * 4 + e;
    C[(size_t)row * ldc + n0 + r] = acc0[e];
    C[(size_t)row * ldc + n0 + 16 + r] = acc1[e];
  }
}

// ---------------- prep_kv: KH/KL[bh][352][8] bf16 (keys j=3*kk, pad 0) and
// VTh/VTl[bh][16][352] bf16 (rows 0..7 = V dims, row 8 = ones, rest 0).
__global__ __launch_bounds__(256) void prep_kv(
    const float* __restrict__ qkv,
    short* __restrict__ KH, short* __restrict__ KL,
    short* __restrict__ VTh, short* __restrict__ VTl)
{
  unsigned idx = blockIdx.x * 256 + threadIdx.x;   // 360448 + 720896 = 1081344
  if (idx < 360448u) {
    unsigned bh = idx / 2816u;             // 352*8
    unsigned rem = idx - bh * 2816u;
    unsigned kk = rem >> 3, d = rem & 7u;
    float v = (kk < 342u)
      ? qkv[((size_t)((bh >> 3) * 1024 + kk * 3)) * 192 + 64 + (bh & 7u) * 8 + d]
      : 0.f;
    short h, l; bsplit(v, h, l);
    KH[idx] = h; KL[idx] = l;
  } else {
    unsigned j = idx - 360448u;
    unsigned bh = j / 5632u;               // 16*352
    unsigned rem = j - bh * 5632u;
    unsigned n = rem / 352u, kk = rem - n * 352u;
    float v;
    if (n < 8u) {
      v = (kk < 342u)
        ? qkv[((size_t)((bh >> 3) * 1024 + kk * 3)) * 192 + 128 + (bh & 7u) * 8 + n]
        : 0.f;
    } else {
      v = (n == 8u) ? 1.f : 0.f;
    }
    short h, l; bsplit(v, h, l);
    VTh[j] = h; VTl[j] = l;
  }
}

// ---------------- MFMA global attention: grid (b=16, h=8, qtile=16), 256 thr.
// Wave w handles 16 queries. Writes UNNORMALIZED O to o_g and l to pl.
__global__ __launch_bounds__(256) void mfma_gattn(
    const float* __restrict__ qkv,
    const short* __restrict__ KH, const short* __restrict__ KL,
    const short* __restrict__ VTh, const short* __restrict__ VTl,
    float* __restrict__ o_g, float* __restrict__ pl)
{
  __shared__ short Pbuf[4][2][2][16][32];   // wave, parity, hi/lo, q, k
  const int b = blockIdx.x, h = blockIdx.y, qt = blockIdx.z;
  const int w = threadIdx.x >> 6, lane = threadIdx.x & 63;
  const int quad = lane >> 4, r = lane & 15;
  const int bh = b * 8 + h;
  const int m0 = qt * 64 + w * 16;

  const short8 z8 = {0,0,0,0,0,0,0,0};
  short8 qh = z8, ql = z8;
  if (quad == 0) {
    const float* qp = qkv + (size_t)(b * 1024 + m0 + r) * 192 + h * 8;
    #pragma unroll
    for (int d = 0; d < 8; d++) { short hh, ll; bsplit(qp[d], hh, ll); qh[d]=hh; ql[d]=ll; }
  }
  const short* kbase  = KH + (size_t)bh * 2816;
  const short* klbase = KL + (size_t)bh * 2816;
  const short* vhbase = VTh + ((size_t)bh * 16 + r) * 352;
  const short* vlbase = VTl + ((size_t)bh * 16 + r) * 352;

  float4v oacc = {0.f, 0.f, 0.f, 0.f};

  for (int kc = 0; kc < 11; kc++) {
    short8 kh0 = z8, kl0 = z8, kh1 = z8, kl1 = z8;
    if (quad == 0) {
      kh0 = *(const short8*)(kbase  + (size_t)(kc * 32 + r) * 8);
      kl0 = *(const short8*)(klbase + (size_t)(kc * 32 + r) * 8);
      kh1 = *(const short8*)(kbase  + (size_t)(kc * 32 + 16 + r) * 8);
      kl1 = *(const short8*)(klbase + (size_t)(kc * 32 + 16 + r) * 8);
    }
    float4v s0 = {0.f,0.f,0.f,0.f}, s1 = {0.f,0.f,0.f,0.f};
    s0 = __builtin_amdgcn_mfma_f32_16x16x32_bf16(qh, kl0, s0, 0, 0, 0);
    s0 = __builtin_amdgcn_mfma_f32_16x16x32_bf16(ql, kh0, s0, 0, 0, 0);
    s0 = __builtin_amdgcn_mfma_f32_16x16x32_bf16(qh, kh0, s0, 0, 0, 0);
    s1 = __builtin_amdgcn_mfma_f32_16x16x32_bf16(qh, kl1, s1, 0, 0, 0);
    s1 = __builtin_amdgcn_mfma_f32_16x16x32_bf16(ql, kh1, s1, 0, 0, 0);
    s1 = __builtin_amdgcn_mfma_f32_16x16x32_bf16(qh, kh1, s1, 0, 0, 0);

    const int par = kc & 1;
    const int key0 = kc * 32 + r, key1 = key0 + 16;
    #pragma unroll
    for (int e = 0; e < 4; e++) {
      float p0 = (key0 < 342) ? __expf(s0[e] * INV_SQRT8) : 0.f;
      float p1 = (key1 < 342) ? __expf(s1[e] * INV_SQRT8) : 0.f;
      short h0, l0, h1, l1; bsplit(p0, h0, l0); bsplit(p1, h1, l1);
      const int qloc = quad * 4 + e;
      Pbuf[w][par][0][qloc][r]      = h0;
      Pbuf[w][par][0][qloc][16 + r] = h1;
      Pbuf[w][par][1][qloc][r]      = l0;
      Pbuf[w][par][1][qloc][16 + r] = l1;
    }
    // Same-wave LDS transpose read (DS ops in-order per wave; no barrier).
    short8 pA = *(const short8*)&Pbuf[w][par][0][r][quad * 8];
    short8 pB = *(const short8*)&Pbuf[w][par][1][r][quad * 8];
    short8 vh = *(const short8*)(vhbase + kc * 32 + quad * 8);
    short8 vl = *(const short8*)(vlbase + kc * 32 + quad * 8);
    oacc = __builtin_amdgcn_mfma_f32_16x16x32_bf16(pA, vl, oacc, 0, 0, 0);
    oacc = __builtin_amdgcn_mfma_f32_16x16x32_bf16(pB, vh, oacc, 0, 0, 0);
    oacc = __builtin_amdgcn_mfma_f32_16x16x32_bf16(pA, vh, oacc, 0, 0, 0);
  }

  #pragma unroll
  for (int e = 0; e < 4; e++) {
    const int orow = b * 1024 + m0 + quad * 4 + e;
    if (r < 8)       o_g[(size_t)orow * 64 + h * 8 + r] = oacc[e];
    else if (r == 8) pl[(size_t)orow * 8 + h] = oacc[e];
  }
}

// ---------------- Local attention: thread per (b,i,h), 11-key window.
__global__ __launch_bounds__(256) void local_attn(
    const float* __restrict__ qkv, float* __restrict__ o)
{
  int t = blockIdx.x * 256 + threadIdx.x;   // 131072
  int h = t & 7;
  int i = (t >> 3) & 1023;
  int b = t >> 13;
  const float* base = qkv + (size_t)b * 1024 * 192;
  const float* qp = base + (size_t)i * 192 + h * 8;
  float4 q0 = ld4(qp), q1 = ld4(qp + 4);
  float l = 0.f;
  float4 o0 = make_float4(0.f, 0.f, 0.f, 0.f);
  float4 o1 = make_float4(0.f, 0.f, 0.f, 0.f);
  int jlo = i - 5; if (jlo < 0) jlo = 0;
  int jhi = i + 5; if (jhi > 1023) jhi = 1023;
  for (int j = jlo; j <= jhi; j++) {
    const float* kp = base + (size_t)j * 192 + 64 + h * 8;
    float4 k0 = ld4(kp), k1 = ld4(kp + 4);
    float s = q0.x * k0.x + q0.y * k0.y + q0.z * k0.z + q0.w * k0.w
            + q1.x * k1.x + q1.y * k1.y + q1.z * k1.z + q1.w * k1.w;
    float p = __expf(s * INV_SQRT8);
    l += p;
    float4 v0 = ld4(kp + 64), v1 = ld4(kp + 68);
    o0 = f4fma(p, v0, o0);
    o1 = f4fma(p, v1, o1);
  }
  float inv = 1.f / l;
  float* op = o + (size_t)(b * 1024 + i) * 64 + h * 8;
  float4 r0, r1;
  r0.x = o0.x * inv; r0.y = o0.y * inv; r0.z = o0.z * inv; r0.w = o0.w * inv;
  r1.x = o1.x * inv; r1.y = o1.y * inv; r1.z = o1.z * inv; r1.w = o1.w * inv;
  *(float4*)op = r0;
  *(float4*)(op + 4) = r1;
}

// ---------------- Fusion GEMM: fused = [o_l | norm(o_g)+diag] @ Wf^T + bc
// ks>=2: A-frag 8-group == one (row, head) of o_g -> fold diagonal key add
// (i%3!=0, from qkv_g) and 1/l normalization into the fragment load.
__global__ __launch_bounds__(256) void gemm_fuse(
    const float* __restrict__ o_l, const float* __restrict__ o_g,
    const float* __restrict__ pl, const float* __restrict__ qkv_g,
    const short* __restrict__ Wh, const short* __restrict__ Wl,
    const float* __restrict__ bc, float* __restrict__ C)
{
  const int lane = threadIdx.x & 63;
  const int w = threadIdx.x >> 6;
  const int q = lane >> 4, r = lane & 15;
  const int m0 = blockIdx.x * 64 + w * 16;
  const int n0 = blockIdx.y * 32;

  float bv0 = bc[n0 + r], bv1 = bc[n0 + 16 + r];
  float4v acc0 = {bv0, bv0, bv0, bv0};
  float4v acc1 = {bv1, bv1, bv1, bv1};

  #pragma unroll
  for (int ks = 0; ks < 4; ks++) {
    const int k0 = ks * 32 + q * 8;
    const int row = m0 + r;
    float av[8];
    if (ks < 2) {   // local branch, already normalized
      const float* ap = o_l + (size_t)row * 64 + k0;
      float4 f0 = ld4(ap), f1 = ld4(ap + 4);
      av[0]=f0.x; av[1]=f0.y; av[2]=f0.z; av[3]=f0.w;
      av[4]=f1.x; av[5]=f1.y; av[6]=f1.z; av[7]=f1.w;
    } else {        // global branch: unnormalized O + diag + normalize
      const int off = k0 - 64;         // head h = off>>3, single head per group
      const int h = off >> 3;
      const float* op = o_g + (size_t)row * 64 + off;
      float4 O0 = ld4(op), O1 = ld4(op + 4);
      float l = pl[(size_t)row * 8 + h];
      const int i = row & 1023;
      if (i % 3 != 0) {
        const float* base = qkv_g + (size_t)row * 192;
        const float* qp = base + h * 8;
        const float* kp = base + 64 + h * 8;
        const float* vp = base + 128 + h * 8;
        float4 q0 = ld4(qp), q1 = ld4(qp + 4);
        float4 k0v = ld4(kp), k1v = ld4(kp + 4);
        float s = q0.x*k0v.x + q0.y*k0v.y + q0.z*k0v.z + q0.w*k0v.w
                + q1.x*k1v.x + q1.y*k1v.y + q1.z*k1v.z + q1.w*k1v.w;
        float p = __expf(s * INV_SQRT8);
        float4 v0 = ld4(vp), v1 = ld4(vp + 4);
        O0 = f4fma(p, v0, O0); O1 = f4fma(p, v1, O1);
        l += p;
      }
      float inv = 1.f / l;
      av[0]=O0.x*inv; av[1]=O0.y*inv; av[2]=O0.z*inv; av[3]=O0.w*inv;
      av[4]=O1.x*inv; av[5]=O1.y*inv; av[6]=O1.z*inv; av[7]=O1.w*inv;
    }
    short8 ah, al;
    #pragma unroll
    for (int i2 = 0; i2 < 8; i2++) { short h2, l2; bsplit(av[i2], h2, l2); ah[i2]=h2; al[i2]=l2; }
    short8 bh0 = *(const short8*)(Wh + (size_t)(n0 + r) * 128 + k0);
    short8 bl0 = *(const short8*)(Wl + (size_t)(n0 + r) * 128 + k0);
    short8 bh1 = *(const short8*)(Wh + (size_t)(n0 + 16 + r) * 128 + k0);
    short8 bl1 = *(const short8*)(Wl + (size_t)(n0 + 16 + r) * 128 + k0);
    acc0 = __builtin_amdgcn_mfma_f32_16x16x32_bf16(al, bh0, acc0, 0, 0, 0);
    acc0 = __builtin_amdgcn_mfma_f32_16x16x32_bf16(ah, bl0, acc0, 0, 0, 0);
    acc0 = __builtin_amdgcn_mfma_f32_16x16x32_bf16(ah, bh0, acc0, 0, 0, 0);
    acc1 = __builtin_amdgcn_mfma_f32_16x16x32_bf16(al, bh1, acc1, 0, 0, 0);
    acc1 = __builtin_amdgcn_mfma_f32_16x16x32_bf16(ah, bl1, acc1, 0, 0, 0);
    acc1 = __builtin_amdgcn_mfma_f32_16x16x32_bf16(ah, bh1, acc1, 0, 0, 0);
  }

  #pragma unroll
  for (int e = 0; e < 4; e++) {
    const int row = m0 + q * 4 + e;
    C[(size_t)row * 64 + n0 + r] = acc0[e];
    C[(size_t)row * 64 + n0 + 16 + r] = acc1[e];
  }
}

// ---------------- score_pool: per-row score, max-free softmax weight, and
// atomic accumulation of num[b][e] = sum p*f, den[b] = sum p.
// |score| <= sum|pw2| + |pb2| ~ 5.8 (tanh-bounded) -> exp safe without max.
__global__ __launch_bounds__(64) void score_pool(
    const float* __restrict__ fused,
    const float* __restrict__ pw1, const float* __restrict__ pb1,
    const float* __restrict__ pw2, const float* __restrict__ pb2,
    float* __restrict__ num, float* __restrict__ den)
{
  __shared__ float Ls[64][65];
  const int b = blockIdx.x, c = blockIdx.y, t = threadIdx.x;
  const int row = b * 1024 + c * 64 + t;
  const float* f = fused + (size_t)row * 64;
  float4 fr[16];
  #pragma unroll
  for (int e = 0; e < 16; e++) fr[e] = ld4(f + e * 4);
  float sc = pb2[0];
  #pragma unroll 4
  for (int j = 0; j < 32; j++) {
    const float* wr = pw1 + j * 64;   // loop-uniform -> s_load
    float hj = pb1[j];
    #pragma unroll
    for (int e = 0; e < 16; e++) {
      float4 w = ld4(wr + e * 4);
      hj += fr[e].x * w.x + fr[e].y * w.y + fr[e].z * w.z + fr[e].w * w.w;
    }
    sc += tanhf(hj) * pw2[j];
  }
  float p = __expf(sc);
  #pragma unroll
  for (int e = 0; e < 16; e++) {
    Ls[t][e*4+0] = p * fr[e].x; Ls[t][e*4+1] = p * fr[e].y;
    Ls[t][e*4+2] = p * fr[e].z; Ls[t][e*4+3] = p * fr[e].w;
  }
  // single wave: DS ops in order, no barrier needed
  float colsum = 0.f;
  #pragma unroll 8
  for (int s = 0; s < 64; s++) colsum += Ls[s][t];
  atomicAdd(&num[b * 64 + t], colsum);
  float ps = p;
  #pragma unroll
  for (int off = 32; off > 0; off >>= 1)
    ps += __shfl_xor(ps, off, 64);
  if (t == 0) atomicAdd(&den[b], ps);
}

// ---------------- finalize: out = num/den
__global__ __launch_bounds__(1024) void finalize(
    const float* __restrict__ num, const float* __restrict__ den,
    float* __restrict__ out)
{
  int t = threadIdx.x;   // 1024 = 16*64
  out[t] = num[t] / den[t >> 6];
}

extern "C" void kernel_launch(void* const* d_in, const int* in_sizes, int n_in,
                              void* d_out, int out_size, void* d_ws, size_t ws_size,
                              hipStream_t stream)
{
  const float* x          = (const float*)d_in[0];
  const float* proj_w     = (const float*)d_in[1];
  const float* proj_b     = (const float*)d_in[2];
  const float* loc_in_w   = (const float*)d_in[3];
  const float* loc_in_b   = (const float*)d_in[4];
  const float* loc_out_w  = (const float*)d_in[5];
  const float* loc_out_b  = (const float*)d_in[6];
  const float* glob_in_w  = (const float*)d_in[7];
  const float* glob_in_b  = (const float*)d_in[8];
  const float* glob_out_w = (const float*)d_in[9];
  const float* glob_out_b = (const float*)d_in[10];
  const float* fusion_w   = (const float*)d_in[11];
  const float* fusion_b   = (const float*)d_in[12];
  const float* pw1        = (const float*)d_in[13];
  const float* pb1        = (const float*)d_in[14];
  const float* pw2        = (const float*)d_in[15];
  const float* pb2        = (const float*)d_in[16];

  float* ws = (float*)d_ws;
  // Layout (float offsets):
  //  qkv_g    [0, 3145728)         qkv -> prep_kv/mfma_gattn/gemm_fuse(diag)
  //  numden   [2097152... NO - inside qkv_g! place at 11042816+ area below.
  //  xph/xpl  shorts at 3538944    proj -> qkv; dead after launch 3
  //  fused    [3538944, 4587520)   gemm_fuse -> score_pool (over dead xp)
  //  qkv_l    [4587520, 7733248)   qkv -> local_attn
  //  o_l      [7733248, 8781824)   local_attn -> gemm_fuse
  //  o_g      [8781824, 9830400)   mfma_gattn -> gemm_fuse (unnormalized)
  //  pl       [9830400, 9961472)   mfma_gattn -> gemm_fuse
  //  KH/KL    shorts at 9961472 / 10141696 (360448 each)
  //  VTh/VTl  shorts at 10321920 / 10682368 (720896 each)
  //  bc       [11042816, 11042880)
  //  numden   [11042880, 11043920)  num[1024], den[16]
  //  wb       shorts at 11043920 (112640)
  float* qkv_g = ws;
  short* xph   = (short*)(ws + 3538944);
  short* xpl   = (short*)(ws + 4063232);
  float* fused = ws + 3538944;
  float* qkv_l = ws + 4587520;
  float* o_l   = ws + 7733248;
  float* o_g   = ws + 8781824;
  float* pl    = ws + 9830400;
  short* KH    = (short*)(ws + 9961472);
  short* KL    = (short*)(ws + 10141696);
  short* VTh   = (short*)(ws + 10321920);
  short* VTl   = (short*)(ws + 10682368);
  float* bc    = ws + 11042816;
  float* numden= ws + 11042880;
  float* num   = numden;
  float* den   = numden + 1024;
  short* wb    = (short*)(ws + 11043920);
  short* projh = wb;           short* projl = wb + 20480;
  short* linh  = wb + 40960;   short* linl  = wb + 53248;
  short* ginh  = wb + 65536;   short* ginl  = wb + 77824;
  short* wfh   = wb + 90112;   short* wfl   = wb + 98304;
  float* out   = (float*)d_out;

  dim3 blk(256);
  // 1: weight split + fused fusion weights + combined bias + zero num/den
  prep_w<<<208, blk, 0, stream>>>(proj_w, loc_in_w, glob_in_w, fusion_w,
                                  loc_out_w, glob_out_w, loc_out_b, glob_out_b,
                                  fusion_b, wb, bc, numden);
  // 2: proj  M=16384 K=310 N=64 -> xp bf16 hi/lo
  gemm_proj<<<dim3(256, 2), blk, 0, stream>>>(x, projh, projl, proj_b, xph, xpl);
  // 3: qkv both branches  K=64 N=192
  gemm_mfma<64><<<dim3(256, 6, 2), blk, 0, stream>>>(
      xph, xpl, linh, linl, ginh, ginl, loc_in_b, glob_in_b,
      qkv_l, qkv_g, 192);
  // 4: K/V prep for MFMA global attention
  prep_kv<<<4224, blk, 0, stream>>>(qkv_g, KH, KL, VTh, VTl);
  // 5: local attention -> o_l
  local_attn<<<512, blk, 0, stream>>>(qkv_l, o_l);
  // 6: MFMA global attention -> unnormalized o_g + pl
  mfma_gattn<<<dim3(16, 8, 16), blk, 0, stream>>>(qkv_g, KH, KL, VTh, VTl, o_g, pl);
  // 7: fusion GEMM (diag + normalize folded into A-load)  K=128 N=64
  gemm_fuse<<<dim3(256, 2, 1), blk, 0, stream>>>(
      o_l, o_g, pl, qkv_g, wfh, wfl, bc, fused);
  // 8: score + pooling partials (max-free softmax, atomics)
  score_pool<<<dim3(16, 16), dim3(64), 0, stream>>>(
      fused, pw1, pb1, pw2, pb2, num, den);
  // 9: finalize out = num/den
  finalize<<<1, dim3(1024), 0, stream>>>(num, den, out);
}

// Round 11
// 194.395 us; speedup vs baseline: 2.5909x; 1.1133x over previous
//
#include <hip/hip_runtime.h>

// Shapes: B=16, S=1024, E=64, H=8, d=8, INPUT_DIM=310
// local mask: |i-j|<=5 (11 keys); sparse mask: j%3==0 or i==j (342 keys + diag)
//
// GEMMs + global attention via mfma_f32_16x16x32_bf16, fp32 = hi+lo bf16 split.
// A-frag A[m=lane&15][k=quad*8+j]; B-frag B[n=lane&15][k=quad*8+j];
// C/D: col=lane&15, row=quad*4+reg.  (verified R6-R10 passing, absmax 4.9e-4)
// Global attn: S=Q.Kc^T (K=8 pad 32), exp in C-layout, same-wave LDS transpose
// to A-frag, O += P.Vaug with ones-column producing l. Diagonal key + 1/l
// normalization folded into gemm_fuse's A-fragment load.
// Pooling: max-free softmax (scores tanh-bounded), atomic num/den.
// score_pool: 4 waves/block, wave w covers 8 of 32 hidden units (R10 was
// 1 wave/CU latency-starved at 44us).

typedef __attribute__((ext_vector_type(8))) short short8;
typedef __attribute__((ext_vector_type(4))) float float4v;

#define INV_SQRT8 0.3535533905932738f

__device__ __forceinline__ float4 ld4(const float* p) { return *(const float4*)p; }

__device__ __forceinline__ float4 f4fma(float s, float4 w, float4 a) {
  a.x = fmaf(s, w.x, a.x); a.y = fmaf(s, w.y, a.y);
  a.z = fmaf(s, w.z, a.z); a.w = fmaf(s, w.w, a.w);
  return a;
}

// RNE fp32 -> (bf16 hi, bf16 lo); x == hi + lo to ~2^-16 relative.
__device__ __forceinline__ void bsplit(float x, short& h, short& l) {
  unsigned xb = __float_as_uint(x);
  unsigned hb = (xb + 0x7fffu + ((xb >> 16) & 1u)) & 0xffff0000u;
  h = (short)(hb >> 16);
  float lf = x - __uint_as_float(hb);
  unsigned lb = __float_as_uint(lf);
  l = (short)((lb + 0x7fffu + ((lb >> 16) & 1u)) >> 16);
}

// ---------------- prep_w: split weights into wb segments (shorts) + fused
// fusion weights + combined bias bc + zero the pooling accumulators.
__global__ __launch_bounds__(256) void prep_w(
    const float* __restrict__ pw, const float* __restrict__ liw,
    const float* __restrict__ giw, const float* __restrict__ fw,
    const float* __restrict__ low, const float* __restrict__ gow,
    const float* __restrict__ lob, const float* __restrict__ gob,
    const float* __restrict__ fb,
    short* __restrict__ wb, float* __restrict__ bc, float* __restrict__ numden)
{
  unsigned idx = blockIdx.x * 256 + threadIdx.x;   // 53248 total
  float v; unsigned ho, lo_;
  if (idx < 20480u) {           // proj, padded K 310->320
    unsigned r = idx / 320u, k = idx - r * 320u;
    v = (k < 310u) ? pw[r * 310u + k] : 0.f;
    ho = 0u + idx; lo_ = 20480u + idx;
  } else if (idx < 32768u) {    // loc_in
    unsigned i = idx - 20480u; v = liw[i]; ho = 40960u + i; lo_ = 53248u + i;
  } else if (idx < 45056u) {    // glob_in
    unsigned i = idx - 32768u; v = giw[i]; ho = 65536u + i; lo_ = 77824u + i;
  } else {                      // fused fusion weight W12[n][k]
    unsigned i = idx - 45056u;
    unsigned n = i >> 7, k = i & 127u;
    float s = 0.f;
    if (k < 64u) {
      for (int e = 0; e < 64; e++) s += fw[n * 128 + e] * low[e * 64 + k];
    } else {
      for (int e = 0; e < 64; e++) s += fw[n * 128 + 64 + e] * gow[e * 64 + (k - 64u)];
    }
    v = s; ho = 90112u + i; lo_ = 98304u + i;
  }
  short h, l; bsplit(v, h, l);
  wb[ho] = h; wb[lo_] = l;
  if (idx < 64u) {
    float b = fb[idx];
    for (int e = 0; e < 64; e++)
      b += lob[e] * fw[idx * 128 + e] + gob[e] * fw[idx * 128 + 64 + e];
    bc[idx] = b;
  }
  if (idx < 1040u) numden[idx] = 0.f;   // num[1024] + den[16]
}

// ---------------- proj GEMM: xp = x @ proj_w^T + proj_b, fp32 A converted
// in-register. K=310 (W padded to 320). Writes bf16 hi/lo.
__global__ __launch_bounds__(256) void gemm_proj(
    const float* __restrict__ X,
    const short* __restrict__ Wh, const short* __restrict__ Wl,
    const float* __restrict__ bias,
    short* __restrict__ Ch, short* __restrict__ Cl)
{
  const int lane = threadIdx.x & 63;
  const int w = threadIdx.x >> 6;
  const int q = lane >> 4, r = lane & 15;
  const int m0 = blockIdx.x * 64 + w * 16;
  const int n0 = blockIdx.y * 32;

  float bv0 = bias[n0 + r], bv1 = bias[n0 + 16 + r];
  float4v acc0 = {bv0, bv0, bv0, bv0};
  float4v acc1 = {bv1, bv1, bv1, bv1};

  const float* arow = X + (size_t)(m0 + r) * 310;

  #pragma unroll
  for (int ks = 0; ks < 10; ks++) {
    const int k0 = ks * 32 + q * 8;
    float av[8];
    if (ks < 9) {
      const float* ap = arow + k0;
      #pragma unroll
      for (int t = 0; t < 4; t++) {
        float2 f = *(const float2*)(ap + t * 2);
        av[t*2] = f.x; av[t*2+1] = f.y;
      }
    } else {
      #pragma unroll
      for (int j = 0; j < 8; j++) {
        int kidx = k0 + j;
        av[j] = (kidx < 310) ? arow[kidx] : 0.f;
      }
    }
    short8 ah, al;
    #pragma unroll
    for (int i = 0; i < 8; i++) { short h, l; bsplit(av[i], h, l); ah[i]=h; al[i]=l; }
    short8 bh0 = *(const short8*)(Wh + (size_t)(n0 + r) * 320 + k0);
    short8 bl0 = *(const short8*)(Wl + (size_t)(n0 + r) * 320 + k0);
    short8 bh1 = *(const short8*)(Wh + (size_t)(n0 + 16 + r) * 320 + k0);
    short8 bl1 = *(const short8*)(Wl + (size_t)(n0 + 16 + r) * 320 + k0);
    acc0 = __builtin_amdgcn_mfma_f32_16x16x32_bf16(al, bh0, acc0, 0, 0, 0);
    acc0 = __builtin_amdgcn_mfma_f32_16x16x32_bf16(ah, bl0, acc0, 0, 0, 0);
    acc0 = __builtin_amdgcn_mfma_f32_16x16x32_bf16(ah, bh0, acc0, 0, 0, 0);
    acc1 = __builtin_amdgcn_mfma_f32_16x16x32_bf16(al, bh1, acc1, 0, 0, 0);
    acc1 = __builtin_amdgcn_mfma_f32_16x16x32_bf16(ah, bl1, acc1, 0, 0, 0);
    acc1 = __builtin_amdgcn_mfma_f32_16x16x32_bf16(ah, bh1, acc1, 0, 0, 0);
  }

  #pragma unroll
  for (int e = 0; e < 4; e++) {
    const int row = m0 + q * 4 + e;
    short h, l;
    bsplit(acc0[e], h, l);
    Ch[(size_t)row * 64 + n0 + r] = h; Cl[(size_t)row * 64 + n0 + r] = l;
    bsplit(acc1[e], h, l);
    Ch[(size_t)row * 64 + n0 + 16 + r] = h; Cl[(size_t)row * 64 + n0 + 16 + r] = l;
  }
}

// ---------------- MFMA GEMM (bf16 A): C = A.W^T + bias (fp32 C)
template<int KP>
__global__ __launch_bounds__(256) void gemm_mfma(
    const short* __restrict__ Ah, const short* __restrict__ Al,
    const short* __restrict__ Wh0, const short* __restrict__ Wl0,
    const short* __restrict__ Wh1, const short* __restrict__ Wl1,
    const float* __restrict__ bias0, const float* __restrict__ bias1,
    float* __restrict__ C0, float* __restrict__ C1, int ldc)
{
  const int z = blockIdx.z;
  const short* Wh = z ? Wh1 : Wh0;
  const short* Wl = z ? Wl1 : Wl0;
  const float* bias = z ? bias1 : bias0;
  float* C = z ? C1 : C0;

  const int lane = threadIdx.x & 63;
  const int w = threadIdx.x >> 6;
  const int q = lane >> 4, r = lane & 15;
  const int m0 = blockIdx.x * 64 + w * 16;
  const int n0 = blockIdx.y * 32;

  float bv0 = bias[n0 + r], bv1 = bias[n0 + 16 + r];
  float4v acc0 = {bv0, bv0, bv0, bv0};
  float4v acc1 = {bv1, bv1, bv1, bv1};

  #pragma unroll
  for (int ks = 0; ks < KP / 32; ks++) {
    const int k0 = ks * 32 + q * 8;
    short8 ah = *(const short8*)(Ah + (size_t)(m0 + r) * KP + k0);
    short8 al = *(const short8*)(Al + (size_t)(m0 + r) * KP + k0);
    short8 bh0 = *(const short8*)(Wh + (size_t)(n0 + r) * KP + k0);
    short8 bl0 = *(const short8*)(Wl + (size_t)(n0 + r) * KP + k0);
    short8 bh1 = *(const short8*)(Wh + (size_t)(n0 + 16 + r) * KP + k0);
    short8 bl1 = *(const short8*)(Wl + (size_t)(n0 + 16 + r) * KP + k0);
    acc0 = __builtin_amdgcn_mfma_f32_16x16x32_bf16(al, bh0, acc0, 0, 0, 0);
    acc0 = __builtin_amdgcn_mfma_f32_16x16x32_bf16(ah, bl0, acc0, 0, 0, 0);
    acc0 = __builtin_amdgcn_mfma_f32_16x16x32_bf16(ah, bh0, acc0, 0, 0, 0);
    acc1 = __builtin_amdgcn_mfma_f32_16x16x32_bf16(al, bh1, acc1, 0, 0, 0);
    acc1 = __builtin_amdgcn_mfma_f32_16x16x32_bf16(ah, bl1, acc1, 0, 0, 0);
    acc1 = __builtin_amdgcn_mfma_f32_16x16x32_bf16(ah, bh1, acc1, 0, 0, 0);
  }

  #pragma unroll
  for (int e = 0; e < 4; e++) {
    const int row = m0 + q * 4 + e;
    C[(size_t)row * ldc + n0 + r] = acc0[e];
    C[(size_t)row * ldc + n0 + 16 + r] = acc1[e];
  }
}

// ---------------- prep_kv: KH/KL[bh][352][8] bf16 (keys j=3*kk, pad 0) and
// VTh/VTl[bh][16][352] bf16 (rows 0..7 = V dims, row 8 = ones, rest 0).
__global__ __launch_bounds__(256) void prep_kv(
    const float* __restrict__ qkv,
    short* __restrict__ KH, short* __restrict__ KL,
    short* __restrict__ VTh, short* __restrict__ VTl)
{
  unsigned idx = blockIdx.x * 256 + threadIdx.x;   // 360448 + 720896 = 1081344
  if (idx < 360448u) {
    unsigned bh = idx / 2816u;             // 352*8
    unsigned rem = idx - bh * 2816u;
    unsigned kk = rem >> 3, d = rem & 7u;
    float v = (kk < 342u)
      ? qkv[((size_t)((bh >> 3) * 1024 + kk * 3)) * 192 + 64 + (bh & 7u) * 8 + d]
      : 0.f;
    short h, l; bsplit(v, h, l);
    KH[idx] = h; KL[idx] = l;
  } else {
    unsigned j = idx - 360448u;
    unsigned bh = j / 5632u;               // 16*352
    unsigned rem = j - bh * 5632u;
    unsigned n = rem / 352u, kk = rem - n * 352u;
    float v;
    if (n < 8u) {
      v = (kk < 342u)
        ? qkv[((size_t)((bh >> 3) * 1024 + kk * 3)) * 192 + 128 + (bh & 7u) * 8 + n]
        : 0.f;
    } else {
      v = (n == 8u) ? 1.f : 0.f;
    }
    short h, l; bsplit(v, h, l);
    VTh[j] = h; VTl[j] = l;
  }
}

// ---------------- MFMA global attention: grid (b=16, h=8, qtile=16), 256 thr.
// Wave w handles 16 queries. Writes UNNORMALIZED O to o_g and l to pl.
__global__ __launch_bounds__(256) void mfma_gattn(
    const float* __restrict__ qkv,
    const short* __restrict__ KH, const short* __restrict__ KL,
    const short* __restrict__ VTh, const short* __restrict__ VTl,
    float* __restrict__ o_g, float* __restrict__ pl)
{
  __shared__ short Pbuf[4][2][2][16][32];   // wave, parity, hi/lo, q, k
  const int b = blockIdx.x, h = blockIdx.y, qt = blockIdx.z;
  const int w = threadIdx.x >> 6, lane = threadIdx.x & 63;
  const int quad = lane >> 4, r = lane & 15;
  const int bh = b * 8 + h;
  const int m0 = qt * 64 + w * 16;

  const short8 z8 = {0,0,0,0,0,0,0,0};
  short8 qh = z8, ql = z8;
  if (quad == 0) {
    const float* qp = qkv + (size_t)(b * 1024 + m0 + r) * 192 + h * 8;
    #pragma unroll
    for (int d = 0; d < 8; d++) { short hh, ll; bsplit(qp[d], hh, ll); qh[d]=hh; ql[d]=ll; }
  }
  const short* kbase  = KH + (size_t)bh * 2816;
  const short* klbase = KL + (size_t)bh * 2816;
  const short* vhbase = VTh + ((size_t)bh * 16 + r) * 352;
  const short* vlbase = VTl + ((size_t)bh * 16 + r) * 352;

  float4v oacc = {0.f, 0.f, 0.f, 0.f};

  for (int kc = 0; kc < 11; kc++) {
    short8 kh0 = z8, kl0 = z8, kh1 = z8, kl1 = z8;
    if (quad == 0) {
      kh0 = *(const short8*)(kbase  + (size_t)(kc * 32 + r) * 8);
      kl0 = *(const short8*)(klbase + (size_t)(kc * 32 + r) * 8);
      kh1 = *(const short8*)(kbase  + (size_t)(kc * 32 + 16 + r) * 8);
      kl1 = *(const short8*)(klbase + (size_t)(kc * 32 + 16 + r) * 8);
    }
    float4v s0 = {0.f,0.f,0.f,0.f}, s1 = {0.f,0.f,0.f,0.f};
    s0 = __builtin_amdgcn_mfma_f32_16x16x32_bf16(qh, kl0, s0, 0, 0, 0);
    s0 = __builtin_amdgcn_mfma_f32_16x16x32_bf16(ql, kh0, s0, 0, 0, 0);
    s0 = __builtin_amdgcn_mfma_f32_16x16x32_bf16(qh, kh0, s0, 0, 0, 0);
    s1 = __builtin_amdgcn_mfma_f32_16x16x32_bf16(qh, kl1, s1, 0, 0, 0);
    s1 = __builtin_amdgcn_mfma_f32_16x16x32_bf16(ql, kh1, s1, 0, 0, 0);
    s1 = __builtin_amdgcn_mfma_f32_16x16x32_bf16(qh, kh1, s1, 0, 0, 0);

    const int par = kc & 1;
    const int key0 = kc * 32 + r, key1 = key0 + 16;
    #pragma unroll
    for (int e = 0; e < 4; e++) {
      float p0 = (key0 < 342) ? __expf(s0[e] * INV_SQRT8) : 0.f;
      float p1 = (key1 < 342) ? __expf(s1[e] * INV_SQRT8) : 0.f;
      short h0, l0, h1, l1; bsplit(p0, h0, l0); bsplit(p1, h1, l1);
      const int qloc = quad * 4 + e;
      Pbuf[w][par][0][qloc][r]      = h0;
      Pbuf[w][par][0][qloc][16 + r] = h1;
      Pbuf[w][par][1][qloc][r]      = l0;
      Pbuf[w][par][1][qloc][16 + r] = l1;
    }
    // Same-wave LDS transpose read (DS ops in-order per wave; no barrier).
    short8 pA = *(const short8*)&Pbuf[w][par][0][r][quad * 8];
    short8 pB = *(const short8*)&Pbuf[w][par][1][r][quad * 8];
    short8 vh = *(const short8*)(vhbase + kc * 32 + quad * 8);
    short8 vl = *(const short8*)(vlbase + kc * 32 + quad * 8);
    oacc = __builtin_amdgcn_mfma_f32_16x16x32_bf16(pA, vl, oacc, 0, 0, 0);
    oacc = __builtin_amdgcn_mfma_f32_16x16x32_bf16(pB, vh, oacc, 0, 0, 0);
    oacc = __builtin_amdgcn_mfma_f32_16x16x32_bf16(pA, vh, oacc, 0, 0, 0);
  }

  #pragma unroll
  for (int e = 0; e < 4; e++) {
    const int orow = b * 1024 + m0 + quad * 4 + e;
    if (r < 8)       o_g[(size_t)orow * 64 + h * 8 + r] = oacc[e];
    else if (r == 8) pl[(size_t)orow * 8 + h] = oacc[e];
  }
}

// ---------------- Local attention: thread per (b,i,h), 11-key window.
__global__ __launch_bounds__(256) void local_attn(
    const float* __restrict__ qkv, float* __restrict__ o)
{
  int t = blockIdx.x * 256 + threadIdx.x;   // 131072
  int h = t & 7;
  int i = (t >> 3) & 1023;
  int b = t >> 13;
  const float* base = qkv + (size_t)b * 1024 * 192;
  const float* qp = base + (size_t)i * 192 + h * 8;
  float4 q0 = ld4(qp), q1 = ld4(qp + 4);
  float l = 0.f;
  float4 o0 = make_float4(0.f, 0.f, 0.f, 0.f);
  float4 o1 = make_float4(0.f, 0.f, 0.f, 0.f);
  int jlo = i - 5; if (jlo < 0) jlo = 0;
  int jhi = i + 5; if (jhi > 1023) jhi = 1023;
  for (int j = jlo; j <= jhi; j++) {
    const float* kp = base + (size_t)j * 192 + 64 + h * 8;
    float4 k0 = ld4(kp), k1 = ld4(kp + 4);
    float s = q0.x * k0.x + q0.y * k0.y + q0.z * k0.z + q0.w * k0.w
            + q1.x * k1.x + q1.y * k1.y + q1.z * k1.z + q1.w * k1.w;
    float p = __expf(s * INV_SQRT8);
    l += p;
    float4 v0 = ld4(kp + 64), v1 = ld4(kp + 68);
    o0 = f4fma(p, v0, o0);
    o1 = f4fma(p, v1, o1);
  }
  float inv = 1.f / l;
  float* op = o + (size_t)(b * 1024 + i) * 64 + h * 8;
  float4 r0, r1;
  r0.x = o0.x * inv; r0.y = o0.y * inv; r0.z = o0.z * inv; r0.w = o0.w * inv;
  r1.x = o1.x * inv; r1.y = o1.y * inv; r1.z = o1.z * inv; r1.w = o1.w * inv;
  *(float4*)op = r0;
  *(float4*)(op + 4) = r1;
}

// ---------------- Fusion GEMM: fused = [o_l | norm(o_g)+diag] @ Wf^T + bc
__global__ __launch_bounds__(256) void gemm_fuse(
    const float* __restrict__ o_l, const float* __restrict__ o_g,
    const float* __restrict__ pl, const float* __restrict__ qkv_g,
    const short* __restrict__ Wh, const short* __restrict__ Wl,
    const float* __restrict__ bc, float* __restrict__ C)
{
  const int lane = threadIdx.x & 63;
  const int w = threadIdx.x >> 6;
  const int q = lane >> 4, r = lane & 15;
  const int m0 = blockIdx.x * 64 + w * 16;
  const int n0 = blockIdx.y * 32;

  float bv0 = bc[n0 + r], bv1 = bc[n0 + 16 + r];
  float4v acc0 = {bv0, bv0, bv0, bv0};
  float4v acc1 = {bv1, bv1, bv1, bv1};

  #pragma unroll
  for (int ks = 0; ks < 4; ks++) {
    const int k0 = ks * 32 + q * 8;
    const int row = m0 + r;
    float av[8];
    if (ks < 2) {   // local branch, already normalized
      const float* ap = o_l + (size_t)row * 64 + k0;
      float4 f0 = ld4(ap), f1 = ld4(ap + 4);
      av[0]=f0.x; av[1]=f0.y; av[2]=f0.z; av[3]=f0.w;
      av[4]=f1.x; av[5]=f1.y; av[6]=f1.z; av[7]=f1.w;
    } else {        // global branch: unnormalized O + diag + normalize
      const int off = k0 - 64;         // head h = off>>3
      const int h = off >> 3;
      const float* op = o_g + (size_t)row * 64 + off;
      float4 O0 = ld4(op), O1 = ld4(op + 4);
      float l = pl[(size_t)row * 8 + h];
      const int i = row & 1023;
      if (i % 3 != 0) {
        const float* base = qkv_g + (size_t)row * 192;
        const float* qp = base + h * 8;
        const float* kp = base + 64 + h * 8;
        const float* vp = base + 128 + h * 8;
        float4 q0 = ld4(qp), q1 = ld4(qp + 4);
        float4 k0v = ld4(kp), k1v = ld4(kp + 4);
        float s = q0.x*k0v.x + q0.y*k0v.y + q0.z*k0v.z + q0.w*k0v.w
                + q1.x*k1v.x + q1.y*k1v.y + q1.z*k1v.z + q1.w*k1v.w;
        float p = __expf(s * INV_SQRT8);
        float4 v0 = ld4(vp), v1 = ld4(vp + 4);
        O0 = f4fma(p, v0, O0); O1 = f4fma(p, v1, O1);
        l += p;
      }
      float inv = 1.f / l;
      av[0]=O0.x*inv; av[1]=O0.y*inv; av[2]=O0.z*inv; av[3]=O0.w*inv;
      av[4]=O1.x*inv; av[5]=O1.y*inv; av[6]=O1.z*inv; av[7]=O1.w*inv;
    }
    short8 ah, al;
    #pragma unroll
    for (int i2 = 0; i2 < 8; i2++) { short h2, l2; bsplit(av[i2], h2, l2); ah[i2]=h2; al[i2]=l2; }
    short8 bh0 = *(const short8*)(Wh + (size_t)(n0 + r) * 128 + k0);
    short8 bl0 = *(const short8*)(Wl + (size_t)(n0 + r) * 128 + k0);
    short8 bh1 = *(const short8*)(Wh + (size_t)(n0 + 16 + r) * 128 + k0);
    short8 bl1 = *(const short8*)(Wl + (size_t)(n0 + 16 + r) * 128 + k0);
    acc0 = __builtin_amdgcn_mfma_f32_16x16x32_bf16(al, bh0, acc0, 0, 0, 0);
    acc0 = __builtin_amdgcn_mfma_f32_16x16x32_bf16(ah, bl0, acc0, 0, 0, 0);
    acc0 = __builtin_amdgcn_mfma_f32_16x16x32_bf16(ah, bh0, acc0, 0, 0, 0);
    acc1 = __builtin_amdgcn_mfma_f32_16x16x32_bf16(al, bh1, acc1, 0, 0, 0);
    acc1 = __builtin_amdgcn_mfma_f32_16x16x32_bf16(ah, bl1, acc1, 0, 0, 0);
    acc1 = __builtin_amdgcn_mfma_f32_16x16x32_bf16(ah, bh1, acc1, 0, 0, 0);
  }

  #pragma unroll
  for (int e = 0; e < 4; e++) {
    const int row = m0 + q * 4 + e;
    C[(size_t)row * 64 + n0 + r] = acc0[e];
    C[(size_t)row * 64 + n0 + 16 + r] = acc1[e];
  }
}

// ---------------- score_pool: 4 waves/block, 64 rows/block (lane = row).
// Wave w computes hidden units j = w*8..w*8+7; partials reduced via LDS;
// wave 0 finishes: p = exp(sc) (max-free, tanh-bounded), transpose-sum
// p*f into num via atomics, den via shuffle+atomic.
__global__ __launch_bounds__(256) void score_pool(
    const float* __restrict__ fused,
    const float* __restrict__ pw1, const float* __restrict__ pb1,
    const float* __restrict__ pw2, const float* __restrict__ pb2,
    float* __restrict__ num, float* __restrict__ den)
{
  __shared__ float partial[4][64];
  __shared__ float Ls[64][65];
  const int b = blockIdx.x, c = blockIdx.y;
  const int w = threadIdx.x >> 6, lane = threadIdx.x & 63;
  const int row = b * 1024 + c * 64 + lane;
  const float* f = fused + (size_t)row * 64;
  float4 fr[16];
  #pragma unroll
  for (int e = 0; e < 16; e++) fr[e] = ld4(f + e * 4);

  float psc = 0.f;
  #pragma unroll
  for (int jj = 0; jj < 8; jj++) {
    const int j = w * 8 + jj;
    const float* wr = pw1 + j * 64;   // wave-uniform -> s_load
    float hj = pb1[j];
    #pragma unroll
    for (int e = 0; e < 16; e++) {
      float4 wv = ld4(wr + e * 4);
      hj += fr[e].x * wv.x + fr[e].y * wv.y + fr[e].z * wv.z + fr[e].w * wv.w;
    }
    float e2 = __expf(2.f * hj);
    psc += ((e2 - 1.f) / (e2 + 1.f)) * pw2[j];   // tanh via exp
  }
  partial[w][lane] = psc;
  __syncthreads();
  if (w == 0) {
    float sc = pb2[0] + partial[0][lane] + partial[1][lane]
             + partial[2][lane] + partial[3][lane];
    float p = __expf(sc);
    #pragma unroll
    for (int e = 0; e < 16; e++) {
      Ls[lane][e*4+0] = p * fr[e].x; Ls[lane][e*4+1] = p * fr[e].y;
      Ls[lane][e*4+2] = p * fr[e].z; Ls[lane][e*4+3] = p * fr[e].w;
    }
    // single wave: DS ops in order, no barrier needed
    float colsum = 0.f;
    #pragma unroll 8
    for (int s = 0; s < 64; s++) colsum += Ls[s][lane];
    atomicAdd(&num[b * 64 + lane], colsum);
    float ps = p;
    #pragma unroll
    for (int off = 32; off > 0; off >>= 1)
      ps += __shfl_xor(ps, off, 64);
    if (lane == 0) atomicAdd(&den[b], ps);
  }
}

// ---------------- finalize: out = num/den
__global__ __launch_bounds__(1024) void finalize(
    const float* __restrict__ num, const float* __restrict__ den,
    float* __restrict__ out)
{
  int t = threadIdx.x;   // 1024 = 16*64
  out[t] = num[t] / den[t >> 6];
}

extern "C" void kernel_launch(void* const* d_in, const int* in_sizes, int n_in,
                              void* d_out, int out_size, void* d_ws, size_t ws_size,
                              hipStream_t stream)
{
  const float* x          = (const float*)d_in[0];
  const float* proj_w     = (const float*)d_in[1];
  const float* proj_b     = (const float*)d_in[2];
  const float* loc_in_w   = (const float*)d_in[3];
  const float* loc_in_b   = (const float*)d_in[4];
  const float* loc_out_w  = (const float*)d_in[5];
  const float* loc_out_b  = (const float*)d_in[6];
  const float* glob_in_w  = (const float*)d_in[7];
  const float* glob_in_b  = (const float*)d_in[8];
  const float* glob_out_w = (const float*)d_in[9];
  const float* glob_out_b = (const float*)d_in[10];
  const float* fusion_w   = (const float*)d_in[11];
  const float* fusion_b   = (const float*)d_in[12];
  const float* pw1        = (const float*)d_in[13];
  const float* pb1        = (const float*)d_in[14];
  const float* pw2        = (const float*)d_in[15];
  const float* pb2        = (const float*)d_in[16];

  float* ws = (float*)d_ws;
  // Layout (float offsets):
  //  qkv_g    [0, 3145728)         qkv -> prep_kv/mfma_gattn/gemm_fuse(diag)
  //  xph/xpl  shorts at 3538944    proj -> qkv; dead after launch 3
  //  fused    [3538944, 4587520)   gemm_fuse -> score_pool (over dead xp)
  //  qkv_l    [4587520, 7733248)   qkv -> local_attn
  //  o_l      [7733248, 8781824)   local_attn -> gemm_fuse
  //  o_g      [8781824, 9830400)   mfma_gattn -> gemm_fuse (unnormalized)
  //  pl       [9830400, 9961472)   mfma_gattn -> gemm_fuse
  //  KH/KL    shorts at 9961472 / 10141696 (360448 each)
  //  VTh/VTl  shorts at 10321920 / 10682368 (720896 each)
  //  bc       [11042816, 11042880)
  //  numden   [11042880, 11043920)  num[1024], den[16]
  //  wb       shorts at 11043920 (112640)
  float* qkv_g = ws;
  short* xph   = (short*)(ws + 3538944);
  short* xpl   = (short*)(ws + 4063232);
  float* fused = ws + 3538944;
  float* qkv_l = ws + 4587520;
  float* o_l   = ws + 7733248;
  float* o_g   = ws + 8781824;
  float* pl    = ws + 9830400;
  short* KH    = (short*)(ws + 9961472);
  short* KL    = (short*)(ws + 10141696);
  short* VTh   = (short*)(ws + 10321920);
  short* VTl   = (short*)(ws + 10682368);
  float* bc    = ws + 11042816;
  float* numden= ws + 11042880;
  float* num   = numden;
  float* den   = numden + 1024;
  short* wb    = (short*)(ws + 11043920);
  short* projh = wb;           short* projl = wb + 20480;
  short* linh  = wb + 40960;   short* linl  = wb + 53248;
  short* ginh  = wb + 65536;   short* ginl  = wb + 77824;
  short* wfh   = wb + 90112;   short* wfl   = wb + 98304;
  float* out   = (float*)d_out;

  dim3 blk(256);
  // 1: weight split + fused fusion weights + combined bias + zero num/den
  prep_w<<<208, blk, 0, stream>>>(proj_w, loc_in_w, glob_in_w, fusion_w,
                                  loc_out_w, glob_out_w, loc_out_b, glob_out_b,
                                  fusion_b, wb, bc, numden);
  // 2: proj  M=16384 K=310 N=64 -> xp bf16 hi/lo
  gemm_proj<<<dim3(256, 2), blk, 0, stream>>>(x, projh, projl, proj_b, xph, xpl);
  // 3: qkv both branches  K=64 N=192
  gemm_mfma<64><<<dim3(256, 6, 2), blk, 0, stream>>>(
      xph, xpl, linh, linl, ginh, ginl, loc_in_b, glob_in_b,
      qkv_l, qkv_g, 192);
  // 4: K/V prep for MFMA global attention
  prep_kv<<<4224, blk, 0, stream>>>(qkv_g, KH, KL, VTh, VTl);
  // 5: local attention -> o_l
  local_attn<<<512, blk, 0, stream>>>(qkv_l, o_l);
  // 6: MFMA global attention -> unnormalized o_g + pl
  mfma_gattn<<<dim3(16, 8, 16), blk, 0, stream>>>(qkv_g, KH, KL, VTh, VTl, o_g, pl);
  // 7: fusion GEMM (diag + normalize folded into A-load)  K=128 N=64
  gemm_fuse<<<dim3(256, 2, 1), blk, 0, stream>>>(
      o_l, o_g, pl, qkv_g, wfh, wfl, bc, fused);
  // 8: score + pooling partials (4 waves/block, max-free softmax, atomics)
  score_pool<<<dim3(16, 16), blk, 0, stream>>>(
      fused, pw1, pb1, pw2, pb2, num, den);
  // 9: finalize out = num/den
  finalize<<<1, dim3(1024), 0, stream>>>(num, den, out);
}

// Round 13
// 194.032 us; speedup vs baseline: 2.5958x; 1.0019x over previous
//
#include <hip/hip_runtime.h>

// Shapes: B=16, S=1024, E=64, H=8, d=8, INPUT_DIM=310
// local mask: |i-j|<=5 (11 keys); sparse mask: j%3==0 or i==j (342 keys + diag)
//
// R11 structure (9 passing dispatches, absmax 4.9e-4) with two safe merges:
//  - prep_kv + local_attn -> one launch (independent work)
//  - gemm_fuse + score_pool -> one launch; fused tile handed off via LDS,
//    fused global buffer eliminated.
// GEMMs + global attention via mfma_f32_16x16x32_bf16, fp32 = hi+lo bf16 split.
// A-frag A[m=lane&15][k=quad*8+j]; B-frag B[n=lane&15][k=quad*8+j];
// C/D: col=lane&15, row=quad*4+reg.

typedef __attribute__((ext_vector_type(8))) short short8;
typedef __attribute__((ext_vector_type(4))) float float4v;

#define INV_SQRT8 0.3535533905932738f

__device__ __forceinline__ float4 ld4(const float* p) { return *(const float4*)p; }

__device__ __forceinline__ float4 f4fma(float s, float4 w, float4 a) {
  a.x = fmaf(s, w.x, a.x); a.y = fmaf(s, w.y, a.y);
  a.z = fmaf(s, w.z, a.z); a.w = fmaf(s, w.w, a.w);
  return a;
}

// RNE fp32 -> (bf16 hi, bf16 lo); x == hi + lo to ~2^-16 relative.
__device__ __forceinline__ void bsplit(float x, short& h, short& l) {
  unsigned xb = __float_as_uint(x);
  unsigned hb = (xb + 0x7fffu + ((xb >> 16) & 1u)) & 0xffff0000u;
  h = (short)(hb >> 16);
  float lf = x - __uint_as_float(hb);
  unsigned lb = __float_as_uint(lf);
  l = (short)((lb + 0x7fffu + ((lb >> 16) & 1u)) >> 16);
}

// ---------------- prep_w: split weights + fused fusion weights + bc + zero num/den
__global__ __launch_bounds__(256) void prep_w(
    const float* __restrict__ pw, const float* __restrict__ liw,
    const float* __restrict__ giw, const float* __restrict__ fw,
    const float* __restrict__ low, const float* __restrict__ gow,
    const float* __restrict__ lob, const float* __restrict__ gob,
    const float* __restrict__ fb,
    short* __restrict__ wb, float* __restrict__ bc, float* __restrict__ numden)
{
  unsigned idx = blockIdx.x * 256 + threadIdx.x;   // 53248 total
  float v; unsigned ho, lo_;
  if (idx < 20480u) {           // proj, padded K 310->320
    unsigned r = idx / 320u, k = idx - r * 320u;
    v = (k < 310u) ? pw[r * 310u + k] : 0.f;
    ho = 0u + idx; lo_ = 20480u + idx;
  } else if (idx < 32768u) {    // loc_in
    unsigned i = idx - 20480u; v = liw[i]; ho = 40960u + i; lo_ = 53248u + i;
  } else if (idx < 45056u) {    // glob_in
    unsigned i = idx - 32768u; v = giw[i]; ho = 65536u + i; lo_ = 77824u + i;
  } else {                      // fused fusion weight W12[n][k]
    unsigned i = idx - 45056u;
    unsigned n = i >> 7, k = i & 127u;
    float s = 0.f;
    if (k < 64u) {
      for (int e = 0; e < 64; e++) s += fw[n * 128 + e] * low[e * 64 + k];
    } else {
      for (int e = 0; e < 64; e++) s += fw[n * 128 + 64 + e] * gow[e * 64 + (k - 64u)];
    }
    v = s; ho = 90112u + i; lo_ = 98304u + i;
  }
  short h, l; bsplit(v, h, l);
  wb[ho] = h; wb[lo_] = l;
  if (idx < 64u) {
    float b = fb[idx];
    for (int e = 0; e < 64; e++)
      b += lob[e] * fw[idx * 128 + e] + gob[e] * fw[idx * 128 + 64 + e];
    bc[idx] = b;
  }
  if (idx < 1040u) numden[idx] = 0.f;   // num[1024] + den[16]
}

// ---------------- proj GEMM: xp = x @ proj_w^T + proj_b (fp32 A in-register)
__global__ __launch_bounds__(256) void gemm_proj(
    const float* __restrict__ X,
    const short* __restrict__ Wh, const short* __restrict__ Wl,
    const float* __restrict__ bias,
    short* __restrict__ Ch, short* __restrict__ Cl)
{
  const int lane = threadIdx.x & 63;
  const int w = threadIdx.x >> 6;
  const int q = lane >> 4, r = lane & 15;
  const int m0 = blockIdx.x * 64 + w * 16;
  const int n0 = blockIdx.y * 32;

  float bv0 = bias[n0 + r], bv1 = bias[n0 + 16 + r];
  float4v acc0 = {bv0, bv0, bv0, bv0};
  float4v acc1 = {bv1, bv1, bv1, bv1};

  const float* arow = X + (size_t)(m0 + r) * 310;

  #pragma unroll
  for (int ks = 0; ks < 10; ks++) {
    const int k0 = ks * 32 + q * 8;
    float av[8];
    if (ks < 9) {
      const float* ap = arow + k0;
      #pragma unroll
      for (int t = 0; t < 4; t++) {
        float2 f = *(const float2*)(ap + t * 2);
        av[t*2] = f.x; av[t*2+1] = f.y;
      }
    } else {
      #pragma unroll
      for (int j = 0; j < 8; j++) {
        int kidx = k0 + j;
        av[j] = (kidx < 310) ? arow[kidx] : 0.f;
      }
    }
    short8 ah, al;
    #pragma unroll
    for (int i = 0; i < 8; i++) { short h, l; bsplit(av[i], h, l); ah[i]=h; al[i]=l; }
    short8 bh0 = *(const short8*)(Wh + (size_t)(n0 + r) * 320 + k0);
    short8 bl0 = *(const short8*)(Wl + (size_t)(n0 + r) * 320 + k0);
    short8 bh1 = *(const short8*)(Wh + (size_t)(n0 + 16 + r) * 320 + k0);
    short8 bl1 = *(const short8*)(Wl + (size_t)(n0 + 16 + r) * 320 + k0);
    acc0 = __builtin_amdgcn_mfma_f32_16x16x32_bf16(al, bh0, acc0, 0, 0, 0);
    acc0 = __builtin_amdgcn_mfma_f32_16x16x32_bf16(ah, bl0, acc0, 0, 0, 0);
    acc0 = __builtin_amdgcn_mfma_f32_16x16x32_bf16(ah, bh0, acc0, 0, 0, 0);
    acc1 = __builtin_amdgcn_mfma_f32_16x16x32_bf16(al, bh1, acc1, 0, 0, 0);
    acc1 = __builtin_amdgcn_mfma_f32_16x16x32_bf16(ah, bl1, acc1, 0, 0, 0);
    acc1 = __builtin_amdgcn_mfma_f32_16x16x32_bf16(ah, bh1, acc1, 0, 0, 0);
  }

  #pragma unroll
  for (int e = 0; e < 4; e++) {
    const int row = m0 + q * 4 + e;
    short h, l;
    bsplit(acc0[e], h, l);
    Ch[(size_t)row * 64 + n0 + r] = h; Cl[(size_t)row * 64 + n0 + r] = l;
    bsplit(acc1[e], h, l);
    Ch[(size_t)row * 64 + n0 + 16 + r] = h; Cl[(size_t)row * 64 + n0 + 16 + r] = l;
  }
}

// ---------------- MFMA GEMM (bf16 A): C = A.W^T + bias (fp32 C)
template<int KP>
__global__ __launch_bounds__(256) void gemm_mfma(
    const short* __restrict__ Ah, const short* __restrict__ Al,
    const short* __restrict__ Wh0, const short* __restrict__ Wl0,
    const short* __restrict__ Wh1, const short* __restrict__ Wl1,
    const float* __restrict__ bias0, const float* __restrict__ bias1,
    float* __restrict__ C0, float* __restrict__ C1, int ldc)
{
  const int z = blockIdx.z;
  const short* Wh = z ? Wh1 : Wh0;
  const short* Wl = z ? Wl1 : Wl0;
  const float* bias = z ? bias1 : bias0;
  float* C = z ? C1 : C0;

  const int lane = threadIdx.x & 63;
  const int w = threadIdx.x >> 6;
  const int q = lane >> 4, r = lane & 15;
  const int m0 = blockIdx.x * 64 + w * 16;
  const int n0 = blockIdx.y * 32;

  float bv0 = bias[n0 + r], bv1 = bias[n0 + 16 + r];
  float4v acc0 = {bv0, bv0, bv0, bv0};
  float4v acc1 = {bv1, bv1, bv1, bv1};

  #pragma unroll
  for (int ks = 0; ks < KP / 32; ks++) {
    const int k0 = ks * 32 + q * 8;
    short8 ah = *(const short8*)(Ah + (size_t)(m0 + r) * KP + k0);
    short8 al = *(const short8*)(Al + (size_t)(m0 + r) * KP + k0);
    short8 bh0 = *(const short8*)(Wh + (size_t)(n0 + r) * KP + k0);
    short8 bl0 = *(const short8*)(Wl + (size_t)(n0 + r) * KP + k0);
    short8 bh1 = *(const short8*)(Wh + (size_t)(n0 + 16 + r) * KP + k0);
    short8 bl1 = *(const short8*)(Wl + (size_t)(n0 + 16 + r) * KP + k0);
    acc0 = __builtin_amdgcn_mfma_f32_16x16x32_bf16(al, bh0, acc0, 0, 0, 0);
    acc0 = __builtin_amdgcn_mfma_f32_16x16x32_bf16(ah, bl0, acc0, 0, 0, 0);
    acc0 = __builtin_amdgcn_mfma_f32_16x16x32_bf16(ah, bh0, acc0, 0, 0, 0);
    acc1 = __builtin_amdgcn_mfma_f32_16x16x32_bf16(al, bh1, acc1, 0, 0, 0);
    acc1 = __builtin_amdgcn_mfma_f32_16x16x32_bf16(ah, bl1, acc1, 0, 0, 0);
    acc1 = __builtin_amdgcn_mfma_f32_16x16x32_bf16(ah, bh1, acc1, 0, 0, 0);
  }

  #pragma unroll
  for (int e = 0; e < 4; e++) {
    const int row = m0 + q * 4 + e;
    C[(size_t)row * ldc + n0 + r] = acc0[e];
    C[(size_t)row * ldc + n0 + 16 + r] = acc1[e];
  }
}

// ---------------- prep_kv + local attention merged (independent work).
// Blocks [0,4224): K/V repack to bf16 hi/lo. Blocks [4224,4736): local attn.
__global__ __launch_bounds__(256) void prep_kv_local(
    const float* __restrict__ qkv_g, const float* __restrict__ qkv_l,
    short* __restrict__ KH, short* __restrict__ KL,
    short* __restrict__ VTh, short* __restrict__ VTl,
    float* __restrict__ o_l)
{
  const int u = blockIdx.x;
  if (u < 4224) {
    unsigned idx = (unsigned)u * 256u + threadIdx.x;   // < 1081344
    if (idx < 360448u) {
      unsigned bh = idx / 2816u;             // 352*8
      unsigned rem = idx - bh * 2816u;
      unsigned kk = rem >> 3, d = rem & 7u;
      float v = (kk < 342u)
        ? qkv_g[((size_t)((bh >> 3) * 1024 + kk * 3)) * 192 + 64 + (bh & 7u) * 8 + d]
        : 0.f;
      short h, l; bsplit(v, h, l);
      KH[idx] = h; KL[idx] = l;
    } else if (idx < 1081344u) {
      unsigned j = idx - 360448u;
      unsigned bh = j / 5632u;               // 16*352
      unsigned rem = j - bh * 5632u;
      unsigned n = rem / 352u, kk = rem - n * 352u;
      float v;
      if (n < 8u) {
        v = (kk < 342u)
          ? qkv_g[((size_t)((bh >> 3) * 1024 + kk * 3)) * 192 + 128 + (bh & 7u) * 8 + n]
          : 0.f;
      } else {
        v = (n == 8u) ? 1.f : 0.f;
      }
      short h, l; bsplit(v, h, l);
      VTh[j] = h; VTl[j] = l;
    }
  } else {
    int t = (u - 4224) * 256 + threadIdx.x;   // 131072
    int h = t & 7;
    int i = (t >> 3) & 1023;
    int b = t >> 13;
    const float* base = qkv_l + (size_t)b * 1024 * 192;
    const float* qp = base + (size_t)i * 192 + h * 8;
    float4 q0 = ld4(qp), q1 = ld4(qp + 4);
    float l = 0.f;
    float4 o0 = make_float4(0.f, 0.f, 0.f, 0.f);
    float4 o1 = make_float4(0.f, 0.f, 0.f, 0.f);
    int jlo = i - 5; if (jlo < 0) jlo = 0;
    int jhi = i + 5; if (jhi > 1023) jhi = 1023;
    for (int j = jlo; j <= jhi; j++) {
      const float* kp = base + (size_t)j * 192 + 64 + h * 8;
      float4 k0 = ld4(kp), k1 = ld4(kp + 4);
      float s = q0.x * k0.x + q0.y * k0.y + q0.z * k0.z + q0.w * k0.w
              + q1.x * k1.x + q1.y * k1.y + q1.z * k1.z + q1.w * k1.w;
      float p = __expf(s * INV_SQRT8);
      l += p;
      float4 v0 = ld4(kp + 64), v1 = ld4(kp + 68);
      o0 = f4fma(p, v0, o0);
      o1 = f4fma(p, v1, o1);
    }
    float inv = 1.f / l;
    float* op = o_l + (size_t)(b * 1024 + i) * 64 + h * 8;
    float4 r0, r1;
    r0.x = o0.x * inv; r0.y = o0.y * inv; r0.z = o0.z * inv; r0.w = o0.w * inv;
    r1.x = o1.x * inv; r1.y = o1.y * inv; r1.z = o1.z * inv; r1.w = o1.w * inv;
    *(float4*)op = r0;
    *(float4*)(op + 4) = r1;
  }
}

// ---------------- MFMA global attention: grid (b=16, h=8, qtile=16), 256 thr.
__global__ __launch_bounds__(256) void mfma_gattn(
    const float* __restrict__ qkv,
    const short* __restrict__ KH, const short* __restrict__ KL,
    const short* __restrict__ VTh, const short* __restrict__ VTl,
    float* __restrict__ o_g, float* __restrict__ pl)
{
  __shared__ short Pbuf[4][2][2][16][32];   // wave, parity, hi/lo, q, k
  const int b = blockIdx.x, h = blockIdx.y, qt = blockIdx.z;
  const int w = threadIdx.x >> 6, lane = threadIdx.x & 63;
  const int quad = lane >> 4, r = lane & 15;
  const int bh = b * 8 + h;
  const int m0 = qt * 64 + w * 16;

  const short8 z8 = {0,0,0,0,0,0,0,0};
  short8 qh = z8, ql = z8;
  if (quad == 0) {
    const float* qp = qkv + (size_t)(b * 1024 + m0 + r) * 192 + h * 8;
    #pragma unroll
    for (int d = 0; d < 8; d++) { short hh, ll; bsplit(qp[d], hh, ll); qh[d]=hh; ql[d]=ll; }
  }
  const short* kbase  = KH + (size_t)bh * 2816;
  const short* klbase = KL + (size_t)bh * 2816;
  const short* vhbase = VTh + ((size_t)bh * 16 + r) * 352;
  const short* vlbase = VTl + ((size_t)bh * 16 + r) * 352;

  float4v oacc = {0.f, 0.f, 0.f, 0.f};

  for (int kc = 0; kc < 11; kc++) {
    short8 kh0 = z8, kl0 = z8, kh1 = z8, kl1 = z8;
    if (quad == 0) {
      kh0 = *(const short8*)(kbase  + (size_t)(kc * 32 + r) * 8);
      kl0 = *(const short8*)(klbase + (size_t)(kc * 32 + r) * 8);
      kh1 = *(const short8*)(kbase  + (size_t)(kc * 32 + 16 + r) * 8);
      kl1 = *(const short8*)(klbase + (size_t)(kc * 32 + 16 + r) * 8);
    }
    float4v s0 = {0.f,0.f,0.f,0.f}, s1 = {0.f,0.f,0.f,0.f};
    s0 = __builtin_amdgcn_mfma_f32_16x16x32_bf16(qh, kl0, s0, 0, 0, 0);
    s0 = __builtin_amdgcn_mfma_f32_16x16x32_bf16(ql, kh0, s0, 0, 0, 0);
    s0 = __builtin_amdgcn_mfma_f32_16x16x32_bf16(qh, kh0, s0, 0, 0, 0);
    s1 = __builtin_amdgcn_mfma_f32_16x16x32_bf16(qh, kl1, s1, 0, 0, 0);
    s1 = __builtin_amdgcn_mfma_f32_16x16x32_bf16(ql, kh1, s1, 0, 0, 0);
    s1 = __builtin_amdgcn_mfma_f32_16x16x32_bf16(qh, kh1, s1, 0, 0, 0);

    const int par = kc & 1;
    const int key0 = kc * 32 + r, key1 = key0 + 16;
    #pragma unroll
    for (int e = 0; e < 4; e++) {
      float p0 = (key0 < 342) ? __expf(s0[e] * INV_SQRT8) : 0.f;
      float p1 = (key1 < 342) ? __expf(s1[e] * INV_SQRT8) : 0.f;
      short h0, l0, h1, l1; bsplit(p0, h0, l0); bsplit(p1, h1, l1);
      const int qloc = quad * 4 + e;
      Pbuf[w][par][0][qloc][r]      = h0;
      Pbuf[w][par][0][qloc][16 + r] = h1;
      Pbuf[w][par][1][qloc][r]      = l0;
      Pbuf[w][par][1][qloc][16 + r] = l1;
    }
    // Same-wave LDS transpose read (DS ops in-order per wave; no barrier).
    short8 pA = *(const short8*)&Pbuf[w][par][0][r][quad * 8];
    short8 pB = *(const short8*)&Pbuf[w][par][1][r][quad * 8];
    short8 vh = *(const short8*)(vhbase + kc * 32 + quad * 8);
    short8 vl = *(const short8*)(vlbase + kc * 32 + quad * 8);
    oacc = __builtin_amdgcn_mfma_f32_16x16x32_bf16(pA, vl, oacc, 0, 0, 0);
    oacc = __builtin_amdgcn_mfma_f32_16x16x32_bf16(pB, vh, oacc, 0, 0, 0);
    oacc = __builtin_amdgcn_mfma_f32_16x16x32_bf16(pA, vh, oacc, 0, 0, 0);
  }

  #pragma unroll
  for (int e = 0; e < 4; e++) {
    const int orow = b * 1024 + m0 + quad * 4 + e;
    if (r < 8)       o_g[(size_t)orow * 64 + h * 8 + r] = oacc[e];
    else if (r == 8) pl[(size_t)orow * 8 + h] = oacc[e];
  }
}

// ---------------- Fusion GEMM + score + pool partials, fused via LDS.
// Block = 64 rows (grid 256). Wave w: rows w*16..+16, ALL 64 cols (4 frags).
// Diag-key + 1/l normalization folded into A-load (as R11 gemm_fuse).
// C-tile parked in LDS (stride 68: rows 16B-aligned), then R11 score_pool
// logic runs from LDS: wave w computes hidden units w*8..+8, wave 0 combines,
// p=exp(sc) (max-free, tanh-bounded), transpose-sum into num/den atomics.
__global__ __launch_bounds__(256) void gemm_fuse_score(
    const float* __restrict__ o_l, const float* __restrict__ o_g,
    const float* __restrict__ pl, const float* __restrict__ qkv_g,
    const short* __restrict__ Wh, const short* __restrict__ Wl,
    const float* __restrict__ bc,
    const float* __restrict__ pw1, const float* __restrict__ pb1,
    const float* __restrict__ pw2, const float* __restrict__ pb2,
    float* __restrict__ num, float* __restrict__ den)
{
  __shared__ float Ls[64][68];
  __shared__ float partial[4][64];
  const int tid = threadIdx.x;
  const int lane = tid & 63, w = tid >> 6;
  const int quad = lane >> 4, r = lane & 15;
  const int bx = blockIdx.x;
  const int m0 = bx * 64 + w * 16;

  float4v acc[4];
  #pragma unroll
  for (int g = 0; g < 4; g++) {
    float bv = bc[g * 16 + r];
    float4v t = {bv, bv, bv, bv};
    acc[g] = t;
  }

  #pragma unroll
  for (int ks = 0; ks < 4; ks++) {
    const int k0 = ks * 32 + quad * 8;
    const int row = m0 + r;
    float av[8];
    if (ks < 2) {   // local branch, already normalized
      const float* ap = o_l + (size_t)row * 64 + k0;
      float4 f0 = ld4(ap), f1 = ld4(ap + 4);
      av[0]=f0.x; av[1]=f0.y; av[2]=f0.z; av[3]=f0.w;
      av[4]=f1.x; av[5]=f1.y; av[6]=f1.z; av[7]=f1.w;
    } else {        // global branch: unnormalized O + diag + normalize
      const int off = k0 - 64;
      const int h = off >> 3;
      const float* op = o_g + (size_t)row * 64 + off;
      float4 O0 = ld4(op), O1 = ld4(op + 4);
      float l = pl[(size_t)row * 8 + h];
      const int i = row & 1023;
      if (i % 3 != 0) {
        const float* base = qkv_g + (size_t)row * 192;
        const float* qp = base + h * 8;
        const float* kpp = base + 64 + h * 8;
        const float* vp = base + 128 + h * 8;
        float4 q0 = ld4(qp), q1 = ld4(qp + 4);
        float4 k0v = ld4(kpp), k1v = ld4(kpp + 4);
        float s = q0.x*k0v.x + q0.y*k0v.y + q0.z*k0v.z + q0.w*k0v.w
                + q1.x*k1v.x + q1.y*k1v.y + q1.z*k1v.z + q1.w*k1v.w;
        float p = __expf(s * INV_SQRT8);
        float4 v0 = ld4(vp), v1 = ld4(vp + 4);
        O0 = f4fma(p, v0, O0); O1 = f4fma(p, v1, O1);
        l += p;
      }
      float inv = 1.f / l;
      av[0]=O0.x*inv; av[1]=O0.y*inv; av[2]=O0.z*inv; av[3]=O0.w*inv;
      av[4]=O1.x*inv; av[5]=O1.y*inv; av[6]=O1.z*inv; av[7]=O1.w*inv;
    }
    short8 ah, al;
    #pragma unroll
    for (int i2 = 0; i2 < 8; i2++) { short h2, l2; bsplit(av[i2], h2, l2); ah[i2]=h2; al[i2]=l2; }
    #pragma unroll
    for (int g = 0; g < 4; g++) {
      short8 bh = *(const short8*)(Wh + (size_t)(g * 16 + r) * 128 + k0);
      short8 bl = *(const short8*)(Wl + (size_t)(g * 16 + r) * 128 + k0);
      acc[g] = __builtin_amdgcn_mfma_f32_16x16x32_bf16(al, bh, acc[g], 0, 0, 0);
      acc[g] = __builtin_amdgcn_mfma_f32_16x16x32_bf16(ah, bl, acc[g], 0, 0, 0);
      acc[g] = __builtin_amdgcn_mfma_f32_16x16x32_bf16(ah, bh, acc[g], 0, 0, 0);
    }
  }

  // park C-tile in LDS: Ls[row_local][col]
  #pragma unroll
  for (int g = 0; g < 4; g++)
    #pragma unroll
    for (int e = 0; e < 4; e++)
      Ls[w * 16 + quad * 4 + e][g * 16 + r] = acc[g][e];
  __syncthreads();

  // score phase (R11 score_pool, source = LDS). lane = row_local.
  float4 fr[16];
  #pragma unroll
  for (int e = 0; e < 16; e++) fr[e] = *(float4*)&Ls[lane][e * 4];

  float psc = 0.f;
  #pragma unroll
  for (int jj = 0; jj < 8; jj++) {
    const int j = w * 8 + jj;
    const float* wr = pw1 + j * 64;   // wave-uniform -> s_load
    float hj = pb1[j];
    #pragma unroll
    for (int e = 0; e < 16; e++) {
      float4 wv = ld4(wr + e * 4);
      hj += fr[e].x * wv.x + fr[e].y * wv.y + fr[e].z * wv.z + fr[e].w * wv.w;
    }
    float e2 = __expf(2.f * hj);
    psc += ((e2 - 1.f) / (e2 + 1.f)) * pw2[j];   // tanh via exp
  }
  partial[w][lane] = psc;
  __syncthreads();
  if (w == 0) {
    const int b = bx >> 4;
    float sc = pb2[0] + partial[0][lane] + partial[1][lane]
             + partial[2][lane] + partial[3][lane];
    float p = __expf(sc);
    #pragma unroll
    for (int e = 0; e < 16; e++) {
      Ls[lane][e*4+0] = p * fr[e].x; Ls[lane][e*4+1] = p * fr[e].y;
      Ls[lane][e*4+2] = p * fr[e].z; Ls[lane][e*4+3] = p * fr[e].w;
    }
    // single wave: DS ops in order, no barrier needed
    float colsum = 0.f;
    #pragma unroll 8
    for (int s = 0; s < 64; s++) colsum += Ls[s][lane];
    atomicAdd(&num[b * 64 + lane], colsum);
    float ps = p;
    #pragma unroll
    for (int off = 32; off > 0; off >>= 1)
      ps += __shfl_xor(ps, off, 64);
    if (lane == 0) atomicAdd(&den[b], ps);
  }
}

// ---------------- finalize: out = num/den
__global__ __launch_bounds__(1024) void finalize(
    const float* __restrict__ num, const float* __restrict__ den,
    float* __restrict__ out)
{
  int t = threadIdx.x;   // 1024 = 16*64
  out[t] = num[t] / den[t >> 6];
}

extern "C" void kernel_launch(void* const* d_in, const int* in_sizes, int n_in,
                              void* d_out, int out_size, void* d_ws, size_t ws_size,
                              hipStream_t stream)
{
  const float* x          = (const float*)d_in[0];
  const float* proj_w     = (const float*)d_in[1];
  const float* proj_b     = (const float*)d_in[2];
  const float* loc_in_w   = (const float*)d_in[3];
  const float* loc_in_b   = (const float*)d_in[4];
  const float* loc_out_w  = (const float*)d_in[5];
  const float* loc_out_b  = (const float*)d_in[6];
  const float* glob_in_w  = (const float*)d_in[7];
  const float* glob_in_b  = (const float*)d_in[8];
  const float* glob_out_w = (const float*)d_in[9];
  const float* glob_out_b = (const float*)d_in[10];
  const float* fusion_w   = (const float*)d_in[11];
  const float* fusion_b   = (const float*)d_in[12];
  const float* pw1        = (const float*)d_in[13];
  const float* pb1        = (const float*)d_in[14];
  const float* pw2        = (const float*)d_in[15];
  const float* pb2        = (const float*)d_in[16];

  float* ws = (float*)d_ws;
  // Layout (float offsets), lifetimes as R11 minus fused:
  //  qkv_g    [0, 3145728)
  //  xph/xpl  shorts at 3538944 (dead after qkv)
  //  qkv_l    [4587520, 7733248)
  //  o_l      [7733248, 8781824)
  //  o_g      [8781824, 9830400)
  //  pl       [9830400, 9961472)
  //  KH/KL    shorts at 9961472 / 10141696 (360448 each)
  //  VTh/VTl  shorts at 10321920 / 10682368 (720896 each)
  //  bc       [11042816, 11042880)
  //  num/den  [11042880, 11043920)
  //  wb       shorts at 11043920 (112640)
  float* qkv_g = ws;
  short* xph   = (short*)(ws + 3538944);
  short* xpl   = (short*)(ws + 4063232);
  float* qkv_l = ws + 4587520;
  float* o_l   = ws + 7733248;
  float* o_g   = ws + 8781824;
  float* pl    = ws + 9830400;
  short* KH    = (short*)(ws + 9961472);
  short* KL    = (short*)(ws + 10141696);
  short* VTh   = (short*)(ws + 10321920);
  short* VTl   = (short*)(ws + 10682368);
  float* bc    = ws + 11042816;
  float* numden= ws + 11042880;
  float* num   = numden;
  float* den   = numden + 1024;
  short* wb    = (short*)(ws + 11043920);
  short* projh = wb;           short* projl = wb + 20480;
  short* linh  = wb + 40960;   short* linl  = wb + 53248;
  short* ginh  = wb + 65536;   short* ginl  = wb + 77824;
  short* wfh   = wb + 90112;   short* wfl   = wb + 98304;
  float* out   = (float*)d_out;

  dim3 blk(256);
  // 1: weight split + fused fusion weights + combined bias + zero num/den
  prep_w<<<208, blk, 0, stream>>>(proj_w, loc_in_w, glob_in_w, fusion_w,
                                  loc_out_w, glob_out_w, loc_out_b, glob_out_b,
                                  fusion_b, wb, bc, numden);
  // 2: proj  M=16384 K=310 N=64 -> xp bf16 hi/lo
  gemm_proj<<<dim3(256, 2), blk, 0, stream>>>(x, projh, projl, proj_b, xph, xpl);
  // 3: qkv both branches  K=64 N=192
  gemm_mfma<64><<<dim3(256, 6, 2), blk, 0, stream>>>(
      xph, xpl, linh, linl, ginh, ginl, loc_in_b, glob_in_b,
      qkv_l, qkv_g, 192);
  // 4: K/V prep + local attention (merged, independent)
  prep_kv_local<<<4736, blk, 0, stream>>>(qkv_g, qkv_l, KH, KL, VTh, VTl, o_l);
  // 5: MFMA global attention -> unnormalized o_g + pl
  mfma_gattn<<<dim3(16, 8, 16), blk, 0, stream>>>(qkv_g, KH, KL, VTh, VTl, o_g, pl);
  // 6: fusion GEMM + score + pool partials (fused via LDS; fused buffer gone)
  gemm_fuse_score<<<256, blk, 0, stream>>>(
      o_l, o_g, pl, qkv_g, wfh, wfl, bc, pw1, pb1, pw2, pb2, num, den);
  // 7: finalize out = num/den
  finalize<<<1, dim3(1024), 0, stream>>>(num, den, out);
}